// Round 1
// baseline (2459.307 us; speedup 1.0000x reference)
//
#include <hip/hip_runtime.h>
#include <cstdint>
#include <cstddef>

#define NB 4
#define NN 2048
#define DD 384
#define NH 6

typedef float f4 __attribute__((ext_vector_type(4)));

__device__ __forceinline__ float gelu_t(float x) {
  float x3 = x*x*x;
  return 0.5f*x*(1.0f + tanhf(0.7978845608028654f*(x + 0.044715f*x3)));
}

// ---------- split (B,387,N) -> coords (B,N,3), feats (B,N,384) ----------
__global__ __launch_bounds__(256) void split_k(const float* __restrict__ pts,
                                               float* __restrict__ coords,
                                               float* __restrict__ feats) {
  __shared__ float t[32][33];
  int b = blockIdx.z;
  int c0 = blockIdx.x*32, n0 = blockIdx.y*32;
  int tx = threadIdx.x, ty = threadIdx.y;
#pragma unroll
  for (int i = 0; i < 4; ++i) {
    int c = c0 + ty + i*8;
    if (c < 387) t[ty+i*8][tx] = pts[((size_t)b*387 + c)*NN + n0 + tx];
  }
  __syncthreads();
#pragma unroll
  for (int i = 0; i < 4; ++i) {
    int n = n0 + ty + i*8;
    int c = c0 + tx;
    if (c < 387) {
      float v = t[tx][ty+i*8];
      if (c < 3) coords[((size_t)b*NN + n)*3 + c] = v;
      else       feats[((size_t)b*NN + n)*DD + (c-3)] = v;
    }
  }
}

// ---------- pack coords+feats -> (B,387,N) ----------
__global__ __launch_bounds__(256) void pack_k(const float* __restrict__ coords,
                                              const float* __restrict__ feats,
                                              float* __restrict__ out) {
  __shared__ float t[32][33];
  int b = blockIdx.z;
  int c0 = blockIdx.x*32, n0 = blockIdx.y*32;
  int tx = threadIdx.x, ty = threadIdx.y;
#pragma unroll
  for (int i = 0; i < 4; ++i) {
    int n = n0 + ty + i*8;
    int c = c0 + tx;
    if (c < 387) {
      float v = (c < 3) ? coords[((size_t)b*NN + n)*3 + c]
                        : feats[((size_t)b*NN + n)*DD + (c-3)];
      t[tx][ty+i*8] = v;
    }
  }
  __syncthreads();
#pragma unroll
  for (int i = 0; i < 4; ++i) {
    int c = c0 + ty + i*8;
    if (c < 387) out[((size_t)b*387 + c)*NN + n0 + tx] = t[ty+i*8][tx];
  }
}

// ---------- LayerNorm over last dim (384), one wave per row ----------
__global__ __launch_bounds__(256) void ln_k(const float* __restrict__ x,
                                            const float* __restrict__ g,
                                            const float* __restrict__ bb,
                                            float* __restrict__ o) {
  int lane = threadIdx.x & 63;
  int row = blockIdx.x*4 + (threadIdx.x >> 6);
  const float* xr = x + (size_t)row*DD;
  float v[6]; float s = 0.f;
#pragma unroll
  for (int i = 0; i < 6; ++i) { v[i] = xr[lane + i*64]; s += v[i]; }
#pragma unroll
  for (int off = 1; off < 64; off <<= 1) s += __shfl_xor(s, off);
  float mean = s * (1.f/384.f);
  float s2 = 0.f;
#pragma unroll
  for (int i = 0; i < 6; ++i) { float d = v[i] - mean; s2 += d*d; }
#pragma unroll
  for (int off = 1; off < 64; off <<= 1) s2 += __shfl_xor(s2, off);
  float rs = rsqrtf(s2*(1.f/384.f) + 1e-5f);
  float* orow = o + (size_t)row*DD;
#pragma unroll
  for (int i = 0; i < 6; ++i) {
    int c = lane + i*64;
    orow[c] = (v[i]-mean)*rs*g[c] + bb[c];
  }
}

// ---------- fp32 GEMM: C[M x N] = act(A[M x K] @ W[K x N] + bias) (+C) ----------
// BM=128, BN=64, BK=16; 256 threads; 8x4 per thread (rows 4ty+i and 64+4ty+i)
template<int ACT, int ACC>
__global__ __launch_bounds__(256) void gemm_k(const float* __restrict__ A, int lda,
                                              const float* __restrict__ W, int ldw,
                                              const float* __restrict__ bias,
                                              float* __restrict__ C, int ldc, int cofs,
                                              int Kd) {
  __shared__ float As[16][132];
  __shared__ float Ws[16][64];
  int tid = threadIdx.x;
  int tx = tid & 15, ty = tid >> 4;
  int n0 = blockIdx.x*64, m0 = blockIdx.y*128;
  f4 acc0[4], acc1[4];
#pragma unroll
  for (int i = 0; i < 4; ++i) { acc0[i] = 0.f; acc1[i] = 0.f; }
  for (int k0 = 0; k0 < Kd; k0 += 16) {
#pragma unroll
    for (int it = 0; it < 2; ++it) {
      int ff = tid + 256*it;
      int m = ff >> 2, k4 = ff & 3;
      f4 a = *(const f4*)(A + (size_t)(m0+m)*lda + k0 + k4*4);
#pragma unroll
      for (int e = 0; e < 4; ++e) As[k4*4+e][m] = a[e];
    }
    {
      int k = tid >> 4, c4 = tid & 15;
      *(f4*)&Ws[k][c4*4] = *(const f4*)(W + (size_t)(k0+k)*ldw + n0 + c4*4);
    }
    __syncthreads();
#pragma unroll
    for (int k = 0; k < 16; ++k) {
      f4 a0 = *(const f4*)&As[k][ty*4];
      f4 a1 = *(const f4*)&As[k][64 + ty*4];
      f4 b0 = *(const f4*)&Ws[k][tx*4];
#pragma unroll
      for (int i = 0; i < 4; ++i) {
#pragma unroll
        for (int j = 0; j < 4; ++j) {
          acc0[i][j] += a0[i]*b0[j];
          acc1[i][j] += a1[i]*b0[j];
        }
      }
    }
    __syncthreads();
  }
  f4 bv = 0.f;
  if (bias) bv = *(const f4*)(bias + n0 + tx*4);
#pragma unroll
  for (int half = 0; half < 2; ++half) {
#pragma unroll
    for (int i = 0; i < 4; ++i) {
      int row = m0 + half*64 + ty*4 + i;
      float* cp = C + (size_t)row*ldc + cofs + n0 + tx*4;
      f4 v;
#pragma unroll
      for (int j = 0; j < 4; ++j) {
        float t = (half ? acc1[i][j] : acc0[i][j]) + bv[j];
        if (ACT == 1) t = gelu_t(t);
        v[j] = t;
      }
      if (ACC) { f4 old = *(const f4*)cp; v = v + old; }
      *(f4*)cp = v;
    }
  }
}

// ---------- flash attention (fp32), qkv rows: [q(384) k(384) v(384)] ----------
// grid (NN/64, H, B), 256 threads; thread tile: 4 q-rows (4ty+i) x 4 cols (4tx+j)
__global__ __launch_bounds__(256) void flash_k(const float* __restrict__ qkv,
                                               float* __restrict__ o) {
  __shared__ float Qs[64][64];
  __shared__ float Ks[64][64];
  __shared__ float Vs[64][64];
  __shared__ float Ps[64][64];
  int b = blockIdx.z, h = blockIdx.y, q0 = blockIdx.x*64;
  int tid = threadIdx.x;
  int tx = tid & 15, ty = tid >> 4;
  const float* qb = qkv + ((size_t)b*NN + q0)*1152 + h*64;
#pragma unroll
  for (int it = 0; it < 4; ++it) {
    int ff = tid + 256*it;
    int r = ff >> 4, c4 = ff & 15;
    f4 v = *(const f4*)(qb + (size_t)r*1152 + c4*4);
    v *= 0.125f;  // 1/sqrt(dh)
    *(f4*)&Qs[r][(c4 ^ ((r>>2)&7))*4] = v;
  }
  float m_[4], l_[4];
  f4 acc[4];
#pragma unroll
  for (int i = 0; i < 4; ++i) { m_[i] = -INFINITY; l_[i] = 0.f; acc[i] = 0.f; }
  __syncthreads();
  for (int kt = 0; kt < 32; ++kt) {
    const float* kb = qkv + ((size_t)b*NN + kt*64)*1152 + DD + h*64;
#pragma unroll
    for (int it = 0; it < 4; ++it) {
      int ff = tid + 256*it;
      int r = ff >> 4, c4 = ff & 15;
      int cs = (c4 ^ ((r>>2)&7))*4;
      *(f4*)&Ks[r][cs] = *(const f4*)(kb + (size_t)r*1152 + c4*4);
      *(f4*)&Vs[r][cs] = *(const f4*)(kb + (size_t)r*1152 + DD + c4*4);
    }
    __syncthreads();
    f4 s[4];
#pragma unroll
    for (int i = 0; i < 4; ++i) s[i] = 0.f;
#pragma unroll
    for (int d4 = 0; d4 < 16; ++d4) {
      f4 q4[4], k4[4];
#pragma unroll
      for (int i = 0; i < 4; ++i) q4[i] = *(const f4*)&Qs[4*ty+i][(d4 ^ (ty&7))*4];
#pragma unroll
      for (int j = 0; j < 4; ++j) k4[j] = *(const f4*)&Ks[4*tx+j][(d4 ^ (tx&7))*4];
#pragma unroll
      for (int i = 0; i < 4; ++i)
#pragma unroll
        for (int j = 0; j < 4; ++j)
          s[i][j] += q4[i][0]*k4[j][0] + q4[i][1]*k4[j][1]
                   + q4[i][2]*k4[j][2] + q4[i][3]*k4[j][3];
    }
#pragma unroll
    for (int i = 0; i < 4; ++i) {
      float rm = fmaxf(fmaxf(s[i][0], s[i][1]), fmaxf(s[i][2], s[i][3]));
      rm = fmaxf(rm, __shfl_xor(rm, 1));
      rm = fmaxf(rm, __shfl_xor(rm, 2));
      rm = fmaxf(rm, __shfl_xor(rm, 4));
      rm = fmaxf(rm, __shfl_xor(rm, 8));
      float mn = fmaxf(m_[i], rm);
      float sc = __expf(m_[i] - mn);
      f4 p;
      float ps = 0.f;
#pragma unroll
      for (int j = 0; j < 4; ++j) { p[j] = __expf(s[i][j] - mn); ps += p[j]; }
      ps += __shfl_xor(ps, 1);
      ps += __shfl_xor(ps, 2);
      ps += __shfl_xor(ps, 4);
      ps += __shfl_xor(ps, 8);
      l_[i] = l_[i]*sc + ps;
      m_[i] = mn;
      acc[i] *= sc;
      *(f4*)&Ps[4*ty+i][(tx ^ (ty&7))*4] = p;
    }
    __syncthreads();
#pragma unroll
    for (int kj4 = 0; kj4 < 16; ++kj4) {
      f4 p4[4];
#pragma unroll
      for (int i = 0; i < 4; ++i) p4[i] = *(const f4*)&Ps[4*ty+i][(kj4 ^ (ty&7))*4];
#pragma unroll
      for (int jj = 0; jj < 4; ++jj) {
        f4 v4 = *(const f4*)&Vs[kj4*4+jj][(tx ^ (kj4&7))*4];
#pragma unroll
        for (int i = 0; i < 4; ++i) acc[i] += p4[i][jj]*v4;
      }
    }
    __syncthreads();
  }
#pragma unroll
  for (int i = 0; i < 4; ++i) {
    f4 v = acc[i] * (1.f/l_[i]);
    *(f4*)(o + ((size_t)b*NN + q0 + 4*ty + i)*DD + h*64 + tx*4) = v;
  }
}

// ---------- KNN top-8 by squared distance, one wave per query ----------
__global__ __launch_bounds__(256) void knn_k(const float* __restrict__ qc,
                                             const float* __restrict__ kc,
                                             int* __restrict__ idx) {
  int lane = threadIdx.x & 63;
  int q = blockIdx.x*4 + (threadIdx.x >> 6);
  int b = q >> 11, n = q & 2047;
  const float* qp = qc + ((size_t)b*NN + n)*3;
  float qx = qp[0], qy = qp[1], qz = qp[2];
  float qq = qx*qx + qy*qy + qz*qz;
  float bd[8]; int bi[8];
#pragma unroll
  for (int i = 0; i < 8; ++i) { bd[i] = INFINITY; bi[i] = 0x7fffffff; }
  const float* kb = kc + (size_t)b*NN*3;
  for (int j = lane; j < NN; j += 64) {
    float kx = kb[(size_t)j*3], ky = kb[(size_t)j*3+1], kz = kb[(size_t)j*3+2];
    float dt = qx*kx + qy*ky + qz*kz;
    float kk = kx*kx + ky*ky + kz*kz;
    float d2 = qq + kk - 2.f*dt;
    if (d2 < bd[7]) {
      float nd = d2; int ni = j;
#pragma unroll
      for (int k = 0; k < 8; ++k) {
        bool sw = (nd < bd[k]) || (nd == bd[k] && ni < bi[k]);  // lexicographic
        float td = sw ? bd[k] : nd;
        int   ti = sw ? bi[k] : ni;
        if (sw) { bd[k] = nd; bi[k] = ni; }
        nd = td; ni = ti;
      }
    }
  }
  int res[8];
#pragma unroll
  for (int r = 0; r < 8; ++r) {
    float cd = bd[0]; int ci = bi[0];
#pragma unroll
    for (int off = 32; off >= 1; off >>= 1) {
      float od = __shfl_xor(cd, off);
      int oi = __shfl_xor(ci, off);
      if (od < cd || (od == cd && oi < ci)) { cd = od; ci = oi; }
    }
    res[r] = ci;
    if (ci == bi[0]) {
#pragma unroll
      for (int k = 0; k < 7; ++k) { bd[k] = bd[k+1]; bi[k] = bi[k+1]; }
      bd[7] = INFINITY; bi[7] = 0x7fffffff;
    }
  }
  if (lane == 0) {
#pragma unroll
    for (int r = 0; r < 8; ++r) idx[(size_t)q*8 + r] = res[r];
  }
}

// ---------- geom = max_k lrelu(G[idx_k] + C), into attnG[:,384:768] ----------
__global__ __launch_bounds__(384) void geom_k(const float* __restrict__ G,
                                              const float* __restrict__ Cb,
                                              const int* __restrict__ idx,
                                              float* __restrict__ out) {
  int q = blockIdx.x;
  int b = q >> 11;
  int d = threadIdx.x;
  float c = Cb[(size_t)q*DD + d];
  float mx = -INFINITY;
#pragma unroll
  for (int kn = 0; kn < 8; ++kn) {
    int j = idx[(size_t)q*8 + kn];
    float gg = G[((size_t)b*NN + j)*DD + d];
    float y = gg + c;
    y = (y > 0.f) ? y : 0.2f*y;
    mx = fmaxf(mx, y);
  }
  out[(size_t)q*768 + 384 + d] = mx;
}

// ---------- wdiff = W[384:768,:] - W[0:384,:] ----------
__global__ __launch_bounds__(256) void wdiff_k(const float* __restrict__ W,
                                               float* __restrict__ d) {
  int i = blockIdx.x*256 + threadIdx.x;
  d[i] = W[384*384 + i] - W[i];
}

extern "C" void kernel_launch(void* const* d_in, const int* in_sizes, int n_in,
                              void* d_out, int out_size, void* d_ws, size_t ws_size,
                              hipStream_t stream) {
  (void)in_sizes; (void)n_in; (void)out_size; (void)ws_size;
  const float* qpts  = (const float*)d_in[0];
  const float* kpts  = (const float*)d_in[1];
  const float* ln_s  = (const float*)d_in[2];
  const float* ln_b  = (const float*)d_in[3];
  const float* qkvW  = (const float*)d_in[4];
  const float* Wo    = (const float*)d_in[5];
  const float* bo    = (const float*)d_in[6];
  const float* ffW1  = (const float*)d_in[7];
  const float* ffb1  = (const float*)d_in[8];
  const float* ffW2  = (const float*)d_in[9];
  const float* ffb2  = (const float*)d_in[10];
  const float* ffns  = (const float*)d_in[11];
  const float* ffnb  = (const float*)d_in[12];
  const float* knn1W = (const float*)d_in[13];
  const float* knn1b = (const float*)d_in[14];
  const float* knn2W = (const float*)d_in[15];
  const float* knn2b = (const float*)d_in[16];
  const float* smW   = (const float*)d_in[17];
  const float* smb   = (const float*)d_in[18];
  const float* cmW   = (const float*)d_in[19];
  const float* cmb   = (const float*)d_in[20];
  const float* cnqs  = (const float*)d_in[21];
  const float* cnqb  = (const float*)d_in[22];
  const float* cnks  = (const float*)d_in[23];
  const float* cnkb  = (const float*)d_in[24];
  const float* cqW   = (const float*)d_in[25];
  const float* ckW   = (const float*)d_in[26];
  const float* cvW   = (const float*)d_in[27];

  float* ws = (float*)d_ws;
  float* qc   = ws;                       // 4*2048*3
  float* kc   = qc  + 24576;
  float* qf   = kc  + 24576;              // 8192*384
  float* kf   = qf  + 3145728;
  float* nrm  = kf  + 3145728;            // norm_f / nq / h
  float* nk   = nrm + 3145728;
  float* qkv  = nk  + 3145728;            // 8192*1152 ; attnG aliases it
  float* attnG= qkv;                      // 8192*768 (cols 0:384 attn, 384:768 geom)
  float* attnO= qkv + 9437184;            // 8192*384 (pre-proj attention out)
  float* G    = attnO;                    // alias: G written after attnO consumed
  float* Cb   = attnO + 3145728;          // 8192*384
  float* wd   = Cb  + 3145728;            // 384*384
  int*   idx  = (int*)(wd + 147456);      // 8192*8

  dim3 tgrid(13, 64, NB), tblk(32, 8);
  split_k<<<tgrid, tblk, 0, stream>>>(qpts, qc, qf);
  split_k<<<tgrid, tblk, 0, stream>>>(kpts, kc, kf);

  dim3 g384(6, 64), g768(12, 64), g1152(18, 64);

  // ---- self attention branch ----
  ln_k<<<2048, 256, 0, stream>>>(qf, ln_s, ln_b, nrm);
  gemm_k<0,0><<<g1152, 256, 0, stream>>>(nrm, DD, qkvW, 1152, nullptr, qkv, 1152, 0, DD);
  flash_k<<<dim3(32, NH, NB), 256, 0, stream>>>(qkv, attnO);
  gemm_k<0,0><<<g384, 256, 0, stream>>>(attnO, DD, Wo, DD, bo, attnG, 768, 0, DD);
  // geometry branch (self): G = nrm@W1top ; Cb = nrm@(W1bot-W1top)+b1
  wdiff_k<<<576, 256, 0, stream>>>(knn1W, wd);
  gemm_k<0,0><<<g384, 256, 0, stream>>>(nrm, DD, knn1W, DD, nullptr, G, DD, 0, DD);
  gemm_k<0,0><<<g384, 256, 0, stream>>>(nrm, DD, wd, DD, knn1b, Cb, DD, 0, DD);
  knn_k<<<2048, 256, 0, stream>>>(qc, qc, idx);
  geom_k<<<8192, 384, 0, stream>>>(G, Cb, idx, attnG);
  gemm_k<0,1><<<g384, 256, 0, stream>>>(attnG, 768, smW, DD, smb, qf, DD, 0, 768);

  // ---- cross attention branch ----
  ln_k<<<2048, 256, 0, stream>>>(qf, cnqs, cnqb, nrm);   // nq
  ln_k<<<2048, 256, 0, stream>>>(kf, cnks, cnkb, nk);    // nk
  gemm_k<0,0><<<g384, 256, 0, stream>>>(nrm, DD, cqW, DD, nullptr, qkv, 1152, 0,   DD);
  gemm_k<0,0><<<g384, 256, 0, stream>>>(nk,  DD, ckW, DD, nullptr, qkv, 1152, 384, DD);
  gemm_k<0,0><<<g384, 256, 0, stream>>>(nk,  DD, cvW, DD, nullptr, qkv, 1152, 768, DD);
  flash_k<<<dim3(32, NH, NB), 256, 0, stream>>>(qkv, attnO);
  gemm_k<0,0><<<g384, 256, 0, stream>>>(attnO, DD, Wo, DD, bo, attnG, 768, 0, DD);
  wdiff_k<<<576, 256, 0, stream>>>(knn2W, wd);
  gemm_k<0,0><<<g384, 256, 0, stream>>>(nk,  DD, knn2W, DD, nullptr, G, DD, 0, DD);
  gemm_k<0,0><<<g384, 256, 0, stream>>>(nrm, DD, wd, DD, knn2b, Cb, DD, 0, DD);
  knn_k<<<2048, 256, 0, stream>>>(qc, kc, idx);
  geom_k<<<8192, 384, 0, stream>>>(G, Cb, idx, attnG);
  gemm_k<0,1><<<g384, 256, 0, stream>>>(attnG, 768, cmW, DD, cmb, qf, DD, 0, 768);

  // ---- FFN ----
  ln_k<<<2048, 256, 0, stream>>>(qf, ffns, ffnb, nrm);
  gemm_k<1,0><<<g768, 256, 0, stream>>>(nrm, DD, ffW1, 768, ffb1, attnG, 768, 0, DD);
  gemm_k<0,1><<<g384, 256, 0, stream>>>(attnG, 768, ffW2, DD, ffb2, qf, DD, 0, 768);

  pack_k<<<tgrid, tblk, 0, stream>>>(qc, qf, (float*)d_out);
}

// Round 2
// 1380.722 us; speedup vs baseline: 1.7812x; 1.7812x over previous
//
#include <hip/hip_runtime.h>
#include <cstdint>
#include <cstddef>

#define NB 4
#define NN 2048
#define DD 384
#define NH 6

typedef float f4 __attribute__((ext_vector_type(4)));
typedef float f32x4 __attribute__((ext_vector_type(4)));
typedef short bf16x8 __attribute__((ext_vector_type(8)));
typedef short s4v __attribute__((ext_vector_type(4)));

__device__ __forceinline__ float gelu_t(float x) {
  float x3 = x*x*x;
  return 0.5f*x*(1.0f + tanhf(0.7978845608028654f*(x + 0.044715f*x3)));
}

__device__ __forceinline__ unsigned short f2b(float f) {
  unsigned u = __builtin_bit_cast(unsigned, f);
  u += 0x7fffu + ((u >> 16) & 1u);
  return (unsigned short)(u >> 16);
}

// ---------- split (B,387,N) -> coords (B,N,3), feats (B,N,384) ----------
__global__ __launch_bounds__(256) void split_k(const float* __restrict__ pts,
                                               float* __restrict__ coords,
                                               float* __restrict__ feats) {
  __shared__ float t[32][33];
  int b = blockIdx.z;
  int c0 = blockIdx.x*32, n0 = blockIdx.y*32;
  int tx = threadIdx.x, ty = threadIdx.y;
#pragma unroll
  for (int i = 0; i < 4; ++i) {
    int c = c0 + ty + i*8;
    if (c < 387) t[ty+i*8][tx] = pts[((size_t)b*387 + c)*NN + n0 + tx];
  }
  __syncthreads();
#pragma unroll
  for (int i = 0; i < 4; ++i) {
    int n = n0 + ty + i*8;
    int c = c0 + tx;
    if (c < 387) {
      float v = t[tx][ty+i*8];
      if (c < 3) coords[((size_t)b*NN + n)*3 + c] = v;
      else       feats[((size_t)b*NN + n)*DD + (c-3)] = v;
    }
  }
}

// ---------- pack coords+feats -> (B,387,N) ----------
__global__ __launch_bounds__(256) void pack_k(const float* __restrict__ coords,
                                              const float* __restrict__ feats,
                                              float* __restrict__ out) {
  __shared__ float t[32][33];
  int b = blockIdx.z;
  int c0 = blockIdx.x*32, n0 = blockIdx.y*32;
  int tx = threadIdx.x, ty = threadIdx.y;
#pragma unroll
  for (int i = 0; i < 4; ++i) {
    int n = n0 + ty + i*8;
    int c = c0 + tx;
    if (c < 387) {
      float v = (c < 3) ? coords[((size_t)b*NN + n)*3 + c]
                        : feats[((size_t)b*NN + n)*DD + (c-3)];
      t[tx][ty+i*8] = v;
    }
  }
  __syncthreads();
#pragma unroll
  for (int i = 0; i < 4; ++i) {
    int c = c0 + ty + i*8;
    if (c < 387) out[((size_t)b*387 + c)*NN + n0 + tx] = t[ty+i*8][tx];
  }
}

// ---------- LayerNorm over last dim (384), one wave per row ----------
__global__ __launch_bounds__(256) void ln_k(const float* __restrict__ x,
                                            const float* __restrict__ g,
                                            const float* __restrict__ bb,
                                            float* __restrict__ o) {
  int lane = threadIdx.x & 63;
  int row = blockIdx.x*4 + (threadIdx.x >> 6);
  const float* xr = x + (size_t)row*DD;
  float v[6]; float s = 0.f;
#pragma unroll
  for (int i = 0; i < 6; ++i) { v[i] = xr[lane + i*64]; s += v[i]; }
#pragma unroll
  for (int off = 1; off < 64; off <<= 1) s += __shfl_xor(s, off);
  float mean = s * (1.f/384.f);
  float s2 = 0.f;
#pragma unroll
  for (int i = 0; i < 6; ++i) { float d = v[i] - mean; s2 += d*d; }
#pragma unroll
  for (int off = 1; off < 64; off <<= 1) s2 += __shfl_xor(s2, off);
  float rs = rsqrtf(s2*(1.f/384.f) + 1e-5f);
  float* orow = o + (size_t)row*DD;
#pragma unroll
  for (int i = 0; i < 6; ++i) {
    int c = lane + i*64;
    orow[c] = (v[i]-mean)*rs*g[c] + bb[c];
  }
}

// ---------- fp32 GEMM: C[M x N] = act(A[M x K] @ W[K x N] + bias) (+C) ----------
// BM=128, BN=64, BK=16; 256 threads; 8x4 per thread
// OB=1: write bf16 (C reinterpreted as ushort*), no ACC
template<int ACT, int ACC, int OB>
__global__ __launch_bounds__(256) void gemm_k(const float* __restrict__ A, int lda,
                                              const float* __restrict__ W, int ldw,
                                              const float* __restrict__ bias,
                                              float* __restrict__ C, int ldc, int cofs,
                                              int Kd) {
  __shared__ float As[16][132];
  __shared__ float Ws[16][64];
  int tid = threadIdx.x;
  int tx = tid & 15, ty = tid >> 4;
  int n0 = blockIdx.x*64, m0 = blockIdx.y*128;
  f4 acc0[4], acc1[4];
#pragma unroll
  for (int i = 0; i < 4; ++i) { acc0[i] = 0.f; acc1[i] = 0.f; }
  for (int k0 = 0; k0 < Kd; k0 += 16) {
#pragma unroll
    for (int it = 0; it < 2; ++it) {
      int ff = tid + 256*it;
      int m = ff >> 2, k4 = ff & 3;
      f4 a = *(const f4*)(A + (size_t)(m0+m)*lda + k0 + k4*4);
#pragma unroll
      for (int e = 0; e < 4; ++e) As[k4*4+e][m] = a[e];
    }
    {
      int k = tid >> 4, c4 = tid & 15;
      *(f4*)&Ws[k][c4*4] = *(const f4*)(W + (size_t)(k0+k)*ldw + n0 + c4*4);
    }
    __syncthreads();
#pragma unroll
    for (int k = 0; k < 16; ++k) {
      f4 a0 = *(const f4*)&As[k][ty*4];
      f4 a1 = *(const f4*)&As[k][64 + ty*4];
      f4 b0 = *(const f4*)&Ws[k][tx*4];
#pragma unroll
      for (int i = 0; i < 4; ++i) {
#pragma unroll
        for (int j = 0; j < 4; ++j) {
          acc0[i][j] += a0[i]*b0[j];
          acc1[i][j] += a1[i]*b0[j];
        }
      }
    }
    __syncthreads();
  }
  f4 bv = 0.f;
  if (bias) bv = *(const f4*)(bias + n0 + tx*4);
#pragma unroll
  for (int half = 0; half < 2; ++half) {
#pragma unroll
    for (int i = 0; i < 4; ++i) {
      int row = m0 + half*64 + ty*4 + i;
      f4 v;
#pragma unroll
      for (int j = 0; j < 4; ++j) {
        float t = (half ? acc1[i][j] : acc0[i][j]) + bv[j];
        if (ACT == 1) t = gelu_t(t);
        v[j] = t;
      }
      if (OB) {
        unsigned short* cb = (unsigned short*)C;
        s4v ob;
#pragma unroll
        for (int j = 0; j < 4; ++j) ob[j] = (short)f2b(v[j]);
        *(s4v*)(cb + (size_t)row*ldc + cofs + n0 + tx*4) = ob;
      } else {
        float* cp = C + (size_t)row*ldc + cofs + n0 + tx*4;
        if (ACC) { f4 old = *(const f4*)cp; v = v + old; }
        *(f4*)cp = v;
      }
    }
  }
}

// ---------- V transpose: qkvb V cols -> vt[(b*6+h)*64 + d][2048 keys] (bf16) ----------
__global__ __launch_bounds__(256) void vtrans_k(const unsigned short* __restrict__ qkvb,
                                                unsigned short* __restrict__ vt) {
  __shared__ unsigned short T[4096];
  int bh = blockIdx.y; int b = bh / NH, h = bh % NH;
  int t0 = blockIdx.x*64;
  int tid = threadIdx.x;
#pragma unroll
  for (int p = 0; p < 2; ++p) {
    int row = p*32 + (tid >> 3);
    int ch  = tid & 7;
    bf16x8 v = *(const bf16x8*)(qkvb + ((size_t)(b*NN + t0 + row))*1152 + 768 + h*64 + ch*8);
    *(bf16x8*)&T[row*64 + ((ch ^ (row & 7))*8)] = v;
  }
  __syncthreads();
#pragma unroll
  for (int p = 0; p < 2; ++p) {
    int d  = p*32 + (tid >> 3);
    int kc = tid & 7;
    bf16x8 v;
#pragma unroll
    for (int e = 0; e < 8; ++e) {
      int tok = kc*8 + e;
      v[e] = (short)T[tok*64 + (((d >> 3) ^ (tok & 7))*8) + (d & 7)];
    }
    *(bf16x8*)(vt + (((size_t)bh*64 + d)*NN) + t0 + kc*8) = v;
  }
}

// ---------- MFMA flash attention (bf16 inputs, f32 accum) ----------
// grid (NN/64, H, B), 256 threads = 4 waves, each wave owns 16 q-rows.
// mfma_f32_16x16x32_bf16: A lane: row=l&15, k=8*(l>>4)+e ; B lane: col=l&15, k=8*(l>>4)+e
// C/D lane: col=l&15, row=4*(l>>4)+r   [verified m89]
__global__ __launch_bounds__(256) void flashm_k(const unsigned short* __restrict__ qkvb,
                                                const unsigned short* __restrict__ vt,
                                                float* __restrict__ o) {
  __shared__ char smem[24576];   // KT 8KB | VT 8KB | PT 8KB
  char* KT = smem;
  char* VT = smem + 8192;
  char* PT = smem + 16384;
  int b = blockIdx.z, h = blockIdx.y, q0 = blockIdx.x*64;
  int tid = threadIdx.x;
  int w = tid >> 6, lane = tid & 63, g = lane >> 4, c = lane & 15;

  // Q fragments in registers (rows w*16+c)
  bf16x8 qf[2];
  {
    const unsigned short* qrow = qkvb + ((size_t)(b*NN + q0 + w*16 + c))*1152 + h*64;
    qf[0] = *(const bf16x8*)(qrow + 8*g);
    qf[1] = *(const bf16x8*)(qrow + 32 + 8*g);
  }
  f32x4 oacc[4];
#pragma unroll
  for (int i = 0; i < 4; ++i) oacc[i] = 0.f;
  float m_[4], l_[4];
#pragma unroll
  for (int r = 0; r < 4; ++r) { m_[r] = -3.0e38f; l_[r] = 0.f; }

  int srow = lane >> 3;          // 0..7
  int scol = (lane & 7)*16;      // byte chunk within 128B row

  for (int kt = 0; kt < 32; ++kt) {
    // stage K and V^T tiles: global -> regs
    bf16x8 kreg[2], vreg[2];
    int rows[2];
#pragma unroll
    for (int i = 0; i < 2; ++i) {
      int row = w*16 + i*8 + srow;
      rows[i] = row;
      kreg[i] = *(const bf16x8*)(qkvb + ((size_t)(b*NN + kt*64 + row))*1152 + 384 + h*64 + (scol >> 1));
      vreg[i] = *(const bf16x8*)(vt + (((size_t)(b*NH + h)*64 + row))*NN + kt*64 + (scol >> 1));
    }
    __syncthreads();   // all waves done reading previous tiles
#pragma unroll
    for (int i = 0; i < 2; ++i) {
      int row = rows[i];
      int cb = scol ^ ((row & 7) << 4);
      *(bf16x8*)(KT + row*128 + cb) = kreg[i];
      *(bf16x8*)(VT + row*128 + cb) = vreg[i];
    }
    __syncthreads();   // tiles visible

    // S = Q K^T  (m = q-rows, n = keys, k = d)
    f32x4 s[4];
#pragma unroll
    for (int nt = 0; nt < 4; ++nt) s[nt] = 0.f;
#pragma unroll
    for (int nt = 0; nt < 4; ++nt) {
      int key = nt*16 + c;
#pragma unroll
      for (int kb = 0; kb < 2; ++kb) {
        int cb = (kb*64 + g*16) ^ ((key & 7) << 4);
        bf16x8 kfrag = *(const bf16x8*)(KT + key*128 + cb);
        s[nt] = __builtin_amdgcn_mfma_f32_16x16x32_bf16(qf[kb], kfrag, s[nt], 0, 0, 0);
      }
    }
#pragma unroll
    for (int nt = 0; nt < 4; ++nt) s[nt] *= 0.125f;

    // online softmax (rows 4g+r; reduce over 16-lane group)
    float sc[4], mn[4];
#pragma unroll
    for (int r = 0; r < 4; ++r) {
      float pm = fmaxf(fmaxf(s[0][r], s[1][r]), fmaxf(s[2][r], s[3][r]));
#pragma unroll
      for (int off = 1; off < 16; off <<= 1) pm = fmaxf(pm, __shfl_xor(pm, off));
      float m2 = fmaxf(m_[r], pm);
      sc[r] = __expf(m_[r] - m2);
      m_[r] = m2; mn[r] = m2;
    }
#pragma unroll
    for (int nt = 0; nt < 4; ++nt)
#pragma unroll
      for (int r = 0; r < 4; ++r) s[nt][r] = __expf(s[nt][r] - mn[r]);
#pragma unroll
    for (int r = 0; r < 4; ++r) {
      float ps = s[0][r] + s[1][r] + s[2][r] + s[3][r];
#pragma unroll
      for (int off = 1; off < 16; off <<= 1) ps += __shfl_xor(ps, off);
      l_[r] = l_[r]*sc[r] + ps;
#pragma unroll
      for (int dt = 0; dt < 4; ++dt) oacc[dt][r] *= sc[r];
    }

    // write P (bf16) to wave-private LDS rows
#pragma unroll
    for (int nt = 0; nt < 4; ++nt)
#pragma unroll
      for (int r = 0; r < 4; ++r) {
        int prow = w*16 + 4*g + r;
        int cb = ((nt*16 + c)*2) ^ ((prow & 7) << 4);
        *(unsigned short*)(PT + prow*128 + cb) = f2b(s[nt][r]);
      }

    // O += P V   (m = q-rows, n = d, k = keys)
    int prow = w*16 + c;
    bf16x8 pa[2];
#pragma unroll
    for (int kb = 0; kb < 2; ++kb) {
      int cb = (kb*64 + g*16) ^ ((prow & 7) << 4);
      pa[kb] = *(const bf16x8*)(PT + prow*128 + cb);
    }
#pragma unroll
    for (int dt = 0; dt < 4; ++dt) {
      int drow = dt*16 + c;
#pragma unroll
      for (int kb = 0; kb < 2; ++kb) {
        int cb = (kb*64 + g*16) ^ ((drow & 7) << 4);
        bf16x8 vb = *(const bf16x8*)(VT + drow*128 + cb);
        oacc[dt] = __builtin_amdgcn_mfma_f32_16x16x32_bf16(pa[kb], vb, oacc[dt], 0, 0, 0);
      }
    }
  }

#pragma unroll
  for (int r = 0; r < 4; ++r) {
    float inv = 1.f / l_[r];
    size_t rowo = ((size_t)b*NN + q0 + w*16 + 4*g + r)*DD + h*64;
#pragma unroll
    for (int dt = 0; dt < 4; ++dt)
      o[rowo + dt*16 + c] = oacc[dt][r]*inv;
  }
}

// ---------- KNN top-8 by squared distance, one wave per query ----------
__global__ __launch_bounds__(256) void knn_k(const float* __restrict__ qc,
                                             const float* __restrict__ kc,
                                             int* __restrict__ idx) {
  int lane = threadIdx.x & 63;
  int q = blockIdx.x*4 + (threadIdx.x >> 6);
  int b = q >> 11, n = q & 2047;
  const float* qp = qc + ((size_t)b*NN + n)*3;
  float qx = qp[0], qy = qp[1], qz = qp[2];
  float qq = qx*qx + qy*qy + qz*qz;
  float bd[8]; int bi[8];
#pragma unroll
  for (int i = 0; i < 8; ++i) { bd[i] = INFINITY; bi[i] = 0x7fffffff; }
  const float* kb = kc + (size_t)b*NN*3;
  for (int j = lane; j < NN; j += 64) {
    float kx = kb[(size_t)j*3], ky = kb[(size_t)j*3+1], kz = kb[(size_t)j*3+2];
    float dt = qx*kx + qy*ky + qz*kz;
    float kk = kx*kx + ky*ky + kz*kz;
    float d2 = qq + kk - 2.f*dt;
    if (d2 < bd[7]) {
      float nd = d2; int ni = j;
#pragma unroll
      for (int k = 0; k < 8; ++k) {
        bool sw = (nd < bd[k]) || (nd == bd[k] && ni < bi[k]);
        float td = sw ? bd[k] : nd;
        int   ti = sw ? bi[k] : ni;
        if (sw) { bd[k] = nd; bi[k] = ni; }
        nd = td; ni = ti;
      }
    }
  }
  int res[8];
#pragma unroll
  for (int r = 0; r < 8; ++r) {
    float cd = bd[0]; int ci = bi[0];
#pragma unroll
    for (int off = 32; off >= 1; off >>= 1) {
      float od = __shfl_xor(cd, off);
      int oi = __shfl_xor(ci, off);
      if (od < cd || (od == cd && oi < ci)) { cd = od; ci = oi; }
    }
    res[r] = ci;
    if (ci == bi[0]) {
#pragma unroll
      for (int k = 0; k < 7; ++k) { bd[k] = bd[k+1]; bi[k] = bi[k+1]; }
      bd[7] = INFINITY; bi[7] = 0x7fffffff;
    }
  }
  if (lane == 0) {
#pragma unroll
    for (int r = 0; r < 8; ++r) idx[(size_t)q*8 + r] = res[r];
  }
}

// ---------- geom = max_k lrelu(G[idx_k] + C), into attnG[:,384:768] ----------
__global__ __launch_bounds__(384) void geom_k(const float* __restrict__ G,
                                              const float* __restrict__ Cb,
                                              const int* __restrict__ idx,
                                              float* __restrict__ out) {
  int q = blockIdx.x;
  int b = q >> 11;
  int d = threadIdx.x;
  float c = Cb[(size_t)q*DD + d];
  float mx = -INFINITY;
#pragma unroll
  for (int kn = 0; kn < 8; ++kn) {
    int j = idx[(size_t)q*8 + kn];
    float gg = G[((size_t)b*NN + j)*DD + d];
    float y = gg + c;
    y = (y > 0.f) ? y : 0.2f*y;
    mx = fmaxf(mx, y);
  }
  out[(size_t)q*768 + 384 + d] = mx;
}

// ---------- wdiff = W[384:768,:] - W[0:384,:] ----------
__global__ __launch_bounds__(256) void wdiff_k(const float* __restrict__ W,
                                               float* __restrict__ d) {
  int i = blockIdx.x*256 + threadIdx.x;
  d[i] = W[384*384 + i] - W[i];
}

extern "C" void kernel_launch(void* const* d_in, const int* in_sizes, int n_in,
                              void* d_out, int out_size, void* d_ws, size_t ws_size,
                              hipStream_t stream) {
  (void)in_sizes; (void)n_in; (void)out_size; (void)ws_size;
  const float* qpts  = (const float*)d_in[0];
  const float* kpts  = (const float*)d_in[1];
  const float* ln_s  = (const float*)d_in[2];
  const float* ln_b  = (const float*)d_in[3];
  const float* qkvW  = (const float*)d_in[4];
  const float* Wo    = (const float*)d_in[5];
  const float* bo    = (const float*)d_in[6];
  const float* ffW1  = (const float*)d_in[7];
  const float* ffb1  = (const float*)d_in[8];
  const float* ffW2  = (const float*)d_in[9];
  const float* ffb2  = (const float*)d_in[10];
  const float* ffns  = (const float*)d_in[11];
  const float* ffnb  = (const float*)d_in[12];
  const float* knn1W = (const float*)d_in[13];
  const float* knn1b = (const float*)d_in[14];
  const float* knn2W = (const float*)d_in[15];
  const float* knn2b = (const float*)d_in[16];
  const float* smW   = (const float*)d_in[17];
  const float* smb   = (const float*)d_in[18];
  const float* cmW   = (const float*)d_in[19];
  const float* cmb   = (const float*)d_in[20];
  const float* cnqs  = (const float*)d_in[21];
  const float* cnqb  = (const float*)d_in[22];
  const float* cnks  = (const float*)d_in[23];
  const float* cnkb  = (const float*)d_in[24];
  const float* cqW   = (const float*)d_in[25];
  const float* ckW   = (const float*)d_in[26];
  const float* cvW   = (const float*)d_in[27];

  float* ws = (float*)d_ws;
  float* qc   = ws;                       // 4*2048*3
  float* kc   = qc  + 24576;
  float* qf   = kc  + 24576;              // 8192*384
  float* kf   = qf  + 3145728;
  float* nrm  = kf  + 3145728;            // norm_f / nq / h
  float* nk   = nrm + 3145728;
  float* qkv  = nk  + 3145728;            // 9437184-float region
  unsigned short* qkvb = (unsigned short*)qkv;      // 8192*1152 bf16 (4.72M floats)
  float* attnG = qkv;                     // 8192*768 f32 (6.29M floats) - after flash
  unsigned short* vtb = (unsigned short*)(qkv + 6291456); // 24*64*2048 bf16 (3.15M floats)
  float* attnO = qkv + 9437184;           // 8192*384
  float* G    = attnO;                    // alias (G written after attnO consumed)
  float* Cb   = attnO + 3145728;
  float* wd   = Cb  + 3145728;            // 384*384
  int*   idx  = (int*)(wd + 147456);      // 8192*8

  dim3 tgrid(13, 64, NB), tblk(32, 8);
  split_k<<<tgrid, tblk, 0, stream>>>(qpts, qc, qf);
  split_k<<<tgrid, tblk, 0, stream>>>(kpts, kc, kf);

  dim3 g384(6, 64), g768(12, 64), g1152(18, 64);
  dim3 fgrid(32, NH, NB), vgrid(32, NB*NH);

  // ---- self attention branch ----
  ln_k<<<2048, 256, 0, stream>>>(qf, ln_s, ln_b, nrm);
  gemm_k<0,0,1><<<g1152, 256, 0, stream>>>(nrm, DD, qkvW, 1152, nullptr, (float*)qkvb, 1152, 0, DD);
  vtrans_k<<<vgrid, 256, 0, stream>>>(qkvb, vtb);
  flashm_k<<<fgrid, 256, 0, stream>>>(qkvb, vtb, attnO);
  gemm_k<0,0,0><<<g384, 256, 0, stream>>>(attnO, DD, Wo, DD, bo, attnG, 768, 0, DD);
  // geometry branch (self): G = nrm@W1top ; Cb = nrm@(W1bot-W1top)+b1
  wdiff_k<<<576, 256, 0, stream>>>(knn1W, wd);
  gemm_k<0,0,0><<<g384, 256, 0, stream>>>(nrm, DD, knn1W, DD, nullptr, G, DD, 0, DD);
  gemm_k<0,0,0><<<g384, 256, 0, stream>>>(nrm, DD, wd, DD, knn1b, Cb, DD, 0, DD);
  knn_k<<<2048, 256, 0, stream>>>(qc, qc, idx);
  geom_k<<<8192, 384, 0, stream>>>(G, Cb, idx, attnG);
  gemm_k<0,1,0><<<g384, 256, 0, stream>>>(attnG, 768, smW, DD, smb, qf, DD, 0, 768);

  // ---- cross attention branch ----
  ln_k<<<2048, 256, 0, stream>>>(qf, cnqs, cnqb, nrm);   // nq
  ln_k<<<2048, 256, 0, stream>>>(kf, cnks, cnkb, nk);    // nk
  gemm_k<0,0,1><<<g384, 256, 0, stream>>>(nrm, DD, cqW, DD, nullptr, (float*)qkvb, 1152, 0,   DD);
  gemm_k<0,0,1><<<g384, 256, 0, stream>>>(nk,  DD, ckW, DD, nullptr, (float*)qkvb, 1152, 384, DD);
  gemm_k<0,0,1><<<g384, 256, 0, stream>>>(nk,  DD, cvW, DD, nullptr, (float*)qkvb, 1152, 768, DD);
  vtrans_k<<<vgrid, 256, 0, stream>>>(qkvb, vtb);
  flashm_k<<<fgrid, 256, 0, stream>>>(qkvb, vtb, attnO);
  gemm_k<0,0,0><<<g384, 256, 0, stream>>>(attnO, DD, Wo, DD, bo, attnG, 768, 0, DD);
  wdiff_k<<<576, 256, 0, stream>>>(knn2W, wd);
  gemm_k<0,0,0><<<g384, 256, 0, stream>>>(nk,  DD, knn2W, DD, nullptr, G, DD, 0, DD);
  gemm_k<0,0,0><<<g384, 256, 0, stream>>>(nrm, DD, wd, DD, knn2b, Cb, DD, 0, DD);
  knn_k<<<2048, 256, 0, stream>>>(qc, kc, idx);
  geom_k<<<8192, 384, 0, stream>>>(G, Cb, idx, attnG);
  gemm_k<0,1,0><<<g384, 256, 0, stream>>>(attnG, 768, cmW, DD, cmb, qf, DD, 0, 768);

  // ---- FFN ----
  ln_k<<<2048, 256, 0, stream>>>(qf, ffns, ffnb, nrm);
  gemm_k<1,0,0><<<g768, 256, 0, stream>>>(nrm, DD, ffW1, 768, ffb1, attnG, 768, 0, DD);
  gemm_k<0,1,0><<<g384, 256, 0, stream>>>(attnG, 768, ffW2, DD, ffb2, qf, DD, 0, 768);

  pack_k<<<tgrid, tblk, 0, stream>>>(qc, qf, (float*)d_out);
}

// Round 3
// 560.169 us; speedup vs baseline: 4.3903x; 2.4648x over previous
//
#include <hip/hip_runtime.h>
#include <cstdint>
#include <cstddef>

#define NB 4
#define NN 2048
#define DD 384
#define NH 6

typedef float f4 __attribute__((ext_vector_type(4)));
typedef float f32x4 __attribute__((ext_vector_type(4)));
typedef short bf16x8 __attribute__((ext_vector_type(8)));

__device__ __forceinline__ float gelu_t(float x) {
  float x3 = x*x*x;
  return 0.5f*x*(1.0f + tanhf(0.7978845608028654f*(x + 0.044715f*x3)));
}

__device__ __forceinline__ unsigned short f2b(float f) {
  unsigned u = __builtin_bit_cast(unsigned, f);
  u += 0x7fffu + ((u >> 16) & 1u);
  return (unsigned short)(u >> 16);
}

// ---------- split (B,387,N) -> coords (B,N,3), feats (B,N,384) ----------
__global__ __launch_bounds__(256) void split_k(const float* __restrict__ pts,
                                               float* __restrict__ coords,
                                               float* __restrict__ feats) {
  __shared__ float t[32][33];
  int b = blockIdx.z;
  int c0 = blockIdx.x*32, n0 = blockIdx.y*32;
  int tx = threadIdx.x, ty = threadIdx.y;
#pragma unroll
  for (int i = 0; i < 4; ++i) {
    int c = c0 + ty + i*8;
    if (c < 387) t[ty+i*8][tx] = pts[((size_t)b*387 + c)*NN + n0 + tx];
  }
  __syncthreads();
#pragma unroll
  for (int i = 0; i < 4; ++i) {
    int n = n0 + ty + i*8;
    int c = c0 + tx;
    if (c < 387) {
      float v = t[tx][ty+i*8];
      if (c < 3) coords[((size_t)b*NN + n)*3 + c] = v;
      else       feats[((size_t)b*NN + n)*DD + (c-3)] = v;
    }
  }
}

// ---------- pack coords+feats -> (B,387,N) ----------
__global__ __launch_bounds__(256) void pack_k(const float* __restrict__ coords,
                                              const float* __restrict__ feats,
                                              float* __restrict__ out) {
  __shared__ float t[32][33];
  int b = blockIdx.z;
  int c0 = blockIdx.x*32, n0 = blockIdx.y*32;
  int tx = threadIdx.x, ty = threadIdx.y;
#pragma unroll
  for (int i = 0; i < 4; ++i) {
    int n = n0 + ty + i*8;
    int c = c0 + tx;
    if (c < 387) {
      float v = (c < 3) ? coords[((size_t)b*NN + n)*3 + c]
                        : feats[((size_t)b*NN + n)*DD + (c-3)];
      t[tx][ty+i*8] = v;
    }
  }
  __syncthreads();
#pragma unroll
  for (int i = 0; i < 4; ++i) {
    int c = c0 + ty + i*8;
    if (c < 387) out[((size_t)b*387 + c)*NN + n0 + tx] = t[ty+i*8][tx];
  }
}

// ---------- LayerNorm over last dim (384), bf16 out ----------
__global__ __launch_bounds__(256) void ln_k(const float* __restrict__ x,
                                            const float* __restrict__ g,
                                            const float* __restrict__ bb,
                                            unsigned short* __restrict__ o) {
  int lane = threadIdx.x & 63;
  int row = blockIdx.x*4 + (threadIdx.x >> 6);
  const float* xr = x + (size_t)row*DD;
  float v[6]; float s = 0.f;
#pragma unroll
  for (int i = 0; i < 6; ++i) { v[i] = xr[lane + i*64]; s += v[i]; }
#pragma unroll
  for (int off = 1; off < 64; off <<= 1) s += __shfl_xor(s, off);
  float mean = s * (1.f/384.f);
  float s2 = 0.f;
#pragma unroll
  for (int i = 0; i < 6; ++i) { float d = v[i] - mean; s2 += d*d; }
#pragma unroll
  for (int off = 1; off < 64; off <<= 1) s2 += __shfl_xor(s2, off);
  float rs = rsqrtf(s2*(1.f/384.f) + 1e-5f);
  unsigned short* orow = o + (size_t)row*DD;
#pragma unroll
  for (int i = 0; i < 6; ++i) {
    int c = lane + i*64;
    orow[c] = f2b((v[i]-mean)*rs*g[c] + bb[c]);
  }
}

// ---------- one-shot weight transpose+convert: Wt[n][k] = W[k][n] (bf16) ----------
struct WSrcs { const float* p[13]; };

__global__ __launch_bounds__(256) void wtrans_k(WSrcs srcs, unsigned short* __restrict__ dst) {
  constexpr int KK[13]  = {384,384,384,384,768,384,384,384,384,384,768,384,768};
  constexpr int NW[13]  = {1152,384,384,384,384,384,384,384,384,384,384,768,384};
  constexpr int MD[13]  = {0,0,0,2,0,0,0,0,0,2,0,0,0};  // 2 = rows[384:768]-rows[0:384]
  constexpr int OFF[13] = {0,442368,589824,737280,884736,1179648,1327104,1474560,
                           1622016,1769472,1916928,2211840,2506752};
  constexpr int PFX[14] = {0,432,576,720,864,1152,1296,1440,1584,1728,1872,2160,2448,2736};
  int bid = blockIdx.x;
  int e = 0;
  while (bid >= PFX[e+1]) ++e;
  int t = bid - PFX[e];
  int K = KK[e], N = NW[e];
  int ntiles = N >> 5;
  int kt = t / ntiles, nt = t - kt*ntiles;
  const float* src = srcs.p[e];
  __shared__ float T[32][33];
  int tx = threadIdx.x & 31, ty = threadIdx.x >> 5;
  int n = nt*32 + tx;
#pragma unroll
  for (int i = 0; i < 4; ++i) {
    int k = kt*32 + ty + i*8;
    float v = src[(size_t)k*N + n];
    if (MD[e] == 2) v = src[(size_t)(k+384)*N + n] - v;
    T[ty+i*8][tx] = v;
  }
  __syncthreads();
#pragma unroll
  for (int i = 0; i < 4; ++i) {
    int nn = nt*32 + ty + i*8;
    int kk = kt*32 + tx;
    dst[(size_t)OFF[e] + (size_t)nn*K + kk] = f2b(T[tx][ty+i*8]);
  }
}

// ---------- MFMA bf16 GEMM: C[M x N] = act(A @ W + bias) (+C) ----------
// A: [M][lda] bf16 row-major. Wt: [N][Kd] bf16 (pre-transposed). BM=128 BN=64 BK=64.
// 256 threads = 4 waves 2x2; wave tile 64x32 = acc[4][2] frags of 16x16.
template<int ACT, int ACC, int OB>
__global__ __launch_bounds__(256) void mgemm_k(const unsigned short* __restrict__ A, int lda,
                                               const unsigned short* __restrict__ Wt,
                                               const float* __restrict__ bias,
                                               void* __restrict__ Cv, int ldc, int cofs,
                                               int Kd) {
  __shared__ char lds[24576];           // As[128][128B] | Bs[64][128B]
  char* As = lds;
  char* Bs = lds + 16384;
  int tid = threadIdx.x;
  int lane = tid & 63, w = tid >> 6, g = lane >> 4, c = lane & 15;
  int wr = w >> 1, wc = w & 1;
  int m0 = blockIdx.y*128, n0 = blockIdx.x*64;

  f32x4 acc[4][2];
#pragma unroll
  for (int mt = 0; mt < 4; ++mt)
#pragma unroll
    for (int nt = 0; nt < 2; ++nt) acc[mt][nt] = 0.f;

  int KT = Kd >> 6;
  bf16x8 rA[4], rB[2];
  // granule (p = it*256+tid): row = p>>3, chunk = p&7 (16B chunks of a 128B row)
#pragma unroll
  for (int it = 0; it < 4; ++it) {
    int p = it*256 + tid; int row = p >> 3, ch = p & 7;
    rA[it] = *(const bf16x8*)(A + (size_t)(m0+row)*lda + ch*8);
  }
#pragma unroll
  for (int it = 0; it < 2; ++it) {
    int p = it*256 + tid; int row = p >> 3, ch = p & 7;
    rB[it] = *(const bf16x8*)(Wt + (size_t)(n0+row)*Kd + ch*8);
  }

  for (int kt = 0; kt < KT; ++kt) {
    __syncthreads();                     // LDS free (prev compute done)
#pragma unroll
    for (int it = 0; it < 4; ++it) {
      int p = it*256 + tid; int row = p >> 3, ch = p & 7;
      *(bf16x8*)(As + row*128 + ((ch ^ (row & 7))*16)) = rA[it];
    }
#pragma unroll
    for (int it = 0; it < 2; ++it) {
      int p = it*256 + tid; int row = p >> 3, ch = p & 7;
      *(bf16x8*)(Bs + row*128 + ((ch ^ (row & 7))*16)) = rB[it];
    }
    if (kt + 1 < KT) {                   // prefetch next K-tile into regs
      int k0 = (kt+1)*64;
#pragma unroll
      for (int it = 0; it < 4; ++it) {
        int p = it*256 + tid; int row = p >> 3, ch = p & 7;
        rA[it] = *(const bf16x8*)(A + (size_t)(m0+row)*lda + k0 + ch*8);
      }
#pragma unroll
      for (int it = 0; it < 2; ++it) {
        int p = it*256 + tid; int row = p >> 3, ch = p & 7;
        rB[it] = *(const bf16x8*)(Wt + (size_t)(n0+row)*Kd + k0 + ch*8);
      }
    }
    __syncthreads();                     // LDS ready
#pragma unroll
    for (int kb = 0; kb < 2; ++kb) {
      bf16x8 af[4], bfr[2];
#pragma unroll
      for (int mt = 0; mt < 4; ++mt) {
        int row = wr*64 + mt*16 + c;
        int ch = (kb*4 + g) ^ (row & 7);
        af[mt] = *(const bf16x8*)(As + row*128 + ch*16);
      }
#pragma unroll
      for (int nt = 0; nt < 2; ++nt) {
        int row = wc*32 + nt*16 + c;
        int ch = (kb*4 + g) ^ (row & 7);
        bfr[nt] = *(const bf16x8*)(Bs + row*128 + ch*16);
      }
#pragma unroll
      for (int mt = 0; mt < 4; ++mt)
#pragma unroll
        for (int nt = 0; nt < 2; ++nt)
          acc[mt][nt] = __builtin_amdgcn_mfma_f32_16x16x32_bf16(af[mt], bfr[nt], acc[mt][nt], 0, 0, 0);
    }
  }

#pragma unroll
  for (int mt = 0; mt < 4; ++mt) {
#pragma unroll
    for (int nt = 0; nt < 2; ++nt) {
      int coln = n0 + wc*32 + nt*16 + c;
      float bval = bias ? bias[coln] : 0.f;
#pragma unroll
      for (int r = 0; r < 4; ++r) {
        int m = m0 + wr*64 + mt*16 + 4*g + r;
        float t = acc[mt][nt][r] + bval;
        if (ACT == 1) t = gelu_t(t);
        if (OB) {
          ((unsigned short*)Cv)[(size_t)m*ldc + cofs + coln] = f2b(t);
        } else {
          float* cp = (float*)Cv + (size_t)m*ldc + cofs + coln;
          if (ACC) t += *cp;
          *cp = t;
        }
      }
    }
  }
}

// ---------- V transpose: qkvb V cols -> vt[(b*6+h)*64 + d][2048 keys] (bf16) ----------
__global__ __launch_bounds__(256) void vtrans_k(const unsigned short* __restrict__ qkvb,
                                                unsigned short* __restrict__ vt) {
  __shared__ unsigned short T[4096];
  int bh = blockIdx.y; int b = bh / NH, h = bh % NH;
  int t0 = blockIdx.x*64;
  int tid = threadIdx.x;
#pragma unroll
  for (int p = 0; p < 2; ++p) {
    int row = p*32 + (tid >> 3);
    int ch  = tid & 7;
    bf16x8 v = *(const bf16x8*)(qkvb + ((size_t)(b*NN + t0 + row))*1152 + 768 + h*64 + ch*8);
    *(bf16x8*)&T[row*64 + ((ch ^ (row & 7))*8)] = v;
  }
  __syncthreads();
#pragma unroll
  for (int p = 0; p < 2; ++p) {
    int d  = p*32 + (tid >> 3);
    int kc = tid & 7;
    bf16x8 v;
#pragma unroll
    for (int e = 0; e < 8; ++e) {
      int tok = kc*8 + e;
      v[e] = (short)T[tok*64 + (((d >> 3) ^ (tok & 7))*8) + (d & 7)];
    }
    *(bf16x8*)(vt + (((size_t)bh*64 + d)*NN) + t0 + kc*8) = v;
  }
}

// ---------- MFMA flash attention (bf16 in, bf16 out) ----------
__global__ __launch_bounds__(256) void flashm_k(const unsigned short* __restrict__ qkvb,
                                                const unsigned short* __restrict__ vt,
                                                unsigned short* __restrict__ o) {
  __shared__ char smem[24576];   // KT 8KB | VT 8KB | PT 8KB
  char* KT = smem;
  char* VT = smem + 8192;
  char* PT = smem + 16384;
  int b = blockIdx.z, h = blockIdx.y, q0 = blockIdx.x*64;
  int tid = threadIdx.x;
  int w = tid >> 6, lane = tid & 63, g = lane >> 4, c = lane & 15;

  bf16x8 qf[2];
  {
    const unsigned short* qrow = qkvb + ((size_t)(b*NN + q0 + w*16 + c))*1152 + h*64;
    qf[0] = *(const bf16x8*)(qrow + 8*g);
    qf[1] = *(const bf16x8*)(qrow + 32 + 8*g);
  }
  f32x4 oacc[4];
#pragma unroll
  for (int i = 0; i < 4; ++i) oacc[i] = 0.f;
  float m_[4], l_[4];
#pragma unroll
  for (int r = 0; r < 4; ++r) { m_[r] = -3.0e38f; l_[r] = 0.f; }

  int srow = lane >> 3;
  int scol = (lane & 7)*16;

  for (int kt = 0; kt < 32; ++kt) {
    bf16x8 kreg[2], vreg[2];
    int rows[2];
#pragma unroll
    for (int i = 0; i < 2; ++i) {
      int row = w*16 + i*8 + srow;
      rows[i] = row;
      kreg[i] = *(const bf16x8*)(qkvb + ((size_t)(b*NN + kt*64 + row))*1152 + 384 + h*64 + (scol >> 1));
      vreg[i] = *(const bf16x8*)(vt + (((size_t)(b*NH + h)*64 + row))*NN + kt*64 + (scol >> 1));
    }
    __syncthreads();
#pragma unroll
    for (int i = 0; i < 2; ++i) {
      int row = rows[i];
      int cb = scol ^ ((row & 7) << 4);
      *(bf16x8*)(KT + row*128 + cb) = kreg[i];
      *(bf16x8*)(VT + row*128 + cb) = vreg[i];
    }
    __syncthreads();

    f32x4 s[4];
#pragma unroll
    for (int nt = 0; nt < 4; ++nt) s[nt] = 0.f;
#pragma unroll
    for (int nt = 0; nt < 4; ++nt) {
      int key = nt*16 + c;
#pragma unroll
      for (int kb = 0; kb < 2; ++kb) {
        int cb = (kb*64 + g*16) ^ ((key & 7) << 4);
        bf16x8 kfrag = *(const bf16x8*)(KT + key*128 + cb);
        s[nt] = __builtin_amdgcn_mfma_f32_16x16x32_bf16(qf[kb], kfrag, s[nt], 0, 0, 0);
      }
    }
#pragma unroll
    for (int nt = 0; nt < 4; ++nt) s[nt] *= 0.125f;

    float sc[4], mn[4];
#pragma unroll
    for (int r = 0; r < 4; ++r) {
      float pm = fmaxf(fmaxf(s[0][r], s[1][r]), fmaxf(s[2][r], s[3][r]));
#pragma unroll
      for (int off = 1; off < 16; off <<= 1) pm = fmaxf(pm, __shfl_xor(pm, off));
      float m2 = fmaxf(m_[r], pm);
      sc[r] = __expf(m_[r] - m2);
      m_[r] = m2; mn[r] = m2;
    }
#pragma unroll
    for (int nt = 0; nt < 4; ++nt)
#pragma unroll
      for (int r = 0; r < 4; ++r) s[nt][r] = __expf(s[nt][r] - mn[r]);
#pragma unroll
    for (int r = 0; r < 4; ++r) {
      float ps = s[0][r] + s[1][r] + s[2][r] + s[3][r];
#pragma unroll
      for (int off = 1; off < 16; off <<= 1) ps += __shfl_xor(ps, off);
      l_[r] = l_[r]*sc[r] + ps;
#pragma unroll
      for (int dt = 0; dt < 4; ++dt) oacc[dt][r] *= sc[r];
    }

#pragma unroll
    for (int nt = 0; nt < 4; ++nt)
#pragma unroll
      for (int r = 0; r < 4; ++r) {
        int prow = w*16 + 4*g + r;
        int cb = ((nt*16 + c)*2) ^ ((prow & 7) << 4);
        *(unsigned short*)(PT + prow*128 + cb) = f2b(s[nt][r]);
      }

    int prow = w*16 + c;
    bf16x8 pa[2];
#pragma unroll
    for (int kb = 0; kb < 2; ++kb) {
      int cb = (kb*64 + g*16) ^ ((prow & 7) << 4);
      pa[kb] = *(const bf16x8*)(PT + prow*128 + cb);
    }
#pragma unroll
    for (int dt = 0; dt < 4; ++dt) {
      int drow = dt*16 + c;
#pragma unroll
      for (int kb = 0; kb < 2; ++kb) {
        int cb = (kb*64 + g*16) ^ ((drow & 7) << 4);
        bf16x8 vb = *(const bf16x8*)(VT + drow*128 + cb);
        oacc[dt] = __builtin_amdgcn_mfma_f32_16x16x32_bf16(pa[kb], vb, oacc[dt], 0, 0, 0);
      }
    }
  }

#pragma unroll
  for (int r = 0; r < 4; ++r) {
    float inv = 1.f / l_[r];
    size_t rowo = ((size_t)b*NN + q0 + w*16 + 4*g + r)*DD + h*64;
#pragma unroll
    for (int dt = 0; dt < 4; ++dt)
      o[rowo + dt*16 + c] = f2b(oacc[dt][r]*inv);
  }
}

// ---------- KNN top-8 by squared distance, one wave per query ----------
__global__ __launch_bounds__(256) void knn_k(const float* __restrict__ qc,
                                             const float* __restrict__ kc,
                                             int* __restrict__ idx) {
  int lane = threadIdx.x & 63;
  int q = blockIdx.x*4 + (threadIdx.x >> 6);
  int b = q >> 11, n = q & 2047;
  const float* qp = qc + ((size_t)b*NN + n)*3;
  float qx = qp[0], qy = qp[1], qz = qp[2];
  float qq = qx*qx + qy*qy + qz*qz;
  float bd[8]; int bi[8];
#pragma unroll
  for (int i = 0; i < 8; ++i) { bd[i] = INFINITY; bi[i] = 0x7fffffff; }
  const float* kb = kc + (size_t)b*NN*3;
  for (int j = lane; j < NN; j += 64) {
    float kx = kb[(size_t)j*3], ky = kb[(size_t)j*3+1], kz = kb[(size_t)j*3+2];
    float dt = qx*kx + qy*ky + qz*kz;
    float kk = kx*kx + ky*ky + kz*kz;
    float d2 = qq + kk - 2.f*dt;
    if (d2 < bd[7]) {
      float nd = d2; int ni = j;
#pragma unroll
      for (int k = 0; k < 8; ++k) {
        bool sw = (nd < bd[k]) || (nd == bd[k] && ni < bi[k]);
        float td = sw ? bd[k] : nd;
        int   ti = sw ? bi[k] : ni;
        if (sw) { bd[k] = nd; bi[k] = ni; }
        nd = td; ni = ti;
      }
    }
  }
  int res[8];
#pragma unroll
  for (int r = 0; r < 8; ++r) {
    float cd = bd[0]; int ci = bi[0];
#pragma unroll
    for (int off = 32; off >= 1; off >>= 1) {
      float od = __shfl_xor(cd, off);
      int oi = __shfl_xor(ci, off);
      if (od < cd || (od == cd && oi < ci)) { cd = od; ci = oi; }
    }
    res[r] = ci;
    if (ci == bi[0]) {
#pragma unroll
      for (int k = 0; k < 7; ++k) { bd[k] = bd[k+1]; bi[k] = bi[k+1]; }
      bd[7] = INFINITY; bi[7] = 0x7fffffff;
    }
  }
  if (lane == 0) {
#pragma unroll
    for (int r = 0; r < 8; ++r) idx[(size_t)q*8 + r] = res[r];
  }
}

// ---------- geom = max_k lrelu(G[idx_k] + C), bf16 into attnG[:,384:768] ----------
__global__ __launch_bounds__(384) void geom_k(const float* __restrict__ G,
                                              const float* __restrict__ Cb,
                                              const int* __restrict__ idx,
                                              unsigned short* __restrict__ out) {
  int q = blockIdx.x;
  int b = q >> 11;
  int d = threadIdx.x;
  float c = Cb[(size_t)q*DD + d];
  float mx = -INFINITY;
#pragma unroll
  for (int kn = 0; kn < 8; ++kn) {
    int j = idx[(size_t)q*8 + kn];
    float gg = G[((size_t)b*NN + j)*DD + d];
    float y = gg + c;
    y = (y > 0.f) ? y : 0.2f*y;
    mx = fmaxf(mx, y);
  }
  out[(size_t)q*768 + 384 + d] = f2b(mx);
}

extern "C" void kernel_launch(void* const* d_in, const int* in_sizes, int n_in,
                              void* d_out, int out_size, void* d_ws, size_t ws_size,
                              hipStream_t stream) {
  (void)in_sizes; (void)n_in; (void)out_size; (void)ws_size;
  const float* qpts  = (const float*)d_in[0];
  const float* kpts  = (const float*)d_in[1];
  const float* ln_s  = (const float*)d_in[2];
  const float* ln_b  = (const float*)d_in[3];
  const float* qkvW  = (const float*)d_in[4];
  const float* Wo    = (const float*)d_in[5];
  const float* bo    = (const float*)d_in[6];
  const float* ffW1  = (const float*)d_in[7];
  const float* ffb1  = (const float*)d_in[8];
  const float* ffW2  = (const float*)d_in[9];
  const float* ffb2  = (const float*)d_in[10];
  const float* ffns  = (const float*)d_in[11];
  const float* ffnb  = (const float*)d_in[12];
  const float* knn1W = (const float*)d_in[13];
  const float* knn1b = (const float*)d_in[14];
  const float* knn2W = (const float*)d_in[15];
  const float* knn2b = (const float*)d_in[16];
  const float* smW   = (const float*)d_in[17];
  const float* smb   = (const float*)d_in[18];
  const float* cmW   = (const float*)d_in[19];
  const float* cmb   = (const float*)d_in[20];
  const float* cnqs  = (const float*)d_in[21];
  const float* cnqb  = (const float*)d_in[22];
  const float* cnks  = (const float*)d_in[23];
  const float* cnkb  = (const float*)d_in[24];
  const float* cqW   = (const float*)d_in[25];
  const float* ckW   = (const float*)d_in[26];
  const float* cvW   = (const float*)d_in[27];

  float* ws = (float*)d_ws;
  float* qc   = ws;                       // 4*2048*3
  float* kc   = qc  + 24576;
  float* qf   = kc  + 24576;              // 8192*384 f32 (residual stream)
  float* kf   = qf  + 3145728;
  unsigned short* nrmb = (unsigned short*)(kf + 3145728);   // bf16 LN out
  unsigned short* nkb  = (unsigned short*)(kf + 3145728 + 3145728);
  float* qkv  = kf + 3145728 + 3145728 + 3145728;           // 9437184-float region
  unsigned short* qkvb  = (unsigned short*)qkv;             // 8192*1152 bf16
  unsigned short* attnGb= (unsigned short*)qkv;             // 8192*768 bf16 (aliases)
  unsigned short* vtb   = (unsigned short*)(qkv + 6291456); // 24*64*2048 bf16
  unsigned short* wtb   = (unsigned short*)(qkv + 7864320); // 2801664 bf16 weights
  float* attnO = qkv + 9437184;           // 8192*384 region (attnOb bf16 / G f32 alias)
  unsigned short* attnOb = (unsigned short*)attnO;
  float* G    = attnO;
  float* Cb   = attnO + 3145728;
  int*   idx  = (int*)(Cb + 3145728);     // 8192*8

  // weight table offsets (bf16 elements)
  const int W_QKV=0, W_WO=442368, W_K1T=589824, W_WD1=737280, W_SM=884736,
            W_CQ=1179648, W_CK=1327104, W_CV=1474560, W_K2T=1622016,
            W_WD2=1769472, W_CM=1916928, W_FF1=2211840, W_FF2=2506752;

  WSrcs srcs;
  srcs.p[0]=qkvW; srcs.p[1]=Wo; srcs.p[2]=knn1W; srcs.p[3]=knn1W; srcs.p[4]=smW;
  srcs.p[5]=cqW; srcs.p[6]=ckW; srcs.p[7]=cvW; srcs.p[8]=knn2W; srcs.p[9]=knn2W;
  srcs.p[10]=cmW; srcs.p[11]=ffW1; srcs.p[12]=ffW2;
  wtrans_k<<<2736, 256, 0, stream>>>(srcs, wtb);

  dim3 tgrid(13, 64, NB), tblk(32, 8);
  split_k<<<tgrid, tblk, 0, stream>>>(qpts, qc, qf);
  split_k<<<tgrid, tblk, 0, stream>>>(kpts, kc, kf);

  dim3 mg384(6, 64), mg768(12, 64), mg1152(18, 64);
  dim3 fgrid(32, NH, NB), vgrid(32, NB*NH);

  // ---- self attention branch ----
  ln_k<<<2048, 256, 0, stream>>>(qf, ln_s, ln_b, nrmb);
  mgemm_k<0,0,1><<<mg1152, 256, 0, stream>>>(nrmb, DD, wtb+W_QKV, nullptr, qkvb, 1152, 0, DD);
  vtrans_k<<<vgrid, 256, 0, stream>>>(qkvb, vtb);
  flashm_k<<<fgrid, 256, 0, stream>>>(qkvb, vtb, attnOb);
  mgemm_k<0,0,1><<<mg384, 256, 0, stream>>>(attnOb, DD, wtb+W_WO, bo, attnGb, 768, 0, DD);
  mgemm_k<0,0,0><<<mg384, 256, 0, stream>>>(nrmb, DD, wtb+W_K1T, nullptr, G, DD, 0, DD);
  mgemm_k<0,0,0><<<mg384, 256, 0, stream>>>(nrmb, DD, wtb+W_WD1, knn1b, Cb, DD, 0, DD);
  knn_k<<<2048, 256, 0, stream>>>(qc, qc, idx);
  geom_k<<<8192, 384, 0, stream>>>(G, Cb, idx, attnGb);
  mgemm_k<0,1,0><<<mg384, 256, 0, stream>>>(attnGb, 768, wtb+W_SM, smb, qf, DD, 0, 768);

  // ---- cross attention branch ----
  ln_k<<<2048, 256, 0, stream>>>(qf, cnqs, cnqb, nrmb);   // nq
  ln_k<<<2048, 256, 0, stream>>>(kf, cnks, cnkb, nkb);    // nk
  mgemm_k<0,0,1><<<mg384, 256, 0, stream>>>(nrmb, DD, wtb+W_CQ, nullptr, qkvb, 1152, 0,   DD);
  mgemm_k<0,0,1><<<mg384, 256, 0, stream>>>(nkb,  DD, wtb+W_CK, nullptr, qkvb, 1152, 384, DD);
  mgemm_k<0,0,1><<<mg384, 256, 0, stream>>>(nkb,  DD, wtb+W_CV, nullptr, qkvb, 1152, 768, DD);
  vtrans_k<<<vgrid, 256, 0, stream>>>(qkvb, vtb);
  flashm_k<<<fgrid, 256, 0, stream>>>(qkvb, vtb, attnOb);
  mgemm_k<0,0,1><<<mg384, 256, 0, stream>>>(attnOb, DD, wtb+W_WO, bo, attnGb, 768, 0, DD);
  mgemm_k<0,0,0><<<mg384, 256, 0, stream>>>(nkb,  DD, wtb+W_K2T, nullptr, G, DD, 0, DD);
  mgemm_k<0,0,0><<<mg384, 256, 0, stream>>>(nrmb, DD, wtb+W_WD2, knn2b, Cb, DD, 0, DD);
  knn_k<<<2048, 256, 0, stream>>>(qc, kc, idx);
  geom_k<<<8192, 384, 0, stream>>>(G, Cb, idx, attnGb);
  mgemm_k<0,1,0><<<mg384, 256, 0, stream>>>(attnGb, 768, wtb+W_CM, cmb, qf, DD, 0, 768);

  // ---- FFN ----
  ln_k<<<2048, 256, 0, stream>>>(qf, ffns, ffnb, nrmb);
  mgemm_k<1,0,1><<<mg768, 256, 0, stream>>>(nrmb, DD, wtb+W_FF1, ffb1, attnGb, 768, 0, DD);
  mgemm_k<0,1,0><<<mg384, 256, 0, stream>>>(attnGb, 768, wtb+W_FF2, ffb2, qf, DD, 0, 768);

  pack_k<<<tgrid, tblk, 0, stream>>>(qc, qf, (float*)d_out);
}

// Round 4
// 477.315 us; speedup vs baseline: 5.1524x; 1.1736x over previous
//
#include <hip/hip_runtime.h>
#include <cstdint>
#include <cstddef>

#define NB 4
#define NN 2048
#define DD 384
#define NH 6

typedef float f4 __attribute__((ext_vector_type(4)));
typedef float f32x4 __attribute__((ext_vector_type(4)));
typedef short bf16x8 __attribute__((ext_vector_type(8)));
typedef short s4v __attribute__((ext_vector_type(4)));

__device__ __forceinline__ float gelu_t(float x) {
  float x3 = x*x*x;
  return 0.5f*x*(1.0f + tanhf(0.7978845608028654f*(x + 0.044715f*x3)));
}

__device__ __forceinline__ unsigned short f2b(float f) {
  unsigned u = __builtin_bit_cast(unsigned, f);
  u += 0x7fffu + ((u >> 16) & 1u);
  return (unsigned short)(u >> 16);
}

// ---------- split (B,387,N) -> coords (B,N,3), feats (B,N,384) ----------
__global__ __launch_bounds__(256) void split_k(const float* __restrict__ pts,
                                               float* __restrict__ coords,
                                               float* __restrict__ feats) {
  __shared__ float t[32][33];
  int b = blockIdx.z;
  int c0 = blockIdx.x*32, n0 = blockIdx.y*32;
  int tx = threadIdx.x, ty = threadIdx.y;
#pragma unroll
  for (int i = 0; i < 4; ++i) {
    int c = c0 + ty + i*8;
    if (c < 387) t[ty+i*8][tx] = pts[((size_t)b*387 + c)*NN + n0 + tx];
  }
  __syncthreads();
#pragma unroll
  for (int i = 0; i < 4; ++i) {
    int n = n0 + ty + i*8;
    int c = c0 + tx;
    if (c < 387) {
      float v = t[tx][ty+i*8];
      if (c < 3) coords[((size_t)b*NN + n)*3 + c] = v;
      else       feats[((size_t)b*NN + n)*DD + (c-3)] = v;
    }
  }
}

// ---------- pack coords+feats -> (B,387,N) ----------
__global__ __launch_bounds__(256) void pack_k(const float* __restrict__ coords,
                                              const float* __restrict__ feats,
                                              float* __restrict__ out) {
  __shared__ float t[32][33];
  int b = blockIdx.z;
  int c0 = blockIdx.x*32, n0 = blockIdx.y*32;
  int tx = threadIdx.x, ty = threadIdx.y;
#pragma unroll
  for (int i = 0; i < 4; ++i) {
    int n = n0 + ty + i*8;
    int c = c0 + tx;
    if (c < 387) {
      float v = (c < 3) ? coords[((size_t)b*NN + n)*3 + c]
                        : feats[((size_t)b*NN + n)*DD + (c-3)];
      t[tx][ty+i*8] = v;
    }
  }
  __syncthreads();
#pragma unroll
  for (int i = 0; i < 4; ++i) {
    int c = c0 + ty + i*8;
    if (c < 387) out[((size_t)b*387 + c)*NN + n0 + tx] = t[ty+i*8][tx];
  }
}

// ---------- LayerNorm over last dim (384), bf16 out ----------
__global__ __launch_bounds__(256) void ln_k(const float* __restrict__ x,
                                            const float* __restrict__ g,
                                            const float* __restrict__ bb,
                                            unsigned short* __restrict__ o) {
  int lane = threadIdx.x & 63;
  int row = blockIdx.x*4 + (threadIdx.x >> 6);
  const float* xr = x + (size_t)row*DD;
  float v[6]; float s = 0.f;
#pragma unroll
  for (int i = 0; i < 6; ++i) { v[i] = xr[lane + i*64]; s += v[i]; }
#pragma unroll
  for (int off = 1; off < 64; off <<= 1) s += __shfl_xor(s, off);
  float mean = s * (1.f/384.f);
  float s2 = 0.f;
#pragma unroll
  for (int i = 0; i < 6; ++i) { float d = v[i] - mean; s2 += d*d; }
#pragma unroll
  for (int off = 1; off < 64; off <<= 1) s2 += __shfl_xor(s2, off);
  float rs = rsqrtf(s2*(1.f/384.f) + 1e-5f);
  unsigned short* orow = o + (size_t)row*DD;
#pragma unroll
  for (int i = 0; i < 6; ++i) {
    int c = lane + i*64;
    orow[c] = f2b((v[i]-mean)*rs*g[c] + bb[c]);
  }
}

// ---------- one-shot weight transpose+convert: Wt[n][k] = W[k][n] (bf16) ----------
struct WSrcs { const float* p[13]; };

__global__ __launch_bounds__(256) void wtrans_k(WSrcs srcs, unsigned short* __restrict__ dst) {
  constexpr int KK[13]  = {384,384,384,384,768,384,384,384,384,384,768,384,768};
  constexpr int NW[13]  = {1152,384,384,384,384,384,384,384,384,384,384,768,384};
  constexpr int MD[13]  = {0,0,0,2,0,0,0,0,0,2,0,0,0};  // 2 = rows[384:768]-rows[0:384]
  constexpr int OFF[13] = {0,442368,589824,737280,884736,1179648,1327104,1474560,
                           1622016,1769472,1916928,2211840,2506752};
  constexpr int PFX[14] = {0,432,576,720,864,1152,1296,1440,1584,1728,1872,2160,2448,2736};
  int bid = blockIdx.x;
  int e = 0;
  while (bid >= PFX[e+1]) ++e;
  int t = bid - PFX[e];
  int K = KK[e], N = NW[e];
  int ntiles = N >> 5;
  int kt = t / ntiles, nt = t - kt*ntiles;
  const float* src = srcs.p[e];
  __shared__ float T[32][33];
  int tx = threadIdx.x & 31, ty = threadIdx.x >> 5;
  int n = nt*32 + tx;
#pragma unroll
  for (int i = 0; i < 4; ++i) {
    int k = kt*32 + ty + i*8;
    float v = src[(size_t)k*N + n];
    if (MD[e] == 2) v = src[(size_t)(k+384)*N + n] - v;
    T[ty+i*8][tx] = v;
  }
  __syncthreads();
#pragma unroll
  for (int i = 0; i < 4; ++i) {
    int nn = nt*32 + ty + i*8;
    int kk = kt*32 + tx;
    dst[(size_t)OFF[e] + (size_t)nn*K + kk] = f2b(T[tx][ty+i*8]);
  }
}

// ---------- MFMA bf16 GEMM: C[M x N] = act(A @ W + bias) (+C) ----------
template<int ACT, int ACC, int OB>
__global__ __launch_bounds__(256) void mgemm_k(const unsigned short* __restrict__ A, int lda,
                                               const unsigned short* __restrict__ Wt,
                                               const float* __restrict__ bias,
                                               void* __restrict__ Cv, int ldc, int cofs,
                                               int Kd) {
  __shared__ char lds[24576];           // As[128][128B] | Bs[64][128B]
  char* As = lds;
  char* Bs = lds + 16384;
  int tid = threadIdx.x;
  int lane = tid & 63, w = tid >> 6, g = lane >> 4, c = lane & 15;
  int wr = w >> 1, wc = w & 1;
  int m0 = blockIdx.y*128, n0 = blockIdx.x*64;

  f32x4 acc[4][2];
#pragma unroll
  for (int mt = 0; mt < 4; ++mt)
#pragma unroll
    for (int nt = 0; nt < 2; ++nt) acc[mt][nt] = 0.f;

  int KT = Kd >> 6;
  bf16x8 rA[4], rB[2];
#pragma unroll
  for (int it = 0; it < 4; ++it) {
    int p = it*256 + tid; int row = p >> 3, ch = p & 7;
    rA[it] = *(const bf16x8*)(A + (size_t)(m0+row)*lda + ch*8);
  }
#pragma unroll
  for (int it = 0; it < 2; ++it) {
    int p = it*256 + tid; int row = p >> 3, ch = p & 7;
    rB[it] = *(const bf16x8*)(Wt + (size_t)(n0+row)*Kd + ch*8);
  }

  for (int kt = 0; kt < KT; ++kt) {
    __syncthreads();
#pragma unroll
    for (int it = 0; it < 4; ++it) {
      int p = it*256 + tid; int row = p >> 3, ch = p & 7;
      *(bf16x8*)(As + row*128 + ((ch ^ (row & 7))*16)) = rA[it];
    }
#pragma unroll
    for (int it = 0; it < 2; ++it) {
      int p = it*256 + tid; int row = p >> 3, ch = p & 7;
      *(bf16x8*)(Bs + row*128 + ((ch ^ (row & 7))*16)) = rB[it];
    }
    if (kt + 1 < KT) {
      int k0 = (kt+1)*64;
#pragma unroll
      for (int it = 0; it < 4; ++it) {
        int p = it*256 + tid; int row = p >> 3, ch = p & 7;
        rA[it] = *(const bf16x8*)(A + (size_t)(m0+row)*lda + k0 + ch*8);
      }
#pragma unroll
      for (int it = 0; it < 2; ++it) {
        int p = it*256 + tid; int row = p >> 3, ch = p & 7;
        rB[it] = *(const bf16x8*)(Wt + (size_t)(n0+row)*Kd + k0 + ch*8);
      }
    }
    __syncthreads();
#pragma unroll
    for (int kb = 0; kb < 2; ++kb) {
      bf16x8 af[4], bfr[2];
#pragma unroll
      for (int mt = 0; mt < 4; ++mt) {
        int row = wr*64 + mt*16 + c;
        int ch = (kb*4 + g) ^ (row & 7);
        af[mt] = *(const bf16x8*)(As + row*128 + ch*16);
      }
#pragma unroll
      for (int nt = 0; nt < 2; ++nt) {
        int row = wc*32 + nt*16 + c;
        int ch = (kb*4 + g) ^ (row & 7);
        bfr[nt] = *(const bf16x8*)(Bs + row*128 + ch*16);
      }
#pragma unroll
      for (int mt = 0; mt < 4; ++mt)
#pragma unroll
        for (int nt = 0; nt < 2; ++nt)
          acc[mt][nt] = __builtin_amdgcn_mfma_f32_16x16x32_bf16(af[mt], bfr[nt], acc[mt][nt], 0, 0, 0);
    }
  }

#pragma unroll
  for (int mt = 0; mt < 4; ++mt) {
#pragma unroll
    for (int nt = 0; nt < 2; ++nt) {
      int coln = n0 + wc*32 + nt*16 + c;
      float bval = bias ? bias[coln] : 0.f;
#pragma unroll
      for (int r = 0; r < 4; ++r) {
        int m = m0 + wr*64 + mt*16 + 4*g + r;
        float t = acc[mt][nt][r] + bval;
        if (ACT == 1) t = gelu_t(t);
        if (OB) {
          ((unsigned short*)Cv)[(size_t)m*ldc + cofs + coln] = f2b(t);
        } else {
          float* cp = (float*)Cv + (size_t)m*ldc + cofs + coln;
          if (ACC) t += *cp;
          *cp = t;
        }
      }
    }
  }
}

// ---------- V transpose: qkvb V cols -> vt[(b*6+h)*64 + d][2048 keys] (bf16) ----------
__global__ __launch_bounds__(256) void vtrans_k(const unsigned short* __restrict__ qkvb,
                                                unsigned short* __restrict__ vt) {
  __shared__ unsigned short T[4096];
  int bh = blockIdx.y; int b = bh / NH, h = bh % NH;
  int t0 = blockIdx.x*64;
  int tid = threadIdx.x;
#pragma unroll
  for (int p = 0; p < 2; ++p) {
    int row = p*32 + (tid >> 3);
    int ch  = tid & 7;
    bf16x8 v = *(const bf16x8*)(qkvb + ((size_t)(b*NN + t0 + row))*1152 + 768 + h*64 + ch*8);
    *(bf16x8*)&T[row*64 + ((ch ^ (row & 7))*8)] = v;
  }
  __syncthreads();
#pragma unroll
  for (int p = 0; p < 2; ++p) {
    int d  = p*32 + (tid >> 3);
    int kc = tid & 7;
    bf16x8 v;
#pragma unroll
    for (int e = 0; e < 8; ++e) {
      int tok = kc*8 + e;
      v[e] = (short)T[tok*64 + (((d >> 3) ^ (tok & 7))*8) + (d & 7)];
    }
    *(bf16x8*)(vt + (((size_t)bh*64 + d)*NN) + t0 + kc*8) = v;
  }
}

// ---------- MFMA flash attention, swapped-operand, fixed-shift softmax ----------
// grid (NN/64, H, B), 4 waves; wave w owns q rows w*16..w*16+15 (q = lane&15).
// QK^T: sT[nt] = mfma(A=K, B=Q) -> col=q(c), row=key(4g+r) per 16-key block nt.
// PV:   oacc[dt] = mfma(A=V^T, B=P^T) -> col=q(c), row=d(4g+r) per 16-d block dt.
__global__ __launch_bounds__(256) void flashm_k(const unsigned short* __restrict__ qkvb,
                                                const unsigned short* __restrict__ vt,
                                                unsigned short* __restrict__ o) {
  __shared__ char smem[24576];   // KT [64 key][128B d] | VT2 [64 d][128B key] | PT [64 q][128B key]
  char* KT  = smem;
  char* VT2 = smem + 8192;
  char* PT  = smem + 16384;
  int b = blockIdx.z, h = blockIdx.y, q0 = blockIdx.x*64;
  int tid = threadIdx.x;
  int w = tid >> 6, lane = tid & 63, g = lane >> 4, c = lane & 15;

  bf16x8 qf[2];
  {
    const unsigned short* qrow = qkvb + ((size_t)(b*NN + q0 + w*16 + c))*1152 + h*64;
    qf[0] = *(const bf16x8*)(qrow + 8*g);
    qf[1] = *(const bf16x8*)(qrow + 32 + 8*g);
  }
  f32x4 oacc[4];
#pragma unroll
  for (int i = 0; i < 4; ++i) oacc[i] = 0.f;
  float lsum = 0.f;

  int srow = lane >> 3;          // 0..7
  int scol = (lane & 7)*16;      // byte chunk in 128B row
  int r0 = w*16 + srow, r1 = w*16 + 8 + srow;
  int cb0 = scol ^ ((r0 & 7) << 4);
  int cb1 = scol ^ ((r1 & 7) << 4);

  const unsigned short* kbase = qkvb + (size_t)b*NN*1152 + 384 + h*64;
  const unsigned short* vbase = vt + ((size_t)(b*NH + h))*64*NN;

  bf16x8 kreg[2], vreg[2];
  kreg[0] = *(const bf16x8*)(kbase + (size_t)r0*1152 + (scol >> 1));
  kreg[1] = *(const bf16x8*)(kbase + (size_t)r1*1152 + (scol >> 1));
  vreg[0] = *(const bf16x8*)(vbase + (size_t)r0*NN + (scol >> 1));
  vreg[1] = *(const bf16x8*)(vbase + (size_t)r1*NN + (scol >> 1));

  for (int kt = 0; kt < 32; ++kt) {
    __syncthreads();             // prev tile's MFMA reads done
    *(bf16x8*)(KT  + r0*128 + cb0) = kreg[0];
    *(bf16x8*)(KT  + r1*128 + cb1) = kreg[1];
    *(bf16x8*)(VT2 + r0*128 + cb0) = vreg[0];
    *(bf16x8*)(VT2 + r1*128 + cb1) = vreg[1];
    if (kt + 1 < 32) {           // prefetch next tile (hides HBM under compute)
      int kn = kt + 1;
      kreg[0] = *(const bf16x8*)(kbase + (size_t)(kn*64 + r0)*1152 + (scol >> 1));
      kreg[1] = *(const bf16x8*)(kbase + (size_t)(kn*64 + r1)*1152 + (scol >> 1));
      vreg[0] = *(const bf16x8*)(vbase + (size_t)r0*NN + kn*64 + (scol >> 1));
      vreg[1] = *(const bf16x8*)(vbase + (size_t)r1*NN + kn*64 + (scol >> 1));
    }
    __syncthreads();             // tiles visible

    // S^T = K Q^T
    f32x4 sT[4];
#pragma unroll
    for (int nt = 0; nt < 4; ++nt) sT[nt] = 0.f;
#pragma unroll
    for (int nt = 0; nt < 4; ++nt) {
      int krow = nt*16 + c;
#pragma unroll
      for (int kb = 0; kb < 2; ++kb) {
        int ch = ((kb*4 + g) ^ (krow & 7))*16;
        bf16x8 kf_ = *(const bf16x8*)(KT + krow*128 + ch);
        sT[nt] = __builtin_amdgcn_mfma_f32_16x16x32_bf16(kf_, qf[kb], sT[nt], 0, 0, 0);
      }
    }

    // p = 2^(s * 0.125*log2e)  (fixed-shift softmax; |s| < ~1 for this model)
    int prow = w*16 + c;
    int pswz = (c & 7) << 4;
#pragma unroll
    for (int nt = 0; nt < 4; ++nt) {
      float p0 = __builtin_amdgcn_exp2f(sT[nt][0] * 0.18033688011112042f);
      float p1 = __builtin_amdgcn_exp2f(sT[nt][1] * 0.18033688011112042f);
      float p2 = __builtin_amdgcn_exp2f(sT[nt][2] * 0.18033688011112042f);
      float p3 = __builtin_amdgcn_exp2f(sT[nt][3] * 0.18033688011112042f);
      lsum += (p0 + p1) + (p2 + p3);
      s4v pk;
      pk[0] = (short)f2b(p0); pk[1] = (short)f2b(p1);
      pk[2] = (short)f2b(p2); pk[3] = (short)f2b(p3);
      *(s4v*)(PT + prow*128 + ((nt*32 + 8*g) ^ pswz)) = pk;   // keys nt*16+4g..+3, row q
    }

    // P^T B-frags (wave-private rows; lgkm dependency tracked by compiler)
    bf16x8 pb[2];
#pragma unroll
    for (int kb = 0; kb < 2; ++kb)
      pb[kb] = *(const bf16x8*)(PT + prow*128 + (((kb*4 + g) ^ (c & 7))*16));

    // O^T += V^T P^T
#pragma unroll
    for (int dt = 0; dt < 4; ++dt) {
      int vrow = dt*16 + c;
#pragma unroll
      for (int kb = 0; kb < 2; ++kb) {
        int ch = ((kb*4 + g) ^ (vrow & 7))*16;
        bf16x8 vf = *(const bf16x8*)(VT2 + vrow*128 + ch);
        oacc[dt] = __builtin_amdgcn_mfma_f32_16x16x32_bf16(vf, pb[kb], oacc[dt], 0, 0, 0);
      }
    }
  }

  lsum += __shfl_xor(lsum, 16);
  lsum += __shfl_xor(lsum, 32);
  float inv = 1.f / lsum;
  size_t orow = ((size_t)b*NN + q0 + w*16 + c)*DD + h*64;
#pragma unroll
  for (int dt = 0; dt < 4; ++dt) {
    s4v ov;
#pragma unroll
    for (int r = 0; r < 4; ++r) ov[r] = (short)f2b(oacc[dt][r]*inv);
    *(s4v*)(o + orow + dt*16 + 4*g) = ov;
  }
}

// ---------- KNN top-8 by squared distance, one wave per query ----------
__global__ __launch_bounds__(256) void knn_k(const float* __restrict__ qc,
                                             const float* __restrict__ kc,
                                             int* __restrict__ idx) {
  int lane = threadIdx.x & 63;
  int q = blockIdx.x*4 + (threadIdx.x >> 6);
  int b = q >> 11, n = q & 2047;
  const float* qp = qc + ((size_t)b*NN + n)*3;
  float qx = qp[0], qy = qp[1], qz = qp[2];
  float qq = qx*qx + qy*qy + qz*qz;
  float bd[8]; int bi[8];
#pragma unroll
  for (int i = 0; i < 8; ++i) { bd[i] = INFINITY; bi[i] = 0x7fffffff; }
  const float* kb = kc + (size_t)b*NN*3;
  for (int j = lane; j < NN; j += 64) {
    float kx = kb[(size_t)j*3], ky = kb[(size_t)j*3+1], kz = kb[(size_t)j*3+2];
    float dt = qx*kx + qy*ky + qz*kz;
    float kk = kx*kx + ky*ky + kz*kz;
    float d2 = qq + kk - 2.f*dt;
    if (d2 < bd[7]) {
      float nd = d2; int ni = j;
#pragma unroll
      for (int k = 0; k < 8; ++k) {
        bool sw = (nd < bd[k]) || (nd == bd[k] && ni < bi[k]);
        float td = sw ? bd[k] : nd;
        int   ti = sw ? bi[k] : ni;
        if (sw) { bd[k] = nd; bi[k] = ni; }
        nd = td; ni = ti;
      }
    }
  }
  int res[8];
#pragma unroll
  for (int r = 0; r < 8; ++r) {
    float cd = bd[0]; int ci = bi[0];
#pragma unroll
    for (int off = 32; off >= 1; off >>= 1) {
      float od = __shfl_xor(cd, off);
      int oi = __shfl_xor(ci, off);
      if (od < cd || (od == cd && oi < ci)) { cd = od; ci = oi; }
    }
    res[r] = ci;
    if (ci == bi[0]) {
#pragma unroll
      for (int k = 0; k < 7; ++k) { bd[k] = bd[k+1]; bi[k] = bi[k+1]; }
      bd[7] = INFINITY; bi[7] = 0x7fffffff;
    }
  }
  if (lane == 0) {
#pragma unroll
    for (int r = 0; r < 8; ++r) idx[(size_t)q*8 + r] = res[r];
  }
}

// ---------- geom = max_k lrelu(G[idx_k] + C), bf16 into attnG[:,384:768] ----------
__global__ __launch_bounds__(384) void geom_k(const float* __restrict__ G,
                                              const float* __restrict__ Cb,
                                              const int* __restrict__ idx,
                                              unsigned short* __restrict__ out) {
  int q = blockIdx.x;
  int b = q >> 11;
  int d = threadIdx.x;
  float c = Cb[(size_t)q*DD + d];
  float mx = -INFINITY;
#pragma unroll
  for (int kn = 0; kn < 8; ++kn) {
    int j = idx[(size_t)q*8 + kn];
    float gg = G[((size_t)b*NN + j)*DD + d];
    float y = gg + c;
    y = (y > 0.f) ? y : 0.2f*y;
    mx = fmaxf(mx, y);
  }
  out[(size_t)q*768 + 384 + d] = f2b(mx);
}

extern "C" void kernel_launch(void* const* d_in, const int* in_sizes, int n_in,
                              void* d_out, int out_size, void* d_ws, size_t ws_size,
                              hipStream_t stream) {
  (void)in_sizes; (void)n_in; (void)out_size; (void)ws_size;
  const float* qpts  = (const float*)d_in[0];
  const float* kpts  = (const float*)d_in[1];
  const float* ln_s  = (const float*)d_in[2];
  const float* ln_b  = (const float*)d_in[3];
  const float* qkvW  = (const float*)d_in[4];
  const float* Wo    = (const float*)d_in[5];
  const float* bo    = (const float*)d_in[6];
  const float* ffW1  = (const float*)d_in[7];
  const float* ffb1  = (const float*)d_in[8];
  const float* ffW2  = (const float*)d_in[9];
  const float* ffb2  = (const float*)d_in[10];
  const float* ffns  = (const float*)d_in[11];
  const float* ffnb  = (const float*)d_in[12];
  const float* knn1W = (const float*)d_in[13];
  const float* knn1b = (const float*)d_in[14];
  const float* knn2W = (const float*)d_in[15];
  const float* knn2b = (const float*)d_in[16];
  const float* smW   = (const float*)d_in[17];
  const float* smb   = (const float*)d_in[18];
  const float* cmW   = (const float*)d_in[19];
  const float* cmb   = (const float*)d_in[20];
  const float* cnqs  = (const float*)d_in[21];
  const float* cnqb  = (const float*)d_in[22];
  const float* cnks  = (const float*)d_in[23];
  const float* cnkb  = (const float*)d_in[24];
  const float* cqW   = (const float*)d_in[25];
  const float* ckW   = (const float*)d_in[26];
  const float* cvW   = (const float*)d_in[27];

  float* ws = (float*)d_ws;
  float* qc   = ws;                       // 4*2048*3
  float* kc   = qc  + 24576;
  float* qf   = kc  + 24576;              // 8192*384 f32 (residual stream)
  float* kf   = qf  + 3145728;
  unsigned short* nrmb = (unsigned short*)(kf + 3145728);   // bf16 LN out
  unsigned short* nkb  = (unsigned short*)(kf + 3145728 + 3145728);
  float* qkv  = kf + 3145728 + 3145728 + 3145728;           // 9437184-float region
  unsigned short* qkvb  = (unsigned short*)qkv;             // 8192*1152 bf16
  unsigned short* attnGb= (unsigned short*)qkv;             // 8192*768 bf16 (aliases)
  unsigned short* vtb   = (unsigned short*)(qkv + 6291456); // 24*64*2048 bf16
  unsigned short* wtb   = (unsigned short*)(qkv + 7864320); // 2801664 bf16 weights
  float* attnO = qkv + 9437184;           // 8192*384 region
  unsigned short* attnOb = (unsigned short*)attnO;
  float* G    = attnO;
  float* Cb   = attnO + 3145728;
  int*   idx  = (int*)(Cb + 3145728);     // 8192*8

  const int W_QKV=0, W_WO=442368, W_K1T=589824, W_WD1=737280, W_SM=884736,
            W_CQ=1179648, W_CK=1327104, W_CV=1474560, W_K2T=1622016,
            W_WD2=1769472, W_CM=1916928, W_FF1=2211840, W_FF2=2506752;

  WSrcs srcs;
  srcs.p[0]=qkvW; srcs.p[1]=Wo; srcs.p[2]=knn1W; srcs.p[3]=knn1W; srcs.p[4]=smW;
  srcs.p[5]=cqW; srcs.p[6]=ckW; srcs.p[7]=cvW; srcs.p[8]=knn2W; srcs.p[9]=knn2W;
  srcs.p[10]=cmW; srcs.p[11]=ffW1; srcs.p[12]=ffW2;
  wtrans_k<<<2736, 256, 0, stream>>>(srcs, wtb);

  dim3 tgrid(13, 64, NB), tblk(32, 8);
  split_k<<<tgrid, tblk, 0, stream>>>(qpts, qc, qf);
  split_k<<<tgrid, tblk, 0, stream>>>(kpts, kc, kf);

  dim3 mg384(6, 64), mg768(12, 64), mg1152(18, 64);
  dim3 fgrid(32, NH, NB), vgrid(32, NB*NH);

  // ---- self attention branch ----
  ln_k<<<2048, 256, 0, stream>>>(qf, ln_s, ln_b, nrmb);
  mgemm_k<0,0,1><<<mg1152, 256, 0, stream>>>(nrmb, DD, wtb+W_QKV, nullptr, qkvb, 1152, 0, DD);
  vtrans_k<<<vgrid, 256, 0, stream>>>(qkvb, vtb);
  flashm_k<<<fgrid, 256, 0, stream>>>(qkvb, vtb, attnOb);
  mgemm_k<0,0,1><<<mg384, 256, 0, stream>>>(attnOb, DD, wtb+W_WO, bo, attnGb, 768, 0, DD);
  mgemm_k<0,0,0><<<mg384, 256, 0, stream>>>(nrmb, DD, wtb+W_K1T, nullptr, G, DD, 0, DD);
  mgemm_k<0,0,0><<<mg384, 256, 0, stream>>>(nrmb, DD, wtb+W_WD1, knn1b, Cb, DD, 0, DD);
  knn_k<<<2048, 256, 0, stream>>>(qc, qc, idx);
  geom_k<<<8192, 384, 0, stream>>>(G, Cb, idx, attnGb);
  mgemm_k<0,1,0><<<mg384, 256, 0, stream>>>(attnGb, 768, wtb+W_SM, smb, qf, DD, 0, 768);

  // ---- cross attention branch ----
  ln_k<<<2048, 256, 0, stream>>>(qf, cnqs, cnqb, nrmb);   // nq
  ln_k<<<2048, 256, 0, stream>>>(kf, cnks, cnkb, nkb);    // nk
  mgemm_k<0,0,1><<<mg384, 256, 0, stream>>>(nrmb, DD, wtb+W_CQ, nullptr, qkvb, 1152, 0,   DD);
  mgemm_k<0,0,1><<<mg384, 256, 0, stream>>>(nkb,  DD, wtb+W_CK, nullptr, qkvb, 1152, 384, DD);
  mgemm_k<0,0,1><<<mg384, 256, 0, stream>>>(nkb,  DD, wtb+W_CV, nullptr, qkvb, 1152, 768, DD);
  vtrans_k<<<vgrid, 256, 0, stream>>>(qkvb, vtb);
  flashm_k<<<fgrid, 256, 0, stream>>>(qkvb, vtb, attnOb);
  mgemm_k<0,0,1><<<mg384, 256, 0, stream>>>(attnOb, DD, wtb+W_WO, bo, attnGb, 768, 0, DD);
  mgemm_k<0,0,0><<<mg384, 256, 0, stream>>>(nkb,  DD, wtb+W_K2T, nullptr, G, DD, 0, DD);
  mgemm_k<0,0,0><<<mg384, 256, 0, stream>>>(nrmb, DD, wtb+W_WD2, knn2b, Cb, DD, 0, DD);
  knn_k<<<2048, 256, 0, stream>>>(qc, kc, idx);
  geom_k<<<8192, 384, 0, stream>>>(G, Cb, idx, attnGb);
  mgemm_k<0,1,0><<<mg384, 256, 0, stream>>>(attnGb, 768, wtb+W_CM, cmb, qf, DD, 0, 768);

  // ---- FFN ----
  ln_k<<<2048, 256, 0, stream>>>(qf, ffns, ffnb, nrmb);
  mgemm_k<1,0,1><<<mg768, 256, 0, stream>>>(nrmb, DD, wtb+W_FF1, ffb1, attnGb, 768, 0, DD);
  mgemm_k<0,1,0><<<mg384, 256, 0, stream>>>(attnGb, 768, wtb+W_FF2, ffb2, qf, DD, 0, 768);

  pack_k<<<tgrid, tblk, 0, stream>>>(qc, qf, (float*)d_out);
}

// Round 5
// 461.277 us; speedup vs baseline: 5.3315x; 1.0348x over previous
//
#include <hip/hip_runtime.h>
#include <cstdint>
#include <cstddef>

#define NB 4
#define NN 2048
#define DD 384
#define NH 6

typedef float f4 __attribute__((ext_vector_type(4)));
typedef float f32x4 __attribute__((ext_vector_type(4)));
typedef short bf16x8 __attribute__((ext_vector_type(8)));
typedef short s4v __attribute__((ext_vector_type(4)));

__device__ __forceinline__ float gelu_t(float x) {
  float x3 = x*x*x;
  return 0.5f*x*(1.0f + tanhf(0.7978845608028654f*(x + 0.044715f*x3)));
}

__device__ __forceinline__ unsigned short f2b(float f) {
  unsigned u = __builtin_bit_cast(unsigned, f);
  u += 0x7fffu + ((u >> 16) & 1u);
  return (unsigned short)(u >> 16);
}

__device__ __forceinline__ float b2f(unsigned short u) {
  return __builtin_bit_cast(float, ((unsigned)u) << 16);
}

typedef __attribute__((address_space(1))) const void gvoid_t;
typedef __attribute__((address_space(3))) void lvoid_t;
__device__ __forceinline__ void gl16(const void* g, void* l) {
  __builtin_amdgcn_global_load_lds((gvoid_t*)g, (lvoid_t*)l, 16, 0, 0);
}

// ---------- split (B,387,N) -> coords (B,N,3), feats (B,N,384) ----------
__global__ __launch_bounds__(256) void split_k(const float* __restrict__ pts,
                                               float* __restrict__ coords,
                                               float* __restrict__ feats) {
  __shared__ float t[32][33];
  int b = blockIdx.z;
  int c0 = blockIdx.x*32, n0 = blockIdx.y*32;
  int tx = threadIdx.x, ty = threadIdx.y;
#pragma unroll
  for (int i = 0; i < 4; ++i) {
    int c = c0 + ty + i*8;
    if (c < 387) t[ty+i*8][tx] = pts[((size_t)b*387 + c)*NN + n0 + tx];
  }
  __syncthreads();
#pragma unroll
  for (int i = 0; i < 4; ++i) {
    int n = n0 + ty + i*8;
    int c = c0 + tx;
    if (c < 387) {
      float v = t[tx][ty+i*8];
      if (c < 3) coords[((size_t)b*NN + n)*3 + c] = v;
      else       feats[((size_t)b*NN + n)*DD + (c-3)] = v;
    }
  }
}

// ---------- pack coords+feats -> (B,387,N) ----------
__global__ __launch_bounds__(256) void pack_k(const float* __restrict__ coords,
                                              const float* __restrict__ feats,
                                              float* __restrict__ out) {
  __shared__ float t[32][33];
  int b = blockIdx.z;
  int c0 = blockIdx.x*32, n0 = blockIdx.y*32;
  int tx = threadIdx.x, ty = threadIdx.y;
#pragma unroll
  for (int i = 0; i < 4; ++i) {
    int n = n0 + ty + i*8;
    int c = c0 + tx;
    if (c < 387) {
      float v = (c < 3) ? coords[((size_t)b*NN + n)*3 + c]
                        : feats[((size_t)b*NN + n)*DD + (c-3)];
      t[tx][ty+i*8] = v;
    }
  }
  __syncthreads();
#pragma unroll
  for (int i = 0; i < 4; ++i) {
    int c = c0 + ty + i*8;
    if (c < 387) out[((size_t)b*387 + c)*NN + n0 + tx] = t[ty+i*8][tx];
  }
}

// ---------- LayerNorm over last dim (384), bf16 out ----------
__global__ __launch_bounds__(256) void ln_k(const float* __restrict__ x,
                                            const float* __restrict__ g,
                                            const float* __restrict__ bb,
                                            unsigned short* __restrict__ o) {
  int lane = threadIdx.x & 63;
  int row = blockIdx.x*4 + (threadIdx.x >> 6);
  const float* xr = x + (size_t)row*DD;
  float v[6]; float s = 0.f;
#pragma unroll
  for (int i = 0; i < 6; ++i) { v[i] = xr[lane + i*64]; s += v[i]; }
#pragma unroll
  for (int off = 1; off < 64; off <<= 1) s += __shfl_xor(s, off);
  float mean = s * (1.f/384.f);
  float s2 = 0.f;
#pragma unroll
  for (int i = 0; i < 6; ++i) { float d = v[i] - mean; s2 += d*d; }
#pragma unroll
  for (int off = 1; off < 64; off <<= 1) s2 += __shfl_xor(s2, off);
  float rs = rsqrtf(s2*(1.f/384.f) + 1e-5f);
  unsigned short* orow = o + (size_t)row*DD;
#pragma unroll
  for (int i = 0; i < 6; ++i) {
    int c = lane + i*64;
    orow[c] = f2b((v[i]-mean)*rs*g[c] + bb[c]);
  }
}

// ---------- one-shot weight transpose+convert: Wt[n][k] = W[k][n] (bf16) ----------
struct WSrcs { const float* p[13]; };

__global__ __launch_bounds__(256) void wtrans_k(WSrcs srcs, unsigned short* __restrict__ dst) {
  constexpr int KK[13]  = {384,384,384,384,768,384,384,384,384,384,768,384,768};
  constexpr int NW[13]  = {1152,384,384,384,384,384,384,384,384,384,384,768,384};
  constexpr int MD[13]  = {0,0,0,2,0,0,0,0,0,2,0,0,0};  // 2 = rows[384:768]-rows[0:384]
  constexpr int OFF[13] = {0,442368,589824,737280,884736,1179648,1327104,1474560,
                           1622016,1769472,1916928,2211840,2506752};
  constexpr int PFX[14] = {0,432,576,720,864,1152,1296,1440,1584,1728,1872,2160,2448,2736};
  int bid = blockIdx.x;
  int e = 0;
  while (bid >= PFX[e+1]) ++e;
  int t = bid - PFX[e];
  int K = KK[e], N = NW[e];
  int ntiles = N >> 5;
  int kt = t / ntiles, nt = t - kt*ntiles;
  const float* src = srcs.p[e];
  __shared__ float T[32][33];
  int tx = threadIdx.x & 31, ty = threadIdx.x >> 5;
  int n = nt*32 + tx;
#pragma unroll
  for (int i = 0; i < 4; ++i) {
    int k = kt*32 + ty + i*8;
    float v = src[(size_t)k*N + n];
    if (MD[e] == 2) v = src[(size_t)(k+384)*N + n] - v;
    T[ty+i*8][tx] = v;
  }
  __syncthreads();
#pragma unroll
  for (int i = 0; i < 4; ++i) {
    int nn = nt*32 + ty + i*8;
    int kk = kt*32 + tx;
    dst[(size_t)OFF[e] + (size_t)nn*K + kk] = f2b(T[tx][ty+i*8]);
  }
}

// ---------- MFMA bf16 GEMM with global_load_lds staging ----------
// A: [M][lda] bf16. Wt: [N][Kd] bf16 (pre-transposed). BM=128 BN=64 BK=64.
// LDS linear per-row 128B; swizzle applied on the GLOBAL source column (m173).
template<int ACT, int ACC, int OB>
__global__ __launch_bounds__(256) void mgemm_k(const unsigned short* __restrict__ A, int lda,
                                               const unsigned short* __restrict__ Wt,
                                               const float* __restrict__ bias,
                                               void* __restrict__ Cv, int ldc, int cofs,
                                               int Kd) {
  __shared__ char lds[24576];           // As[128][128B] | Bs[64][128B]
  char* As = lds;
  char* Bs = lds + 16384;
  int tid = threadIdx.x;
  int lane = tid & 63, w = tid >> 6, g = lane >> 4, c = lane & 15;
  int wr = w >> 1, wc = w & 1;
  int m0 = blockIdx.y*128, n0 = blockIdx.x*64;
  int lrow = lane >> 3;                       // 0..7 (row within 8-row granule)
  int cswz = ((lane & 7) ^ lrow)*8;           // pre-swizzled global column (bf16 elems)

  f32x4 acc[4][2];
#pragma unroll
  for (int mt = 0; mt < 4; ++mt)
#pragma unroll
    for (int nt = 0; nt < 2; ++nt) acc[mt][nt] = 0.f;

  int KT = Kd >> 6;
  for (int kt = 0; kt < KT; ++kt) {
    int k0 = kt*64;
    __syncthreads();                          // prev compute done (LDS free)
#pragma unroll
    for (int i = 0; i < 4; ++i) {
      int rbase = i*32 + w*8;                 // wave-uniform granule base row
      gl16(A + (size_t)(m0 + rbase + lrow)*lda + k0 + cswz, As + rbase*128);
    }
#pragma unroll
    for (int i = 0; i < 2; ++i) {
      int rbase = i*32 + w*8;
      gl16(Wt + (size_t)(n0 + rbase + lrow)*Kd + k0 + cswz, Bs + rbase*128);
    }
    __syncthreads();                          // drains vmcnt -> tiles visible
#pragma unroll
    for (int kb = 0; kb < 2; ++kb) {
      bf16x8 af[4], bfr[2];
#pragma unroll
      for (int mt = 0; mt < 4; ++mt) {
        int row = wr*64 + mt*16 + c;
        int ch = (kb*4 + g) ^ (row & 7);
        af[mt] = *(const bf16x8*)(As + row*128 + ch*16);
      }
#pragma unroll
      for (int nt = 0; nt < 2; ++nt) {
        int row = wc*32 + nt*16 + c;
        int ch = (kb*4 + g) ^ (row & 7);
        bfr[nt] = *(const bf16x8*)(Bs + row*128 + ch*16);
      }
#pragma unroll
      for (int mt = 0; mt < 4; ++mt)
#pragma unroll
        for (int nt = 0; nt < 2; ++nt)
          acc[mt][nt] = __builtin_amdgcn_mfma_f32_16x16x32_bf16(af[mt], bfr[nt], acc[mt][nt], 0, 0, 0);
    }
  }

#pragma unroll
  for (int mt = 0; mt < 4; ++mt) {
#pragma unroll
    for (int nt = 0; nt < 2; ++nt) {
      int coln = n0 + wc*32 + nt*16 + c;
      float bval = bias ? bias[coln] : 0.f;
#pragma unroll
      for (int r = 0; r < 4; ++r) {
        int m = m0 + wr*64 + mt*16 + 4*g + r;
        float t = acc[mt][nt][r] + bval;
        if (ACT == 1) t = gelu_t(t);
        if (OB) {
          ((unsigned short*)Cv)[(size_t)m*ldc + cofs + coln] = f2b(t);
        } else {
          float* cp = (float*)Cv + (size_t)m*ldc + cofs + coln;
          if (ACC) t += *cp;
          *cp = t;
        }
      }
    }
  }
}

// ---------- V transpose: qkvb V cols -> vt[(b*6+h)*64 + d][2048 keys] (bf16) ----------
__global__ __launch_bounds__(256) void vtrans_k(const unsigned short* __restrict__ qkvb,
                                                unsigned short* __restrict__ vt) {
  __shared__ unsigned short T[4096];
  int bh = blockIdx.y; int b = bh / NH, h = bh % NH;
  int t0 = blockIdx.x*64;
  int tid = threadIdx.x;
#pragma unroll
  for (int p = 0; p < 2; ++p) {
    int row = p*32 + (tid >> 3);
    int ch  = tid & 7;
    bf16x8 v = *(const bf16x8*)(qkvb + ((size_t)(b*NN + t0 + row))*1152 + 768 + h*64 + ch*8);
    *(bf16x8*)&T[row*64 + ((ch ^ (row & 7))*8)] = v;
  }
  __syncthreads();
#pragma unroll
  for (int p = 0; p < 2; ++p) {
    int d  = p*32 + (tid >> 3);
    int kc = tid & 7;
    bf16x8 v;
#pragma unroll
    for (int e = 0; e < 8; ++e) {
      int tok = kc*8 + e;
      v[e] = (short)T[tok*64 + (((d >> 3) ^ (tok & 7))*8) + (d & 7)];
    }
    *(bf16x8*)(vt + (((size_t)bh*64 + d)*NN) + t0 + kc*8) = v;
  }
}

// ---------- MFMA flash attention, swapped-operand, fixed-shift softmax ----------
__global__ __launch_bounds__(256) void flashm_k(const unsigned short* __restrict__ qkvb,
                                                const unsigned short* __restrict__ vt,
                                                unsigned short* __restrict__ o) {
  __shared__ char smem[24576];   // KT [64 key][128B d] | VT2 [64 d][128B key] | PT [64 q][128B key]
  char* KT  = smem;
  char* VT2 = smem + 8192;
  char* PT  = smem + 16384;
  int b = blockIdx.z, h = blockIdx.y, q0 = blockIdx.x*64;
  int tid = threadIdx.x;
  int w = tid >> 6, lane = tid & 63, g = lane >> 4, c = lane & 15;

  bf16x8 qf[2];
  {
    const unsigned short* qrow = qkvb + ((size_t)(b*NN + q0 + w*16 + c))*1152 + h*64;
    qf[0] = *(const bf16x8*)(qrow + 8*g);
    qf[1] = *(const bf16x8*)(qrow + 32 + 8*g);
  }
  f32x4 oacc[4];
#pragma unroll
  for (int i = 0; i < 4; ++i) oacc[i] = 0.f;
  float lsum = 0.f;

  int srow = lane >> 3;
  int scol = (lane & 7)*16;
  int r0 = w*16 + srow, r1 = w*16 + 8 + srow;
  int cb0 = scol ^ ((r0 & 7) << 4);
  int cb1 = scol ^ ((r1 & 7) << 4);

  const unsigned short* kbase = qkvb + (size_t)b*NN*1152 + 384 + h*64;
  const unsigned short* vbase = vt + ((size_t)(b*NH + h))*64*NN;

  bf16x8 kreg[2], vreg[2];
  kreg[0] = *(const bf16x8*)(kbase + (size_t)r0*1152 + (scol >> 1));
  kreg[1] = *(const bf16x8*)(kbase + (size_t)r1*1152 + (scol >> 1));
  vreg[0] = *(const bf16x8*)(vbase + (size_t)r0*NN + (scol >> 1));
  vreg[1] = *(const bf16x8*)(vbase + (size_t)r1*NN + (scol >> 1));

  for (int kt = 0; kt < 32; ++kt) {
    __syncthreads();
    *(bf16x8*)(KT  + r0*128 + cb0) = kreg[0];
    *(bf16x8*)(KT  + r1*128 + cb1) = kreg[1];
    *(bf16x8*)(VT2 + r0*128 + cb0) = vreg[0];
    *(bf16x8*)(VT2 + r1*128 + cb1) = vreg[1];
    if (kt + 1 < 32) {
      int kn = kt + 1;
      kreg[0] = *(const bf16x8*)(kbase + (size_t)(kn*64 + r0)*1152 + (scol >> 1));
      kreg[1] = *(const bf16x8*)(kbase + (size_t)(kn*64 + r1)*1152 + (scol >> 1));
      vreg[0] = *(const bf16x8*)(vbase + (size_t)r0*NN + kn*64 + (scol >> 1));
      vreg[1] = *(const bf16x8*)(vbase + (size_t)r1*NN + kn*64 + (scol >> 1));
    }
    __syncthreads();

    // S^T = K Q^T
    f32x4 sT[4];
#pragma unroll
    for (int nt = 0; nt < 4; ++nt) sT[nt] = 0.f;
#pragma unroll
    for (int nt = 0; nt < 4; ++nt) {
      int krow = nt*16 + c;
#pragma unroll
      for (int kb = 0; kb < 2; ++kb) {
        int ch = ((kb*4 + g) ^ (krow & 7))*16;
        bf16x8 kf_ = *(const bf16x8*)(KT + krow*128 + ch);
        sT[nt] = __builtin_amdgcn_mfma_f32_16x16x32_bf16(kf_, qf[kb], sT[nt], 0, 0, 0);
      }
    }

    int prow = w*16 + c;
    int pswz = (c & 7) << 4;
#pragma unroll
    for (int nt = 0; nt < 4; ++nt) {
      float p0 = __builtin_amdgcn_exp2f(sT[nt][0] * 0.18033688011112042f);
      float p1 = __builtin_amdgcn_exp2f(sT[nt][1] * 0.18033688011112042f);
      float p2 = __builtin_amdgcn_exp2f(sT[nt][2] * 0.18033688011112042f);
      float p3 = __builtin_amdgcn_exp2f(sT[nt][3] * 0.18033688011112042f);
      lsum += (p0 + p1) + (p2 + p3);
      s4v pk;
      pk[0] = (short)f2b(p0); pk[1] = (short)f2b(p1);
      pk[2] = (short)f2b(p2); pk[3] = (short)f2b(p3);
      *(s4v*)(PT + prow*128 + ((nt*32 + 8*g) ^ pswz)) = pk;
    }

    bf16x8 pb[2];
#pragma unroll
    for (int kb = 0; kb < 2; ++kb)
      pb[kb] = *(const bf16x8*)(PT + prow*128 + (((kb*4 + g) ^ (c & 7))*16));

#pragma unroll
    for (int dt = 0; dt < 4; ++dt) {
      int vrow = dt*16 + c;
#pragma unroll
      for (int kb = 0; kb < 2; ++kb) {
        int ch = ((kb*4 + g) ^ (vrow & 7))*16;
        bf16x8 vf = *(const bf16x8*)(VT2 + vrow*128 + ch);
        oacc[dt] = __builtin_amdgcn_mfma_f32_16x16x32_bf16(vf, pb[kb], oacc[dt], 0, 0, 0);
      }
    }
  }

  lsum += __shfl_xor(lsum, 16);
  lsum += __shfl_xor(lsum, 32);
  float inv = 1.f / lsum;
  size_t orow = ((size_t)b*NN + q0 + w*16 + c)*DD + h*64;
#pragma unroll
  for (int dt = 0; dt < 4; ++dt) {
    s4v ov;
#pragma unroll
    for (int r = 0; r < 4; ++r) ov[r] = (short)f2b(oacc[dt][r]*inv);
    *(s4v*)(o + orow + dt*16 + 4*g) = ov;
  }
}

// ---------- KNN top-8 by squared distance, one wave per query ----------
__global__ __launch_bounds__(256) void knn_k(const float* __restrict__ qc,
                                             const float* __restrict__ kc,
                                             int* __restrict__ idx) {
  int lane = threadIdx.x & 63;
  int q = blockIdx.x*4 + (threadIdx.x >> 6);
  int b = q >> 11, n = q & 2047;
  const float* qp = qc + ((size_t)b*NN + n)*3;
  float qx = qp[0], qy = qp[1], qz = qp[2];
  float qq = qx*qx + qy*qy + qz*qz;
  float bd[8]; int bi[8];
#pragma unroll
  for (int i = 0; i < 8; ++i) { bd[i] = INFINITY; bi[i] = 0x7fffffff; }
  const float* kb = kc + (size_t)b*NN*3;
  for (int j = lane; j < NN; j += 64) {
    float kx = kb[(size_t)j*3], ky = kb[(size_t)j*3+1], kz = kb[(size_t)j*3+2];
    float dt = qx*kx + qy*ky + qz*kz;
    float kk = kx*kx + ky*ky + kz*kz;
    float d2 = qq + kk - 2.f*dt;
    if (d2 < bd[7]) {
      float nd = d2; int ni = j;
#pragma unroll
      for (int k = 0; k < 8; ++k) {
        bool sw = (nd < bd[k]) || (nd == bd[k] && ni < bi[k]);
        float td = sw ? bd[k] : nd;
        int   ti = sw ? bi[k] : ni;
        if (sw) { bd[k] = nd; bi[k] = ni; }
        nd = td; ni = ti;
      }
    }
  }
  int res[8];
#pragma unroll
  for (int r = 0; r < 8; ++r) {
    float cd = bd[0]; int ci = bi[0];
#pragma unroll
    for (int off = 32; off >= 1; off >>= 1) {
      float od = __shfl_xor(cd, off);
      int oi = __shfl_xor(ci, off);
      if (od < cd || (od == cd && oi < ci)) { cd = od; ci = oi; }
    }
    res[r] = ci;
    if (ci == bi[0]) {
#pragma unroll
      for (int k = 0; k < 7; ++k) { bd[k] = bd[k+1]; bi[k] = bi[k+1]; }
      bd[7] = INFINITY; bi[7] = 0x7fffffff;
    }
  }
  if (lane == 0) {
#pragma unroll
    for (int r = 0; r < 8; ++r) idx[(size_t)q*8 + r] = res[r];
  }
}

// ---------- geom = max_k lrelu(G[idx_k] + Cb + bias), bf16 GCb input ----------
__global__ __launch_bounds__(384) void geom_k(const unsigned short* __restrict__ GCb,
                                              const float* __restrict__ bias,
                                              const int* __restrict__ idx,
                                              unsigned short* __restrict__ out) {
  int q = blockIdx.x;
  int b = q >> 11;
  int d = threadIdx.x;
  float c = b2f(GCb[(size_t)q*768 + 384 + d]) + bias[d];
  float mx = -INFINITY;
#pragma unroll
  for (int kn = 0; kn < 8; ++kn) {
    int j = idx[(size_t)q*8 + kn];
    float gg = b2f(GCb[((size_t)(b << 11) + j)*768 + d]);
    float y = gg + c;
    y = (y > 0.f) ? y : 0.2f*y;
    mx = fmaxf(mx, y);
  }
  out[(size_t)q*768 + 384 + d] = f2b(mx);
}

extern "C" void kernel_launch(void* const* d_in, const int* in_sizes, int n_in,
                              void* d_out, int out_size, void* d_ws, size_t ws_size,
                              hipStream_t stream) {
  (void)in_sizes; (void)n_in; (void)out_size; (void)ws_size;
  const float* qpts  = (const float*)d_in[0];
  const float* kpts  = (const float*)d_in[1];
  const float* ln_s  = (const float*)d_in[2];
  const float* ln_b  = (const float*)d_in[3];
  const float* qkvW  = (const float*)d_in[4];
  const float* Wo    = (const float*)d_in[5];
  const float* bo    = (const float*)d_in[6];
  const float* ffW1  = (const float*)d_in[7];
  const float* ffb1  = (const float*)d_in[8];
  const float* ffW2  = (const float*)d_in[9];
  const float* ffb2  = (const float*)d_in[10];
  const float* ffns  = (const float*)d_in[11];
  const float* ffnb  = (const float*)d_in[12];
  const float* knn1W = (const float*)d_in[13];
  const float* knn1b = (const float*)d_in[14];
  const float* knn2W = (const float*)d_in[15];
  const float* knn2b = (const float*)d_in[16];
  const float* smW   = (const float*)d_in[17];
  const float* smb   = (const float*)d_in[18];
  const float* cmW   = (const float*)d_in[19];
  const float* cmb   = (const float*)d_in[20];
  const float* cnqs  = (const float*)d_in[21];
  const float* cnqb  = (const float*)d_in[22];
  const float* cnks  = (const float*)d_in[23];
  const float* cnkb  = (const float*)d_in[24];
  const float* cqW   = (const float*)d_in[25];
  const float* ckW   = (const float*)d_in[26];
  const float* cvW   = (const float*)d_in[27];

  float* ws = (float*)d_ws;
  float* qc   = ws;                        // 24576
  float* kc   = qc + 24576;                // 24576
  float* qf   = kc + 24576;                // 3145728 f32 residual
  float* kf   = qf + 3145728;              // 3145728
  unsigned short* nrmb = (unsigned short*)(kf + 3145728);       // 1572864 floats
  unsigned short* nkb  = (unsigned short*)(kf + 3145728 + 1572864);
  float* qkv = kf + 3145728 + 1572864 + 1572864;
  unsigned short* qkvb   = (unsigned short*)qkv;                // 8192*1152 bf16
  unsigned short* attnGb = (unsigned short*)qkv;                // 8192*768 bf16 (alias)
  unsigned short* vtb    = (unsigned short*)(qkv + 4718592);    // 24*64*2048 bf16
  unsigned short* wtb    = (unsigned short*)(qkv + 4718592 + 1572864); // weights bf16
  unsigned short* attnOb = (unsigned short*)(qkv + 4718592 + 1572864 + 1400832);
  unsigned short* GCbb   = (unsigned short*)((float*)attnOb + 1572864); // 8192*768 bf16
  int* idx = (int*)((float*)GCbb + 3145728);

  const int W_QKV=0, W_WO=442368, W_K1T=589824, W_SM=884736,
            W_CQ=1179648, W_CK=1327104, W_K2T=1622016,
            W_WD2=1769472, W_CM=1916928, W_FF1=2211840, W_FF2=2506752;
  // W_WD1 = 737280 (adjacent to W_K1T -> fused), W_CV = 1474560 (adjacent to W_CK -> fused)

  WSrcs srcs;
  srcs.p[0]=qkvW; srcs.p[1]=Wo; srcs.p[2]=knn1W; srcs.p[3]=knn1W; srcs.p[4]=smW;
  srcs.p[5]=cqW; srcs.p[6]=ckW; srcs.p[7]=cvW; srcs.p[8]=knn2W; srcs.p[9]=knn2W;
  srcs.p[10]=cmW; srcs.p[11]=ffW1; srcs.p[12]=ffW2;
  wtrans_k<<<2736, 256, 0, stream>>>(srcs, wtb);

  dim3 tgrid(13, 64, NB), tblk(32, 8);
  split_k<<<tgrid, tblk, 0, stream>>>(qpts, qc, qf);
  split_k<<<tgrid, tblk, 0, stream>>>(kpts, kc, kf);

  dim3 mg384(6, 64), mg768(12, 64), mg1152(18, 64);
  dim3 fgrid(32, NH, NB), vgrid(32, NB*NH);

  // ---- self attention branch ----
  ln_k<<<2048, 256, 0, stream>>>(qf, ln_s, ln_b, nrmb);
  mgemm_k<0,0,1><<<mg1152, 256, 0, stream>>>(nrmb, DD, wtb+W_QKV, nullptr, qkvb, 1152, 0, DD);
  vtrans_k<<<vgrid, 256, 0, stream>>>(qkvb, vtb);
  flashm_k<<<fgrid, 256, 0, stream>>>(qkvb, vtb, attnOb);
  mgemm_k<0,0,1><<<mg384, 256, 0, stream>>>(attnOb, DD, wtb+W_WO, bo, attnGb, 768, 0, DD);
  // fused G|Cb: N=768 (k1^T rows then wdiff1 rows adjacent in wtb)
  mgemm_k<0,0,1><<<mg768, 256, 0, stream>>>(nrmb, DD, wtb+W_K1T, nullptr, GCbb, 768, 0, DD);
  knn_k<<<2048, 256, 0, stream>>>(qc, qc, idx);
  geom_k<<<8192, 384, 0, stream>>>(GCbb, knn1b, idx, attnGb);
  mgemm_k<0,1,0><<<mg384, 256, 0, stream>>>(attnGb, 768, wtb+W_SM, smb, qf, DD, 0, 768);

  // ---- cross attention branch ----
  ln_k<<<2048, 256, 0, stream>>>(qf, cnqs, cnqb, nrmb);   // nq
  ln_k<<<2048, 256, 0, stream>>>(kf, cnks, cnkb, nkb);    // nk
  mgemm_k<0,0,1><<<mg384, 256, 0, stream>>>(nrmb, DD, wtb+W_CQ, nullptr, qkvb, 1152, 0, DD);
  // fused K|V: N=768 (ck^T rows then cv^T rows adjacent)
  mgemm_k<0,0,1><<<mg768, 256, 0, stream>>>(nkb, DD, wtb+W_CK, nullptr, qkvb, 1152, 384, DD);
  vtrans_k<<<vgrid, 256, 0, stream>>>(qkvb, vtb);
  flashm_k<<<fgrid, 256, 0, stream>>>(qkvb, vtb, attnOb);
  mgemm_k<0,0,1><<<mg384, 256, 0, stream>>>(attnOb, DD, wtb+W_WO, bo, attnGb, 768, 0, DD);
  mgemm_k<0,0,1><<<mg384, 256, 0, stream>>>(nkb,  DD, wtb+W_K2T, nullptr, GCbb, 768, 0,   DD);
  mgemm_k<0,0,1><<<mg384, 256, 0, stream>>>(nrmb, DD, wtb+W_WD2, nullptr, GCbb, 768, 384, DD);
  knn_k<<<2048, 256, 0, stream>>>(qc, kc, idx);
  geom_k<<<8192, 384, 0, stream>>>(GCbb, knn2b, idx, attnGb);
  mgemm_k<0,1,0><<<mg384, 256, 0, stream>>>(attnGb, 768, wtb+W_CM, cmb, qf, DD, 0, 768);

  // ---- FFN ----
  ln_k<<<2048, 256, 0, stream>>>(qf, ffns, ffnb, nrmb);
  mgemm_k<1,0,1><<<mg768, 256, 0, stream>>>(nrmb, DD, wtb+W_FF1, ffb1, attnGb, 768, 0, DD);
  mgemm_k<0,1,0><<<mg384, 256, 0, stream>>>(attnGb, 768, wtb+W_FF2, ffb2, qf, DD, 0, 768);

  pack_k<<<tgrid, tblk, 0, stream>>>(qc, qf, (float*)d_out);
}

// Round 6
// 403.220 us; speedup vs baseline: 6.0992x; 1.1440x over previous
//
#include <hip/hip_runtime.h>
#include <cstdint>
#include <cstddef>

#define NB 4
#define NN 2048
#define DD 384
#define NH 6

typedef float f4 __attribute__((ext_vector_type(4)));
typedef float f32x4 __attribute__((ext_vector_type(4)));
typedef short bf16x8 __attribute__((ext_vector_type(8)));
typedef short s4v __attribute__((ext_vector_type(4)));
typedef unsigned u32x2 __attribute__((ext_vector_type(2)));

__device__ __forceinline__ float gelu_t(float x) {
  float x3 = x*x*x;
  return 0.5f*x*(1.0f + tanhf(0.7978845608028654f*(x + 0.044715f*x3)));
}

__device__ __forceinline__ unsigned short f2b(float f) {
  unsigned u = __builtin_bit_cast(unsigned, f);
  u += 0x7fffu + ((u >> 16) & 1u);
  return (unsigned short)(u >> 16);
}

__device__ __forceinline__ float b2f(unsigned short u) {
  return __builtin_bit_cast(float, ((unsigned)u) << 16);
}

__device__ __forceinline__ unsigned cvtpk(float a, float b) {
  unsigned r;
  asm("v_cvt_pk_bf16_f32 %0, %1, %2" : "=v"(r) : "v"(a), "v"(b));
  return r;
}

typedef __attribute__((address_space(1))) const void gvoid_t;
typedef __attribute__((address_space(3))) void lvoid_t;
__device__ __forceinline__ void gl16(const void* g, void* l) {
  __builtin_amdgcn_global_load_lds((gvoid_t*)g, (lvoid_t*)l, 16, 0, 0);
}

// ---------- split (B,387,N) -> coords (B,N,3), feats (B,N,384) ----------
__global__ __launch_bounds__(256) void split_k(const float* __restrict__ pts,
                                               float* __restrict__ coords,
                                               float* __restrict__ feats) {
  __shared__ float t[32][33];
  int b = blockIdx.z;
  int c0 = blockIdx.x*32, n0 = blockIdx.y*32;
  int tx = threadIdx.x, ty = threadIdx.y;
#pragma unroll
  for (int i = 0; i < 4; ++i) {
    int c = c0 + ty + i*8;
    if (c < 387) t[ty+i*8][tx] = pts[((size_t)b*387 + c)*NN + n0 + tx];
  }
  __syncthreads();
#pragma unroll
  for (int i = 0; i < 4; ++i) {
    int n = n0 + ty + i*8;
    int c = c0 + tx;
    if (c < 387) {
      float v = t[tx][ty+i*8];
      if (c < 3) coords[((size_t)b*NN + n)*3 + c] = v;
      else       feats[((size_t)b*NN + n)*DD + (c-3)] = v;
    }
  }
}

// ---------- pack coords+feats -> (B,387,N) ----------
__global__ __launch_bounds__(256) void pack_k(const float* __restrict__ coords,
                                              const float* __restrict__ feats,
                                              float* __restrict__ out) {
  __shared__ float t[32][33];
  int b = blockIdx.z;
  int c0 = blockIdx.x*32, n0 = blockIdx.y*32;
  int tx = threadIdx.x, ty = threadIdx.y;
#pragma unroll
  for (int i = 0; i < 4; ++i) {
    int n = n0 + ty + i*8;
    int c = c0 + tx;
    if (c < 387) {
      float v = (c < 3) ? coords[((size_t)b*NN + n)*3 + c]
                        : feats[((size_t)b*NN + n)*DD + (c-3)];
      t[tx][ty+i*8] = v;
    }
  }
  __syncthreads();
#pragma unroll
  for (int i = 0; i < 4; ++i) {
    int c = c0 + ty + i*8;
    if (c < 387) out[((size_t)b*387 + c)*NN + n0 + tx] = t[ty+i*8][tx];
  }
}

// ---------- LayerNorm body ----------
__device__ __forceinline__ void ln_body(const float* __restrict__ x,
                                        const float* __restrict__ g,
                                        const float* __restrict__ bb,
                                        unsigned short* __restrict__ o,
                                        int row) {
  int lane = threadIdx.x & 63;
  const float* xr = x + (size_t)row*DD;
  float v[6]; float s = 0.f;
#pragma unroll
  for (int i = 0; i < 6; ++i) { v[i] = xr[lane + i*64]; s += v[i]; }
#pragma unroll
  for (int off = 1; off < 64; off <<= 1) s += __shfl_xor(s, off);
  float mean = s * (1.f/384.f);
  float s2 = 0.f;
#pragma unroll
  for (int i = 0; i < 6; ++i) { float d = v[i] - mean; s2 += d*d; }
#pragma unroll
  for (int off = 1; off < 64; off <<= 1) s2 += __shfl_xor(s2, off);
  float rs = rsqrtf(s2*(1.f/384.f) + 1e-5f);
  unsigned short* orow = o + (size_t)row*DD;
#pragma unroll
  for (int i = 0; i < 6; ++i) {
    int c = lane + i*64;
    orow[c] = f2b((v[i]-mean)*rs*g[c] + bb[c]);
  }
}

__global__ __launch_bounds__(256) void ln_k(const float* __restrict__ x,
                                            const float* __restrict__ g,
                                            const float* __restrict__ bb,
                                            unsigned short* __restrict__ o) {
  ln_body(x, g, bb, o, blockIdx.x*4 + (threadIdx.x >> 6));
}

// ---------- merged nq/nk LayerNorm ----------
__global__ __launch_bounds__(256) void ln2_k(const float* __restrict__ x1,
                                             const float* __restrict__ g1,
                                             const float* __restrict__ b1,
                                             unsigned short* __restrict__ o1,
                                             const float* __restrict__ x2,
                                             const float* __restrict__ g2,
                                             const float* __restrict__ b2,
                                             unsigned short* __restrict__ o2) {
  int row = blockIdx.x*4 + (threadIdx.x >> 6);
  if (blockIdx.y == 0) ln_body(x1, g1, b1, o1, row);
  else                 ln_body(x2, g2, b2, o2, row);
}

// ---------- one-shot weight transpose+convert: Wt[n][k] = W[k][n] (bf16) ----------
// layout: [QKV(1152)|K1T(384)|WD1(384)] fused_A rows 0..1919 at 0
//         WO 737280 | SM 884736 | [CQ|CK|CV|K2T|WD2] fused_B rows at 1179648
//         CM 1916928 | FF1 2211840 | FF2 2506752
struct WSrcs { const float* p[13]; };

__global__ __launch_bounds__(256) void wtrans_k(WSrcs srcs, unsigned short* __restrict__ dst) {
  constexpr int KK[13]  = {384,384,384,384,768,384,384,384,384,384,768,384,768};
  constexpr int NW[13]  = {1152,384,384,384,384,384,384,384,384,384,384,768,384};
  constexpr int MD[13]  = {0,0,2,0,0,0,0,0,0,2,0,0,0};
  constexpr int OFF[13] = {0,442368,589824,737280,884736,1179648,1327104,1474560,
                           1622016,1769472,1916928,2211840,2506752};
  constexpr int PFX[14] = {0,432,576,720,864,1152,1296,1440,1584,1728,1872,2160,2448,2736};
  int bid = blockIdx.x;
  int e = 0;
  while (bid >= PFX[e+1]) ++e;
  int t = bid - PFX[e];
  int K = KK[e], N = NW[e];
  int ntiles = N >> 5;
  int kt = t / ntiles, nt = t - kt*ntiles;
  const float* src = srcs.p[e];
  __shared__ float T[32][33];
  int tx = threadIdx.x & 31, ty = threadIdx.x >> 5;
  int n = nt*32 + tx;
#pragma unroll
  for (int i = 0; i < 4; ++i) {
    int k = kt*32 + ty + i*8;
    float v = src[(size_t)k*N + n];
    if (MD[e] == 2) v = src[(size_t)(k+384)*N + n] - v;
    T[ty+i*8][tx] = v;
  }
  __syncthreads();
#pragma unroll
  for (int i = 0; i < 4; ++i) {
    int nn = nt*32 + ty + i*8;
    int kk = kt*32 + tx;
    dst[(size_t)OFF[e] + (size_t)nn*K + kk] = f2b(T[tx][ty+i*8]);
  }
}

// ---------- MFMA bf16 GEMM, double-buffered gl16 staging (2-phase T3) ----------
template<int ACT, int ACC, int OB>
__global__ __launch_bounds__(256) void mgemm_k(const unsigned short* __restrict__ A, int lda,
                                               const unsigned short* __restrict__ Wt,
                                               const float* __restrict__ bias,
                                               void* __restrict__ Cv, int ldc, int cofs,
                                               int Kd) {
  __shared__ char lds[49152];           // 2 x (As 16KB | Bs 8KB)
  int tid = threadIdx.x;
  int lane = tid & 63, w = tid >> 6, g = lane >> 4, c = lane & 15;
  int wr = w >> 1, wc = w & 1;
  int m0 = blockIdx.y*128, n0 = blockIdx.x*64;
  int lrow = lane >> 3;
  int cswz = ((lane & 7) ^ lrow)*8;

  f32x4 acc[4][2];
#pragma unroll
  for (int mt = 0; mt < 4; ++mt)
#pragma unroll
    for (int nt = 0; nt < 2; ++nt) acc[mt][nt] = 0.f;

  int KT = Kd >> 6;
  // prologue: stage tile 0 into buf 0
  {
    char* As = lds; char* Bs = lds + 16384;
#pragma unroll
    for (int i = 0; i < 4; ++i) {
      int rb = i*32 + w*8;
      gl16(A + (size_t)(m0 + rb + lrow)*lda + cswz, As + rb*128);
    }
#pragma unroll
    for (int i = 0; i < 2; ++i) {
      int rb = i*32 + w*8;
      gl16(Wt + (size_t)(n0 + rb + lrow)*Kd + cswz, Bs + rb*128);
    }
  }
  __syncthreads();

  for (int kt = 0; kt < KT; ++kt) {
    char* Asc = lds + (kt & 1)*24576;
    char* Bsc = Asc + 16384;
    if (kt + 1 < KT) {                 // issue next-tile stage before compute
      char* Asn = lds + ((kt + 1) & 1)*24576;
      char* Bsn = Asn + 16384;
      int k0 = (kt + 1)*64;
#pragma unroll
      for (int i = 0; i < 4; ++i) {
        int rb = i*32 + w*8;
        gl16(A + (size_t)(m0 + rb + lrow)*lda + k0 + cswz, Asn + rb*128);
      }
#pragma unroll
      for (int i = 0; i < 2; ++i) {
        int rb = i*32 + w*8;
        gl16(Wt + (size_t)(n0 + rb + lrow)*Kd + k0 + cswz, Bsn + rb*128);
      }
    }
#pragma unroll
    for (int kb = 0; kb < 2; ++kb) {
      bf16x8 af[4], bfr[2];
#pragma unroll
      for (int mt = 0; mt < 4; ++mt) {
        int row = wr*64 + mt*16 + c;
        int ch = (kb*4 + g) ^ (row & 7);
        af[mt] = *(const bf16x8*)(Asc + row*128 + ch*16);
      }
#pragma unroll
      for (int nt = 0; nt < 2; ++nt) {
        int row = wc*32 + nt*16 + c;
        int ch = (kb*4 + g) ^ (row & 7);
        bfr[nt] = *(const bf16x8*)(Bsc + row*128 + ch*16);
      }
#pragma unroll
      for (int mt = 0; mt < 4; ++mt)
#pragma unroll
        for (int nt = 0; nt < 2; ++nt)
          acc[mt][nt] = __builtin_amdgcn_mfma_f32_16x16x32_bf16(af[mt], bfr[nt], acc[mt][nt], 0, 0, 0);
    }
    __syncthreads();                   // drains vmcnt(0): next buf ready; cur free
  }

#pragma unroll
  for (int mt = 0; mt < 4; ++mt) {
#pragma unroll
    for (int nt = 0; nt < 2; ++nt) {
      int coln = n0 + wc*32 + nt*16 + c;
      float bval = bias ? bias[coln] : 0.f;
#pragma unroll
      for (int r = 0; r < 4; ++r) {
        int m = m0 + wr*64 + mt*16 + 4*g + r;
        float t = acc[mt][nt][r] + bval;
        if (ACT == 1) t = gelu_t(t);
        if (OB) {
          ((unsigned short*)Cv)[(size_t)m*ldc + cofs + coln] = f2b(t);
        } else {
          float* cp = (float*)Cv + (size_t)m*ldc + cofs + coln;
          if (ACC) t += *cp;
          *cp = t;
        }
      }
    }
  }
}

// ---------- fused 5-segment GEMM (K=384, N=1920), per-segment A/out ----------
struct FSegs {
  const unsigned short* A[5];
  unsigned short* out[5];
  int ldc[5];
  int cofs[5];
};

__global__ __launch_bounds__(256) void fgemm_k(FSegs fs, const unsigned short* __restrict__ Wt) {
  __shared__ char lds[49152];
  int tid = threadIdx.x;
  int lane = tid & 63, w = tid >> 6, g = lane >> 4, c = lane & 15;
  int wr = w >> 1, wc = w & 1;
  int m0 = blockIdx.y*128, n0 = blockIdx.x*64;
  int seg = n0 / 384;
  const unsigned short* A = fs.A[seg];
  int lrow = lane >> 3;
  int cswz = ((lane & 7) ^ lrow)*8;

  f32x4 acc[4][2];
#pragma unroll
  for (int mt = 0; mt < 4; ++mt)
#pragma unroll
    for (int nt = 0; nt < 2; ++nt) acc[mt][nt] = 0.f;

  {
    char* As = lds; char* Bs = lds + 16384;
#pragma unroll
    for (int i = 0; i < 4; ++i) {
      int rb = i*32 + w*8;
      gl16(A + (size_t)(m0 + rb + lrow)*384 + cswz, As + rb*128);
    }
#pragma unroll
    for (int i = 0; i < 2; ++i) {
      int rb = i*32 + w*8;
      gl16(Wt + (size_t)(n0 + rb + lrow)*384 + cswz, Bs + rb*128);
    }
  }
  __syncthreads();

  for (int kt = 0; kt < 6; ++kt) {
    char* Asc = lds + (kt & 1)*24576;
    char* Bsc = Asc + 16384;
    if (kt + 1 < 6) {
      char* Asn = lds + ((kt + 1) & 1)*24576;
      char* Bsn = Asn + 16384;
      int k0 = (kt + 1)*64;
#pragma unroll
      for (int i = 0; i < 4; ++i) {
        int rb = i*32 + w*8;
        gl16(A + (size_t)(m0 + rb + lrow)*384 + k0 + cswz, Asn + rb*128);
      }
#pragma unroll
      for (int i = 0; i < 2; ++i) {
        int rb = i*32 + w*8;
        gl16(Wt + (size_t)(n0 + rb + lrow)*384 + k0 + cswz, Bsn + rb*128);
      }
    }
#pragma unroll
    for (int kb = 0; kb < 2; ++kb) {
      bf16x8 af[4], bfr[2];
#pragma unroll
      for (int mt = 0; mt < 4; ++mt) {
        int row = wr*64 + mt*16 + c;
        int ch = (kb*4 + g) ^ (row & 7);
        af[mt] = *(const bf16x8*)(Asc + row*128 + ch*16);
      }
#pragma unroll
      for (int nt = 0; nt < 2; ++nt) {
        int row = wc*32 + nt*16 + c;
        int ch = (kb*4 + g) ^ (row & 7);
        bfr[nt] = *(const bf16x8*)(Bsc + row*128 + ch*16);
      }
#pragma unroll
      for (int mt = 0; mt < 4; ++mt)
#pragma unroll
        for (int nt = 0; nt < 2; ++nt)
          acc[mt][nt] = __builtin_amdgcn_mfma_f32_16x16x32_bf16(af[mt], bfr[nt], acc[mt][nt], 0, 0, 0);
    }
    __syncthreads();
  }

  unsigned short* outp = fs.out[seg];
  int ldcs = fs.ldc[seg];
  int cbase = fs.cofs[seg] + (n0 - seg*384);
#pragma unroll
  for (int mt = 0; mt < 4; ++mt) {
#pragma unroll
    for (int nt = 0; nt < 2; ++nt) {
      int coln = cbase + wc*32 + nt*16 + c;
#pragma unroll
      for (int r = 0; r < 4; ++r) {
        int m = m0 + wr*64 + mt*16 + 4*g + r;
        outp[(size_t)m*ldcs + coln] = f2b(acc[mt][nt][r]);
      }
    }
  }
}

// ---------- V transpose ----------
__global__ __launch_bounds__(256) void vtrans_k(const unsigned short* __restrict__ qkvb,
                                                unsigned short* __restrict__ vt) {
  __shared__ unsigned short T[4096];
  int bh = blockIdx.y; int b = bh / NH, h = bh % NH;
  int t0 = blockIdx.x*64;
  int tid = threadIdx.x;
#pragma unroll
  for (int p = 0; p < 2; ++p) {
    int row = p*32 + (tid >> 3);
    int ch  = tid & 7;
    bf16x8 v = *(const bf16x8*)(qkvb + ((size_t)(b*NN + t0 + row))*1152 + 768 + h*64 + ch*8);
    *(bf16x8*)&T[row*64 + ((ch ^ (row & 7))*8)] = v;
  }
  __syncthreads();
#pragma unroll
  for (int p = 0; p < 2; ++p) {
    int d  = p*32 + (tid >> 3);
    int kc = tid & 7;
    bf16x8 v;
#pragma unroll
    for (int e = 0; e < 8; ++e) {
      int tok = kc*8 + e;
      v[e] = (short)T[tok*64 + (((d >> 3) ^ (tok & 7))*8) + (d & 7)];
    }
    *(bf16x8*)(vt + (((size_t)bh*64 + d)*NN) + t0 + kc*8) = v;
  }
}

// ---------- MFMA flash attention, swapped-operand, fixed-shift softmax ----------
__global__ __launch_bounds__(256) void flashm_k(const unsigned short* __restrict__ qkvb,
                                                const unsigned short* __restrict__ vt,
                                                unsigned short* __restrict__ o) {
  __shared__ char smem[24576];
  char* KT  = smem;
  char* VT2 = smem + 8192;
  char* PT  = smem + 16384;
  int b = blockIdx.z, h = blockIdx.y, q0 = blockIdx.x*64;
  int tid = threadIdx.x;
  int w = tid >> 6, lane = tid & 63, g = lane >> 4, c = lane & 15;

  bf16x8 qf[2];
  {
    const unsigned short* qrow = qkvb + ((size_t)(b*NN + q0 + w*16 + c))*1152 + h*64;
    qf[0] = *(const bf16x8*)(qrow + 8*g);
    qf[1] = *(const bf16x8*)(qrow + 32 + 8*g);
  }
  f32x4 oacc[4];
#pragma unroll
  for (int i = 0; i < 4; ++i) oacc[i] = 0.f;
  float lsum = 0.f;

  int srow = lane >> 3;
  int scol = (lane & 7)*16;
  int r0 = w*16 + srow, r1 = w*16 + 8 + srow;
  int cb0 = scol ^ ((r0 & 7) << 4);
  int cb1 = scol ^ ((r1 & 7) << 4);

  const unsigned short* kbase = qkvb + (size_t)b*NN*1152 + 384 + h*64;
  const unsigned short* vbase = vt + ((size_t)(b*NH + h))*64*NN;

  bf16x8 kreg[2], vreg[2];
  kreg[0] = *(const bf16x8*)(kbase + (size_t)r0*1152 + (scol >> 1));
  kreg[1] = *(const bf16x8*)(kbase + (size_t)r1*1152 + (scol >> 1));
  vreg[0] = *(const bf16x8*)(vbase + (size_t)r0*NN + (scol >> 1));
  vreg[1] = *(const bf16x8*)(vbase + (size_t)r1*NN + (scol >> 1));

  for (int kt = 0; kt < 32; ++kt) {
    __syncthreads();
    *(bf16x8*)(KT  + r0*128 + cb0) = kreg[0];
    *(bf16x8*)(KT  + r1*128 + cb1) = kreg[1];
    *(bf16x8*)(VT2 + r0*128 + cb0) = vreg[0];
    *(bf16x8*)(VT2 + r1*128 + cb1) = vreg[1];
    if (kt + 1 < 32) {
      int kn = kt + 1;
      kreg[0] = *(const bf16x8*)(kbase + (size_t)(kn*64 + r0)*1152 + (scol >> 1));
      kreg[1] = *(const bf16x8*)(kbase + (size_t)(kn*64 + r1)*1152 + (scol >> 1));
      vreg[0] = *(const bf16x8*)(vbase + (size_t)r0*NN + kn*64 + (scol >> 1));
      vreg[1] = *(const bf16x8*)(vbase + (size_t)r1*NN + kn*64 + (scol >> 1));
    }
    __syncthreads();

    f32x4 sT[4];
#pragma unroll
    for (int nt = 0; nt < 4; ++nt) sT[nt] = 0.f;
#pragma unroll
    for (int nt = 0; nt < 4; ++nt) {
      int krow = nt*16 + c;
#pragma unroll
      for (int kb = 0; kb < 2; ++kb) {
        int ch = ((kb*4 + g) ^ (krow & 7))*16;
        bf16x8 kf_ = *(const bf16x8*)(KT + krow*128 + ch);
        sT[nt] = __builtin_amdgcn_mfma_f32_16x16x32_bf16(kf_, qf[kb], sT[nt], 0, 0, 0);
      }
    }

    int prow = w*16 + c;
    int pswz = (c & 7) << 4;
#pragma unroll
    for (int nt = 0; nt < 4; ++nt) {
      float p0 = __builtin_amdgcn_exp2f(sT[nt][0] * 0.18033688011112042f);
      float p1 = __builtin_amdgcn_exp2f(sT[nt][1] * 0.18033688011112042f);
      float p2 = __builtin_amdgcn_exp2f(sT[nt][2] * 0.18033688011112042f);
      float p3 = __builtin_amdgcn_exp2f(sT[nt][3] * 0.18033688011112042f);
      lsum += (p0 + p1) + (p2 + p3);
      u32x2 pk;
      pk[0] = cvtpk(p0, p1);
      pk[1] = cvtpk(p2, p3);
      *(u32x2*)(PT + prow*128 + ((nt*32 + 8*g) ^ pswz)) = pk;
    }

    bf16x8 pb[2];
#pragma unroll
    for (int kb = 0; kb < 2; ++kb)
      pb[kb] = *(const bf16x8*)(PT + prow*128 + (((kb*4 + g) ^ (c & 7))*16));

#pragma unroll
    for (int dt = 0; dt < 4; ++dt) {
      int vrow = dt*16 + c;
#pragma unroll
      for (int kb = 0; kb < 2; ++kb) {
        int ch = ((kb*4 + g) ^ (vrow & 7))*16;
        bf16x8 vf = *(const bf16x8*)(VT2 + vrow*128 + ch);
        oacc[dt] = __builtin_amdgcn_mfma_f32_16x16x32_bf16(vf, pb[kb], oacc[dt], 0, 0, 0);
      }
    }
  }

  lsum += __shfl_xor(lsum, 16);
  lsum += __shfl_xor(lsum, 32);
  float inv = 1.f / lsum;
  size_t orow = ((size_t)b*NN + q0 + w*16 + c)*DD + h*64;
#pragma unroll
  for (int dt = 0; dt < 4; ++dt) {
    u32x2 ov;
    ov[0] = cvtpk(oacc[dt][0]*inv, oacc[dt][1]*inv);
    ov[1] = cvtpk(oacc[dt][2]*inv, oacc[dt][3]*inv);
    *(u32x2*)(o + orow + dt*16 + 4*g) = ov;
  }
}

// ---------- merged KNN top-8 (y=0: self qc/qc->idx1; y=1: cross qc/kc->idx2) ----------
__global__ __launch_bounds__(256) void knn2_k(const float* __restrict__ qc,
                                              const float* __restrict__ kc,
                                              int* __restrict__ idx1,
                                              int* __restrict__ idx2) {
  const float* kcs = blockIdx.y ? kc : qc;
  int* idxo = blockIdx.y ? idx2 : idx1;
  int lane = threadIdx.x & 63;
  int q = blockIdx.x*4 + (threadIdx.x >> 6);
  int b = q >> 11, n = q & 2047;
  const float* qp = qc + ((size_t)b*NN + n)*3;
  float qx = qp[0], qy = qp[1], qz = qp[2];
  float qq = qx*qx + qy*qy + qz*qz;
  float bd[8]; int bi[8];
#pragma unroll
  for (int i = 0; i < 8; ++i) { bd[i] = INFINITY; bi[i] = 0x7fffffff; }
  const float* kb = kcs + (size_t)b*NN*3;
  for (int j = lane; j < NN; j += 64) {
    float kx = kb[(size_t)j*3], ky = kb[(size_t)j*3+1], kz = kb[(size_t)j*3+2];
    float dt = qx*kx + qy*ky + qz*kz;
    float kk = kx*kx + ky*ky + kz*kz;
    float d2 = qq + kk - 2.f*dt;
    if (d2 < bd[7]) {
      float nd = d2; int ni = j;
#pragma unroll
      for (int k = 0; k < 8; ++k) {
        bool sw = (nd < bd[k]) || (nd == bd[k] && ni < bi[k]);
        float td = sw ? bd[k] : nd;
        int   ti = sw ? bi[k] : ni;
        if (sw) { bd[k] = nd; bi[k] = ni; }
        nd = td; ni = ti;
      }
    }
  }
  int res[8];
#pragma unroll
  for (int r = 0; r < 8; ++r) {
    float cd = bd[0]; int ci = bi[0];
#pragma unroll
    for (int off = 32; off >= 1; off >>= 1) {
      float od = __shfl_xor(cd, off);
      int oi = __shfl_xor(ci, off);
      if (od < cd || (od == cd && oi < ci)) { cd = od; ci = oi; }
    }
    res[r] = ci;
    if (ci == bi[0]) {
#pragma unroll
      for (int k = 0; k < 7; ++k) { bd[k] = bd[k+1]; bi[k] = bi[k+1]; }
      bd[7] = INFINITY; bi[7] = 0x7fffffff;
    }
  }
  if (lane == 0) {
#pragma unroll
    for (int r = 0; r < 8; ++r) idxo[(size_t)q*8 + r] = res[r];
  }
}

// ---------- geom = max_k lrelu(G[idx_k] + Cb + bias) ----------
__global__ __launch_bounds__(384) void geom_k(const unsigned short* __restrict__ GCb,
                                              const float* __restrict__ bias,
                                              const int* __restrict__ idx,
                                              unsigned short* __restrict__ out) {
  int q = blockIdx.x;
  int b = q >> 11;
  int d = threadIdx.x;
  float c = b2f(GCb[(size_t)q*768 + 384 + d]) + bias[d];
  float mx = -INFINITY;
#pragma unroll
  for (int kn = 0; kn < 8; ++kn) {
    int j = idx[(size_t)q*8 + kn];
    float gg = b2f(GCb[((size_t)(b << 11) + j)*768 + d]);
    float y = gg + c;
    y = (y > 0.f) ? y : 0.2f*y;
    mx = fmaxf(mx, y);
  }
  out[(size_t)q*768 + 384 + d] = f2b(mx);
}

extern "C" void kernel_launch(void* const* d_in, const int* in_sizes, int n_in,
                              void* d_out, int out_size, void* d_ws, size_t ws_size,
                              hipStream_t stream) {
  (void)in_sizes; (void)n_in; (void)out_size; (void)ws_size;
  const float* qpts  = (const float*)d_in[0];
  const float* kpts  = (const float*)d_in[1];
  const float* ln_s  = (const float*)d_in[2];
  const float* ln_b  = (const float*)d_in[3];
  const float* qkvW  = (const float*)d_in[4];
  const float* Wo    = (const float*)d_in[5];
  const float* bo    = (const float*)d_in[6];
  const float* ffW1  = (const float*)d_in[7];
  const float* ffb1  = (const float*)d_in[8];
  const float* ffW2  = (const float*)d_in[9];
  const float* ffb2  = (const float*)d_in[10];
  const float* ffns  = (const float*)d_in[11];
  const float* ffnb  = (const float*)d_in[12];
  const float* knn1W = (const float*)d_in[13];
  const float* knn1b = (const float*)d_in[14];
  const float* knn2W = (const float*)d_in[15];
  const float* knn2b = (const float*)d_in[16];
  const float* smW   = (const float*)d_in[17];
  const float* smb   = (const float*)d_in[18];
  const float* cmW   = (const float*)d_in[19];
  const float* cmb   = (const float*)d_in[20];
  const float* cnqs  = (const float*)d_in[21];
  const float* cnqb  = (const float*)d_in[22];
  const float* cnks  = (const float*)d_in[23];
  const float* cnkb  = (const float*)d_in[24];
  const float* cqW   = (const float*)d_in[25];
  const float* ckW   = (const float*)d_in[26];
  const float* cvW   = (const float*)d_in[27];

  float* ws = (float*)d_ws;
  float* qc   = ws;
  float* kc   = qc + 24576;
  float* qf   = kc + 24576;
  float* kf   = qf + 3145728;
  unsigned short* nrmb = (unsigned short*)(kf + 3145728);
  unsigned short* nkb  = (unsigned short*)(kf + 3145728 + 1572864);
  float* qkv = kf + 3145728 + 1572864 + 1572864;
  unsigned short* qkvb   = (unsigned short*)qkv;
  unsigned short* attnGb = (unsigned short*)qkv;
  unsigned short* vtb    = (unsigned short*)(qkv + 4718592);
  unsigned short* wtb    = (unsigned short*)(qkv + 4718592 + 1572864);
  unsigned short* attnOb = (unsigned short*)(qkv + 4718592 + 1572864 + 1400832);
  unsigned short* GCbb   = (unsigned short*)((float*)attnOb + 1572864);
  int* idx1 = (int*)((float*)GCbb + 3145728);
  int* idx2 = idx1 + 65536;

  const int W_FA=0, W_WO=737280, W_SM=884736, W_FB=1179648,
            W_CM=1916928, W_FF1=2211840, W_FF2=2506752;

  WSrcs srcs;
  srcs.p[0]=qkvW; srcs.p[1]=knn1W; srcs.p[2]=knn1W; srcs.p[3]=Wo; srcs.p[4]=smW;
  srcs.p[5]=cqW; srcs.p[6]=ckW; srcs.p[7]=cvW; srcs.p[8]=knn2W; srcs.p[9]=knn2W;
  srcs.p[10]=cmW; srcs.p[11]=ffW1; srcs.p[12]=ffW2;
  wtrans_k<<<2736, 256, 0, stream>>>(srcs, wtb);

  dim3 tgrid(13, 64, NB), tblk(32, 8);
  split_k<<<tgrid, tblk, 0, stream>>>(qpts, qc, qf);
  split_k<<<tgrid, tblk, 0, stream>>>(kpts, kc, kf);

  knn2_k<<<dim3(2048, 2), 256, 0, stream>>>(qc, kc, idx1, idx2);

  dim3 mg384(6, 64), mg768(12, 64), fg(30, 64);
  dim3 fgrid(32, NH, NB), vgrid(32, NB*NH);

  // ---- self attention branch ----
  ln_k<<<2048, 256, 0, stream>>>(qf, ln_s, ln_b, nrmb);
  {
    FSegs fa;
    for (int s = 0; s < 5; ++s) fa.A[s] = nrmb;
    fa.out[0] = qkvb; fa.ldc[0] = 1152; fa.cofs[0] = 0;
    fa.out[1] = qkvb; fa.ldc[1] = 1152; fa.cofs[1] = 384;
    fa.out[2] = qkvb; fa.ldc[2] = 1152; fa.cofs[2] = 768;
    fa.out[3] = GCbb; fa.ldc[3] = 768;  fa.cofs[3] = 0;
    fa.out[4] = GCbb; fa.ldc[4] = 768;  fa.cofs[4] = 384;
    fgemm_k<<<fg, 256, 0, stream>>>(fa, wtb + W_FA);
  }
  vtrans_k<<<vgrid, 256, 0, stream>>>(qkvb, vtb);
  flashm_k<<<fgrid, 256, 0, stream>>>(qkvb, vtb, attnOb);
  mgemm_k<0,0,1><<<mg384, 256, 0, stream>>>(attnOb, DD, wtb+W_WO, bo, attnGb, 768, 0, DD);
  geom_k<<<8192, 384, 0, stream>>>(GCbb, knn1b, idx1, attnGb);
  mgemm_k<0,1,0><<<mg384, 256, 0, stream>>>(attnGb, 768, wtb+W_SM, smb, qf, DD, 0, 768);

  // ---- cross attention branch ----
  ln2_k<<<dim3(2048, 2), 256, 0, stream>>>(qf, cnqs, cnqb, nrmb, kf, cnks, cnkb, nkb);
  {
    FSegs fb;
    fb.A[0] = nrmb; fb.A[1] = nkb; fb.A[2] = nkb; fb.A[3] = nkb; fb.A[4] = nrmb;
    fb.out[0] = qkvb; fb.ldc[0] = 1152; fb.cofs[0] = 0;
    fb.out[1] = qkvb; fb.ldc[1] = 1152; fb.cofs[1] = 384;
    fb.out[2] = qkvb; fb.ldc[2] = 1152; fb.cofs[2] = 768;
    fb.out[3] = GCbb; fb.ldc[3] = 768;  fb.cofs[3] = 0;
    fb.out[4] = GCbb; fb.ldc[4] = 768;  fb.cofs[4] = 384;
    fgemm_k<<<fg, 256, 0, stream>>>(fb, wtb + W_FB);
  }
  vtrans_k<<<vgrid, 256, 0, stream>>>(qkvb, vtb);
  flashm_k<<<fgrid, 256, 0, stream>>>(qkvb, vtb, attnOb);
  mgemm_k<0,0,1><<<mg384, 256, 0, stream>>>(attnOb, DD, wtb+W_WO, bo, attnGb, 768, 0, DD);
  geom_k<<<8192, 384, 0, stream>>>(GCbb, knn2b, idx2, attnGb);
  mgemm_k<0,1,0><<<mg384, 256, 0, stream>>>(attnGb, 768, wtb+W_CM, cmb, qf, DD, 0, 768);

  // ---- FFN ----
  ln_k<<<2048, 256, 0, stream>>>(qf, ffns, ffnb, nrmb);
  mgemm_k<1,0,1><<<mg768, 256, 0, stream>>>(nrmb, DD, wtb+W_FF1, ffb1, attnGb, 768, 0, DD);
  mgemm_k<0,1,0><<<mg384, 256, 0, stream>>>(attnGb, 768, wtb+W_FF2, ffb2, qf, DD, 0, 768);

  pack_k<<<tgrid, tblk, 0, stream>>>(qc, qf, (float*)d_out);
}

// Round 7
// 381.542 us; speedup vs baseline: 6.4457x; 1.0568x over previous
//
#include <hip/hip_runtime.h>
#include <cstdint>
#include <cstddef>

#define NB 4
#define NN 2048
#define DD 384
#define NH 6

typedef float f4 __attribute__((ext_vector_type(4)));
typedef float f32x4 __attribute__((ext_vector_type(4)));
typedef short bf16x8 __attribute__((ext_vector_type(8)));
typedef short s4v __attribute__((ext_vector_type(4)));
typedef unsigned u32x2 __attribute__((ext_vector_type(2)));

__device__ __forceinline__ float gelu_t(float x) {
  float x3 = x*x*x;
  return 0.5f*x*(1.0f + tanhf(0.7978845608028654f*(x + 0.044715f*x3)));
}

__device__ __forceinline__ unsigned short f2b(float f) {
  unsigned u = __builtin_bit_cast(unsigned, f);
  u += 0x7fffu + ((u >> 16) & 1u);
  return (unsigned short)(u >> 16);
}

__device__ __forceinline__ float b2f(unsigned short u) {
  return __builtin_bit_cast(float, ((unsigned)u) << 16);
}

__device__ __forceinline__ unsigned cvtpk(float a, float b) {
  unsigned r;
  asm("v_cvt_pk_bf16_f32 %0, %1, %2" : "=v"(r) : "v"(a), "v"(b));
  return r;
}

typedef __attribute__((address_space(1))) const void gvoid_t;
typedef __attribute__((address_space(3))) void lvoid_t;
__device__ __forceinline__ void gl16(const void* g, void* l) {
  __builtin_amdgcn_global_load_lds((gvoid_t*)g, (lvoid_t*)l, 16, 0, 0);
}

__device__ __forceinline__ unsigned long long shfl_xor_u64(unsigned long long v, int m) {
  unsigned lo = (unsigned)v, hi = (unsigned)(v >> 32);
  lo = (unsigned)__shfl_xor((int)lo, m);
  hi = (unsigned)__shfl_xor((int)hi, m);
  return ((unsigned long long)hi << 32) | lo;
}

// ---------- split (B,387,N) -> coords (B,N,3), feats (B,N,384) ----------
__global__ __launch_bounds__(256) void split_k(const float* __restrict__ pts,
                                               float* __restrict__ coords,
                                               float* __restrict__ feats) {
  __shared__ float t[32][33];
  int b = blockIdx.z;
  int c0 = blockIdx.x*32, n0 = blockIdx.y*32;
  int tx = threadIdx.x, ty = threadIdx.y;
#pragma unroll
  for (int i = 0; i < 4; ++i) {
    int c = c0 + ty + i*8;
    if (c < 387) t[ty+i*8][tx] = pts[((size_t)b*387 + c)*NN + n0 + tx];
  }
  __syncthreads();
#pragma unroll
  for (int i = 0; i < 4; ++i) {
    int n = n0 + ty + i*8;
    int c = c0 + tx;
    if (c < 387) {
      float v = t[tx][ty+i*8];
      if (c < 3) coords[((size_t)b*NN + n)*3 + c] = v;
      else       feats[((size_t)b*NN + n)*DD + (c-3)] = v;
    }
  }
}

// ---------- pack coords+feats -> (B,387,N) ----------
__global__ __launch_bounds__(256) void pack_k(const float* __restrict__ coords,
                                              const float* __restrict__ feats,
                                              float* __restrict__ out) {
  __shared__ float t[32][33];
  int b = blockIdx.z;
  int c0 = blockIdx.x*32, n0 = blockIdx.y*32;
  int tx = threadIdx.x, ty = threadIdx.y;
#pragma unroll
  for (int i = 0; i < 4; ++i) {
    int n = n0 + ty + i*8;
    int c = c0 + tx;
    if (c < 387) {
      float v = (c < 3) ? coords[((size_t)b*NN + n)*3 + c]
                        : feats[((size_t)b*NN + n)*DD + (c-3)];
      t[tx][ty+i*8] = v;
    }
  }
  __syncthreads();
#pragma unroll
  for (int i = 0; i < 4; ++i) {
    int c = c0 + ty + i*8;
    if (c < 387) out[((size_t)b*387 + c)*NN + n0 + tx] = t[ty+i*8][tx];
  }
}

// ---------- LayerNorm body ----------
__device__ __forceinline__ void ln_body(const float* __restrict__ x,
                                        const float* __restrict__ g,
                                        const float* __restrict__ bb,
                                        unsigned short* __restrict__ o,
                                        int row) {
  int lane = threadIdx.x & 63;
  const float* xr = x + (size_t)row*DD;
  float v[6]; float s = 0.f;
#pragma unroll
  for (int i = 0; i < 6; ++i) { v[i] = xr[lane + i*64]; s += v[i]; }
#pragma unroll
  for (int off = 1; off < 64; off <<= 1) s += __shfl_xor(s, off);
  float mean = s * (1.f/384.f);
  float s2 = 0.f;
#pragma unroll
  for (int i = 0; i < 6; ++i) { float d = v[i] - mean; s2 += d*d; }
#pragma unroll
  for (int off = 1; off < 64; off <<= 1) s2 += __shfl_xor(s2, off);
  float rs = rsqrtf(s2*(1.f/384.f) + 1e-5f);
  unsigned short* orow = o + (size_t)row*DD;
#pragma unroll
  for (int i = 0; i < 6; ++i) {
    int c = lane + i*64;
    orow[c] = f2b((v[i]-mean)*rs*g[c] + bb[c]);
  }
}

__global__ __launch_bounds__(256) void ln_k(const float* __restrict__ x,
                                            const float* __restrict__ g,
                                            const float* __restrict__ bb,
                                            unsigned short* __restrict__ o) {
  ln_body(x, g, bb, o, blockIdx.x*4 + (threadIdx.x >> 6));
}

__global__ __launch_bounds__(256) void ln2_k(const float* __restrict__ x1,
                                             const float* __restrict__ g1,
                                             const float* __restrict__ b1,
                                             unsigned short* __restrict__ o1,
                                             const float* __restrict__ x2,
                                             const float* __restrict__ g2,
                                             const float* __restrict__ b2,
                                             unsigned short* __restrict__ o2) {
  int row = blockIdx.x*4 + (threadIdx.x >> 6);
  if (blockIdx.y == 0) ln_body(x1, g1, b1, o1, row);
  else                 ln_body(x2, g2, b2, o2, row);
}

// ---------- one-shot weight transpose+convert ----------
struct WSrcs { const float* p[13]; };

__global__ __launch_bounds__(256) void wtrans_k(WSrcs srcs, unsigned short* __restrict__ dst) {
  constexpr int KK[13]  = {384,384,384,384,768,384,384,384,384,384,768,384,768};
  constexpr int NW[13]  = {1152,384,384,384,384,384,384,384,384,384,384,768,384};
  constexpr int MD[13]  = {0,0,2,0,0,0,0,0,0,2,0,0,0};
  constexpr int OFF[13] = {0,442368,589824,737280,884736,1179648,1327104,1474560,
                           1622016,1769472,1916928,2211840,2506752};
  constexpr int PFX[14] = {0,432,576,720,864,1152,1296,1440,1584,1728,1872,2160,2448,2736};
  int bid = blockIdx.x;
  int e = 0;
  while (bid >= PFX[e+1]) ++e;
  int t = bid - PFX[e];
  int K = KK[e], N = NW[e];
  int ntiles = N >> 5;
  int kt = t / ntiles, nt = t - kt*ntiles;
  const float* src = srcs.p[e];
  __shared__ float T[32][33];
  int tx = threadIdx.x & 31, ty = threadIdx.x >> 5;
  int n = nt*32 + tx;
#pragma unroll
  for (int i = 0; i < 4; ++i) {
    int k = kt*32 + ty + i*8;
    float v = src[(size_t)k*N + n];
    if (MD[e] == 2) v = src[(size_t)(k+384)*N + n] - v;
    T[ty+i*8][tx] = v;
  }
  __syncthreads();
#pragma unroll
  for (int i = 0; i < 4; ++i) {
    int nn = nt*32 + ty + i*8;
    int kk = kt*32 + tx;
    dst[(size_t)OFF[e] + (size_t)nn*K + kk] = f2b(T[tx][ty+i*8]);
  }
}

// ---------- MFMA bf16 GEMM, double-buffered gl16 staging ----------
template<int ACT, int ACC, int OB>
__global__ __launch_bounds__(256) void mgemm_k(const unsigned short* __restrict__ A, int lda,
                                               const unsigned short* __restrict__ Wt,
                                               const float* __restrict__ bias,
                                               void* __restrict__ Cv, int ldc, int cofs,
                                               int Kd) {
  __shared__ char lds[49152];
  int tid = threadIdx.x;
  int lane = tid & 63, w = tid >> 6, g = lane >> 4, c = lane & 15;
  int wr = w >> 1, wc = w & 1;
  int m0 = blockIdx.y*128, n0 = blockIdx.x*64;
  int lrow = lane >> 3;
  int cswz = ((lane & 7) ^ lrow)*8;

  f32x4 acc[4][2];
#pragma unroll
  for (int mt = 0; mt < 4; ++mt)
#pragma unroll
    for (int nt = 0; nt < 2; ++nt) acc[mt][nt] = 0.f;

  int KT = Kd >> 6;
  {
    char* As = lds; char* Bs = lds + 16384;
#pragma unroll
    for (int i = 0; i < 4; ++i) {
      int rb = i*32 + w*8;
      gl16(A + (size_t)(m0 + rb + lrow)*lda + cswz, As + rb*128);
    }
#pragma unroll
    for (int i = 0; i < 2; ++i) {
      int rb = i*32 + w*8;
      gl16(Wt + (size_t)(n0 + rb + lrow)*Kd + cswz, Bs + rb*128);
    }
  }
  __syncthreads();

  for (int kt = 0; kt < KT; ++kt) {
    char* Asc = lds + (kt & 1)*24576;
    char* Bsc = Asc + 16384;
    if (kt + 1 < KT) {
      char* Asn = lds + ((kt + 1) & 1)*24576;
      char* Bsn = Asn + 16384;
      int k0 = (kt + 1)*64;
#pragma unroll
      for (int i = 0; i < 4; ++i) {
        int rb = i*32 + w*8;
        gl16(A + (size_t)(m0 + rb + lrow)*lda + k0 + cswz, Asn + rb*128);
      }
#pragma unroll
      for (int i = 0; i < 2; ++i) {
        int rb = i*32 + w*8;
        gl16(Wt + (size_t)(n0 + rb + lrow)*Kd + k0 + cswz, Bsn + rb*128);
      }
    }
#pragma unroll
    for (int kb = 0; kb < 2; ++kb) {
      bf16x8 af[4], bfr[2];
#pragma unroll
      for (int mt = 0; mt < 4; ++mt) {
        int row = wr*64 + mt*16 + c;
        int ch = (kb*4 + g) ^ (row & 7);
        af[mt] = *(const bf16x8*)(Asc + row*128 + ch*16);
      }
#pragma unroll
      for (int nt = 0; nt < 2; ++nt) {
        int row = wc*32 + nt*16 + c;
        int ch = (kb*4 + g) ^ (row & 7);
        bfr[nt] = *(const bf16x8*)(Bsc + row*128 + ch*16);
      }
#pragma unroll
      for (int mt = 0; mt < 4; ++mt)
#pragma unroll
        for (int nt = 0; nt < 2; ++nt)
          acc[mt][nt] = __builtin_amdgcn_mfma_f32_16x16x32_bf16(af[mt], bfr[nt], acc[mt][nt], 0, 0, 0);
    }
    __syncthreads();
  }

#pragma unroll
  for (int mt = 0; mt < 4; ++mt) {
#pragma unroll
    for (int nt = 0; nt < 2; ++nt) {
      int coln = n0 + wc*32 + nt*16 + c;
      float bval = bias ? bias[coln] : 0.f;
#pragma unroll
      for (int r = 0; r < 4; ++r) {
        int m = m0 + wr*64 + mt*16 + 4*g + r;
        float t = acc[mt][nt][r] + bval;
        if (ACT == 1) t = gelu_t(t);
        if (OB) {
          ((unsigned short*)Cv)[(size_t)m*ldc + cofs + coln] = f2b(t);
        } else {
          float* cp = (float*)Cv + (size_t)m*ldc + cofs + coln;
          if (ACC) t += *cp;
          *cp = t;
        }
      }
    }
  }
}

// ---------- fused 5-segment GEMM (K=384, N=1920); seg 2 writes V^T ----------
struct FSegs {
  const unsigned short* A[5];
  unsigned short* out[5];     // out[2] = vt base
  int ldc[5];
  int cofs[5];
};

__global__ __launch_bounds__(256) void fgemm_k(FSegs fs, const unsigned short* __restrict__ Wt) {
  __shared__ char lds[49152];
  int tid = threadIdx.x;
  int lane = tid & 63, w = tid >> 6, g = lane >> 4, c = lane & 15;
  int wr = w >> 1, wc = w & 1;
  int m0 = blockIdx.y*128, n0 = blockIdx.x*64;
  int seg = n0 / 384;
  const unsigned short* A = fs.A[seg];
  int lrow = lane >> 3;
  int cswz = ((lane & 7) ^ lrow)*8;

  f32x4 acc[4][2];
#pragma unroll
  for (int mt = 0; mt < 4; ++mt)
#pragma unroll
    for (int nt = 0; nt < 2; ++nt) acc[mt][nt] = 0.f;

  {
    char* As = lds; char* Bs = lds + 16384;
#pragma unroll
    for (int i = 0; i < 4; ++i) {
      int rb = i*32 + w*8;
      gl16(A + (size_t)(m0 + rb + lrow)*384 + cswz, As + rb*128);
    }
#pragma unroll
    for (int i = 0; i < 2; ++i) {
      int rb = i*32 + w*8;
      gl16(Wt + (size_t)(n0 + rb + lrow)*384 + cswz, Bs + rb*128);
    }
  }
  __syncthreads();

  for (int kt = 0; kt < 6; ++kt) {
    char* Asc = lds + (kt & 1)*24576;
    char* Bsc = Asc + 16384;
    if (kt + 1 < 6) {
      char* Asn = lds + ((kt + 1) & 1)*24576;
      char* Bsn = Asn + 16384;
      int k0 = (kt + 1)*64;
#pragma unroll
      for (int i = 0; i < 4; ++i) {
        int rb = i*32 + w*8;
        gl16(A + (size_t)(m0 + rb + lrow)*384 + k0 + cswz, Asn + rb*128);
      }
#pragma unroll
      for (int i = 0; i < 2; ++i) {
        int rb = i*32 + w*8;
        gl16(Wt + (size_t)(n0 + rb + lrow)*384 + k0 + cswz, Bsn + rb*128);
      }
    }
#pragma unroll
    for (int kb = 0; kb < 2; ++kb) {
      bf16x8 af[4], bfr[2];
#pragma unroll
      for (int mt = 0; mt < 4; ++mt) {
        int row = wr*64 + mt*16 + c;
        int ch = (kb*4 + g) ^ (row & 7);
        af[mt] = *(const bf16x8*)(Asc + row*128 + ch*16);
      }
#pragma unroll
      for (int nt = 0; nt < 2; ++nt) {
        int row = wc*32 + nt*16 + c;
        int ch = (kb*4 + g) ^ (row & 7);
        bfr[nt] = *(const bf16x8*)(Bsc + row*128 + ch*16);
      }
#pragma unroll
      for (int mt = 0; mt < 4; ++mt)
#pragma unroll
        for (int nt = 0; nt < 2; ++nt)
          acc[mt][nt] = __builtin_amdgcn_mfma_f32_16x16x32_bf16(af[mt], bfr[nt], acc[mt][nt], 0, 0, 0);
    }
    __syncthreads();
  }

  if (seg == 2) {
    // V^T: vt[(b*NH+h)*64 + d][token], packed 4-token 8B stores
    unsigned short* vtp = fs.out[2];
    int bb = m0 >> 11;
    int tokb = (m0 & 2047) + wr*64 + 4*g;
#pragma unroll
    for (int mt = 0; mt < 4; ++mt) {
#pragma unroll
      for (int nt = 0; nt < 2; ++nt) {
        int cseg = (n0 - 768) + wc*32 + nt*16 + c;
        int h = cseg >> 6, d = cseg & 63;
        u32x2 pv;
        pv[0] = cvtpk(acc[mt][nt][0], acc[mt][nt][1]);
        pv[1] = cvtpk(acc[mt][nt][2], acc[mt][nt][3]);
        *(u32x2*)(vtp + ((size_t)((bb*NH + h)*64 + d))*NN + tokb + mt*16) = pv;
      }
    }
    return;
  }

  unsigned short* outp = fs.out[seg];
  int ldcs = fs.ldc[seg];
  int cbase = fs.cofs[seg] + (n0 - seg*384);
#pragma unroll
  for (int mt = 0; mt < 4; ++mt) {
#pragma unroll
    for (int nt = 0; nt < 2; ++nt) {
      int coln = cbase + wc*32 + nt*16 + c;
#pragma unroll
      for (int r = 0; r < 4; ++r) {
        int m = m0 + wr*64 + mt*16 + 4*g + r;
        outp[(size_t)m*ldcs + coln] = f2b(acc[mt][nt][r]);
      }
    }
  }
}

// ---------- MFMA flash attention, dbuf K/V, single barrier/tile ----------
__global__ __launch_bounds__(256) void flashm_k(const unsigned short* __restrict__ qkvb,
                                                const unsigned short* __restrict__ vt,
                                                unsigned short* __restrict__ o) {
  __shared__ char smem[40960];   // KT0|VT0|KT1|VT1 (8KB each) | PT 8KB
  char* PT = smem + 32768;
  int b = blockIdx.z, h = blockIdx.y, q0 = blockIdx.x*64;
  int tid = threadIdx.x;
  int w = tid >> 6, lane = tid & 63, g = lane >> 4, c = lane & 15;

  bf16x8 qf[2];
  {
    const unsigned short* qrow = qkvb + ((size_t)(b*NN + q0 + w*16 + c))*1152 + h*64;
    qf[0] = *(const bf16x8*)(qrow + 8*g);
    qf[1] = *(const bf16x8*)(qrow + 32 + 8*g);
  }
  f32x4 oacc[4];
#pragma unroll
  for (int i = 0; i < 4; ++i) oacc[i] = 0.f;
  float lsum = 0.f;

  int srow = lane >> 3;
  int scol = (lane & 7)*16;
  int r0 = w*16 + srow, r1 = w*16 + 8 + srow;
  int cb0 = scol ^ ((r0 & 7) << 4);
  int cb1 = scol ^ ((r1 & 7) << 4);

  const unsigned short* kbase = qkvb + (size_t)b*NN*1152 + 384 + h*64;
  const unsigned short* vbase = vt + ((size_t)(b*NH + h))*64*NN;

  bf16x8 kreg[2], vreg[2];
  // tile 0 -> regs -> buf0
  kreg[0] = *(const bf16x8*)(kbase + (size_t)r0*1152 + (scol >> 1));
  kreg[1] = *(const bf16x8*)(kbase + (size_t)r1*1152 + (scol >> 1));
  vreg[0] = *(const bf16x8*)(vbase + (size_t)r0*NN + (scol >> 1));
  vreg[1] = *(const bf16x8*)(vbase + (size_t)r1*NN + (scol >> 1));
  {
    char* KT0 = smem; char* VT0 = smem + 8192;
    *(bf16x8*)(KT0 + r0*128 + cb0) = kreg[0];
    *(bf16x8*)(KT0 + r1*128 + cb1) = kreg[1];
    *(bf16x8*)(VT0 + r0*128 + cb0) = vreg[0];
    *(bf16x8*)(VT0 + r1*128 + cb1) = vreg[1];
  }
  // tile 1 -> regs
  kreg[0] = *(const bf16x8*)(kbase + (size_t)(64 + r0)*1152 + (scol >> 1));
  kreg[1] = *(const bf16x8*)(kbase + (size_t)(64 + r1)*1152 + (scol >> 1));
  vreg[0] = *(const bf16x8*)(vbase + (size_t)r0*NN + 64 + (scol >> 1));
  vreg[1] = *(const bf16x8*)(vbase + (size_t)r1*NN + 64 + (scol >> 1));
  __syncthreads();

  for (int kt = 0; kt < 32; ++kt) {
    char* KTc = smem + (kt & 1)*16384;
    char* VTc = KTc + 8192;
    if (kt + 1 < 32) {
      char* KTn = smem + ((kt + 1) & 1)*16384;
      char* VTn = KTn + 8192;
      *(bf16x8*)(KTn + r0*128 + cb0) = kreg[0];
      *(bf16x8*)(KTn + r1*128 + cb1) = kreg[1];
      *(bf16x8*)(VTn + r0*128 + cb0) = vreg[0];
      *(bf16x8*)(VTn + r1*128 + cb1) = vreg[1];
      if (kt + 2 < 32) {
        int kn = kt + 2;
        kreg[0] = *(const bf16x8*)(kbase + (size_t)(kn*64 + r0)*1152 + (scol >> 1));
        kreg[1] = *(const bf16x8*)(kbase + (size_t)(kn*64 + r1)*1152 + (scol >> 1));
        vreg[0] = *(const bf16x8*)(vbase + (size_t)r0*NN + kn*64 + (scol >> 1));
        vreg[1] = *(const bf16x8*)(vbase + (size_t)r1*NN + kn*64 + (scol >> 1));
      }
    }

    f32x4 sT[4];
#pragma unroll
    for (int nt = 0; nt < 4; ++nt) sT[nt] = 0.f;
#pragma unroll
    for (int nt = 0; nt < 4; ++nt) {
      int krow = nt*16 + c;
#pragma unroll
      for (int kb = 0; kb < 2; ++kb) {
        int ch = ((kb*4 + g) ^ (krow & 7))*16;
        bf16x8 kf_ = *(const bf16x8*)(KTc + krow*128 + ch);
        sT[nt] = __builtin_amdgcn_mfma_f32_16x16x32_bf16(kf_, qf[kb], sT[nt], 0, 0, 0);
      }
    }

    int prow = w*16 + c;
    int pswz = (c & 7) << 4;
#pragma unroll
    for (int nt = 0; nt < 4; ++nt) {
      float p0 = __builtin_amdgcn_exp2f(sT[nt][0] * 0.18033688011112042f);
      float p1 = __builtin_amdgcn_exp2f(sT[nt][1] * 0.18033688011112042f);
      float p2 = __builtin_amdgcn_exp2f(sT[nt][2] * 0.18033688011112042f);
      float p3 = __builtin_amdgcn_exp2f(sT[nt][3] * 0.18033688011112042f);
      lsum += (p0 + p1) + (p2 + p3);
      u32x2 pk;
      pk[0] = cvtpk(p0, p1);
      pk[1] = cvtpk(p2, p3);
      *(u32x2*)(PT + prow*128 + ((nt*32 + 8*g) ^ pswz)) = pk;
    }

    bf16x8 pb[2];
#pragma unroll
    for (int kb = 0; kb < 2; ++kb)
      pb[kb] = *(const bf16x8*)(PT + prow*128 + (((kb*4 + g) ^ (c & 7))*16));

#pragma unroll
    for (int dt = 0; dt < 4; ++dt) {
      int vrow = dt*16 + c;
#pragma unroll
      for (int kb = 0; kb < 2; ++kb) {
        int ch = ((kb*4 + g) ^ (vrow & 7))*16;
        bf16x8 vf = *(const bf16x8*)(VTc + vrow*128 + ch);
        oacc[dt] = __builtin_amdgcn_mfma_f32_16x16x32_bf16(vf, pb[kb], oacc[dt], 0, 0, 0);
      }
    }
    __syncthreads();
  }

  lsum += __shfl_xor(lsum, 16);
  lsum += __shfl_xor(lsum, 32);
  float inv = 1.f / lsum;
  size_t orow = ((size_t)b*NN + q0 + w*16 + c)*DD + h*64;
#pragma unroll
  for (int dt = 0; dt < 4; ++dt) {
    u32x2 ov;
    ov[0] = cvtpk(oacc[dt][0]*inv, oacc[dt][1]*inv);
    ov[1] = cvtpk(oacc[dt][2]*inv, oacc[dt][3]*inv);
    *(u32x2*)(o + orow + dt*16 + 4*g) = ov;
  }
}

// ---------- merged KNN top-8: u64 keys, branchless insert, bitonic merge ----------
#define CEX(a, b) { \
  unsigned long long lo_ = bd[a] < bd[b] ? bd[a] : bd[b]; \
  unsigned long long hi_ = bd[a] < bd[b] ? bd[b] : bd[a]; \
  bd[a] = lo_; bd[b] = hi_; }

__global__ __launch_bounds__(256) void knn2_k(const float* __restrict__ qc,
                                              const float* __restrict__ kc,
                                              int* __restrict__ idx1,
                                              int* __restrict__ idx2) {
  const float* kcs = blockIdx.y ? kc : qc;
  int* idxo = blockIdx.y ? idx2 : idx1;
  int lane = threadIdx.x & 63;
  int q = blockIdx.x*4 + (threadIdx.x >> 6);
  int b = q >> 11;
  const float* qp = qc + (size_t)q*3;
  float qx = qp[0], qy = qp[1], qz = qp[2];
  float qq = qx*qx + qy*qy + qz*qz;
  unsigned long long bd[8];
#pragma unroll
  for (int i = 0; i < 8; ++i) bd[i] = ~0ull;
  const float* kb = kcs + (size_t)b*NN*3;
#pragma unroll 4
  for (int j = lane; j < NN; j += 64) {
    float kx = kb[(size_t)j*3], ky = kb[(size_t)j*3+1], kz = kb[(size_t)j*3+2];
    float kk = kx*kx + ky*ky + kz*kz;
    float dt = qx*kx + qy*ky + qz*kz;
    float d2 = qq + kk - 2.f*dt;
    unsigned u = __builtin_bit_cast(unsigned, d2);
    u ^= 0x80000000u | (unsigned)((int)u >> 31);     // monotone flip
    unsigned long long key = ((unsigned long long)u << 32) | (unsigned)j;
    // branchless sorted insert (ascending), largest falls off
#pragma unroll
    for (int k = 0; k < 8; ++k) {
      unsigned long long lo = key < bd[k] ? key : bd[k];
      unsigned long long hi = key < bd[k] ? bd[k] : key;
      bd[k] = lo; key = hi;
    }
  }
  // 6-level bitonic list-merge across lanes (all lanes converge)
#pragma unroll
  for (int m = 1; m <= 32; m <<= 1) {
    unsigned long long pr[8];
#pragma unroll
    for (int i = 0; i < 8; ++i) pr[i] = shfl_xor_u64(bd[7-i], m);
#pragma unroll
    for (int i = 0; i < 8; ++i) bd[i] = bd[i] < pr[i] ? bd[i] : pr[i];
    // bitonic cleanup sort-8 ascending
    CEX(0,4) CEX(1,5) CEX(2,6) CEX(3,7)
    CEX(0,2) CEX(1,3) CEX(4,6) CEX(5,7)
    CEX(0,1) CEX(2,3) CEX(4,5) CEX(6,7)
  }
  if (lane == 0) {
#pragma unroll
    for (int r = 0; r < 8; ++r) idxo[(size_t)q*8 + r] = (int)(unsigned)bd[r];
  }
}

// ---------- geom = max_k lrelu(G[idx_k] + Cb + bias) ----------
__global__ __launch_bounds__(384) void geom_k(const unsigned short* __restrict__ GCb,
                                              const float* __restrict__ bias,
                                              const int* __restrict__ idx,
                                              unsigned short* __restrict__ out) {
  int q = blockIdx.x;
  int b = q >> 11;
  int d = threadIdx.x;
  float c = b2f(GCb[(size_t)q*768 + 384 + d]) + bias[d];
  float mx = -INFINITY;
#pragma unroll
  for (int kn = 0; kn < 8; ++kn) {
    int j = idx[(size_t)q*8 + kn];
    float gg = b2f(GCb[((size_t)(b << 11) + j)*768 + d]);
    float y = gg + c;
    y = (y > 0.f) ? y : 0.2f*y;
    mx = fmaxf(mx, y);
  }
  out[(size_t)q*768 + 384 + d] = f2b(mx);
}

extern "C" void kernel_launch(void* const* d_in, const int* in_sizes, int n_in,
                              void* d_out, int out_size, void* d_ws, size_t ws_size,
                              hipStream_t stream) {
  (void)in_sizes; (void)n_in; (void)out_size; (void)ws_size;
  const float* qpts  = (const float*)d_in[0];
  const float* kpts  = (const float*)d_in[1];
  const float* ln_s  = (const float*)d_in[2];
  const float* ln_b  = (const float*)d_in[3];
  const float* qkvW  = (const float*)d_in[4];
  const float* Wo    = (const float*)d_in[5];
  const float* bo    = (const float*)d_in[6];
  const float* ffW1  = (const float*)d_in[7];
  const float* ffb1  = (const float*)d_in[8];
  const float* ffW2  = (const float*)d_in[9];
  const float* ffb2  = (const float*)d_in[10];
  const float* ffns  = (const float*)d_in[11];
  const float* ffnb  = (const float*)d_in[12];
  const float* knn1W = (const float*)d_in[13];
  const float* knn1b = (const float*)d_in[14];
  const float* knn2W = (const float*)d_in[15];
  const float* knn2b = (const float*)d_in[16];
  const float* smW   = (const float*)d_in[17];
  const float* smb   = (const float*)d_in[18];
  const float* cmW   = (const float*)d_in[19];
  const float* cmb   = (const float*)d_in[20];
  const float* cnqs  = (const float*)d_in[21];
  const float* cnqb  = (const float*)d_in[22];
  const float* cnks  = (const float*)d_in[23];
  const float* cnkb  = (const float*)d_in[24];
  const float* cqW   = (const float*)d_in[25];
  const float* ckW   = (const float*)d_in[26];
  const float* cvW   = (const float*)d_in[27];

  float* ws = (float*)d_ws;
  float* qc   = ws;
  float* kc   = qc + 24576;
  float* qf   = kc + 24576;
  float* kf   = qf + 3145728;
  unsigned short* nrmb = (unsigned short*)(kf + 3145728);
  unsigned short* nkb  = (unsigned short*)(kf + 3145728 + 1572864);
  float* qkv = kf + 3145728 + 1572864 + 1572864;
  unsigned short* qkvb   = (unsigned short*)qkv;
  unsigned short* attnGb = (unsigned short*)qkv;
  unsigned short* vtb    = (unsigned short*)(qkv + 4718592);
  unsigned short* wtb    = (unsigned short*)(qkv + 4718592 + 1572864);
  unsigned short* attnOb = (unsigned short*)(qkv + 4718592 + 1572864 + 1400832);
  unsigned short* GCbb   = (unsigned short*)((float*)attnOb + 1572864);
  int* idx1 = (int*)((float*)GCbb + 3145728);
  int* idx2 = idx1 + 65536;

  const int W_FA=0, W_WO=737280, W_SM=884736, W_FB=1179648,
            W_CM=1916928, W_FF1=2211840, W_FF2=2506752;

  WSrcs srcs;
  srcs.p[0]=qkvW; srcs.p[1]=knn1W; srcs.p[2]=knn1W; srcs.p[3]=Wo; srcs.p[4]=smW;
  srcs.p[5]=cqW; srcs.p[6]=ckW; srcs.p[7]=cvW; srcs.p[8]=knn2W; srcs.p[9]=knn2W;
  srcs.p[10]=cmW; srcs.p[11]=ffW1; srcs.p[12]=ffW2;
  wtrans_k<<<2736, 256, 0, stream>>>(srcs, wtb);

  dim3 tgrid(13, 64, NB), tblk(32, 8);
  split_k<<<tgrid, tblk, 0, stream>>>(qpts, qc, qf);
  split_k<<<tgrid, tblk, 0, stream>>>(kpts, kc, kf);

  knn2_k<<<dim3(2048, 2), 256, 0, stream>>>(qc, kc, idx1, idx2);

  dim3 mg384(6, 64), mg768(12, 64), fg(30, 64);
  dim3 fgrid(32, NH, NB);

  // ---- self attention branch ----
  ln_k<<<2048, 256, 0, stream>>>(qf, ln_s, ln_b, nrmb);
  {
    FSegs fa;
    for (int s = 0; s < 5; ++s) fa.A[s] = nrmb;
    fa.out[0] = qkvb; fa.ldc[0] = 1152; fa.cofs[0] = 0;
    fa.out[1] = qkvb; fa.ldc[1] = 1152; fa.cofs[1] = 384;
    fa.out[2] = vtb;  fa.ldc[2] = 0;    fa.cofs[2] = 0;
    fa.out[3] = GCbb; fa.ldc[3] = 768;  fa.cofs[3] = 0;
    fa.out[4] = GCbb; fa.ldc[4] = 768;  fa.cofs[4] = 384;
    fgemm_k<<<fg, 256, 0, stream>>>(fa, wtb + W_FA);
  }
  flashm_k<<<fgrid, 256, 0, stream>>>(qkvb, vtb, attnOb);
  mgemm_k<0,0,1><<<mg384, 256, 0, stream>>>(attnOb, DD, wtb+W_WO, bo, attnGb, 768, 0, DD);
  geom_k<<<8192, 384, 0, stream>>>(GCbb, knn1b, idx1, attnGb);
  mgemm_k<0,1,0><<<mg384, 256, 0, stream>>>(attnGb, 768, wtb+W_SM, smb, qf, DD, 0, 768);

  // ---- cross attention branch ----
  ln2_k<<<dim3(2048, 2), 256, 0, stream>>>(qf, cnqs, cnqb, nrmb, kf, cnks, cnkb, nkb);
  {
    FSegs fb;
    fb.A[0] = nrmb; fb.A[1] = nkb; fb.A[2] = nkb; fb.A[3] = nkb; fb.A[4] = nrmb;
    fb.out[0] = qkvb; fb.ldc[0] = 1152; fb.cofs[0] = 0;
    fb.out[1] = qkvb; fb.ldc[1] = 1152; fb.cofs[1] = 384;
    fb.out[2] = vtb;  fb.ldc[2] = 0;    fb.cofs[2] = 0;
    fb.out[3] = GCbb; fb.ldc[3] = 768;  fb.cofs[3] = 0;
    fb.out[4] = GCbb; fb.ldc[4] = 768;  fb.cofs[4] = 384;
    fgemm_k<<<fg, 256, 0, stream>>>(fb, wtb + W_FB);
  }
  flashm_k<<<fgrid, 256, 0, stream>>>(qkvb, vtb, attnOb);
  mgemm_k<0,0,1><<<mg384, 256, 0, stream>>>(attnOb, DD, wtb+W_WO, bo, attnGb, 768, 0, DD);
  geom_k<<<8192, 384, 0, stream>>>(GCbb, knn2b, idx2, attnGb);
  mgemm_k<0,1,0><<<mg384, 256, 0, stream>>>(attnGb, 768, wtb+W_CM, cmb, qf, DD, 0, 768);

  // ---- FFN ----
  ln_k<<<2048, 256, 0, stream>>>(qf, ffns, ffnb, nrmb);
  mgemm_k<1,0,1><<<mg768, 256, 0, stream>>>(nrmb, DD, wtb+W_FF1, ffb1, attnGb, 768, 0, DD);
  mgemm_k<0,1,0><<<mg384, 256, 0, stream>>>(attnGb, 768, wtb+W_FF2, ffb2, qf, DD, 0, 768);

  pack_k<<<tgrid, tblk, 0, stream>>>(qc, qf, (float*)d_out);
}

// Round 8
// 379.602 us; speedup vs baseline: 6.4786x; 1.0051x over previous
//
#include <hip/hip_runtime.h>
#include <cstdint>
#include <cstddef>

#define NB 4
#define NN 2048
#define DD 384
#define NH 6

typedef float f4 __attribute__((ext_vector_type(4)));
typedef float f32x4 __attribute__((ext_vector_type(4)));
typedef short bf16x8 __attribute__((ext_vector_type(8)));
typedef unsigned u32x2 __attribute__((ext_vector_type(2)));

__device__ __forceinline__ float gelu_t(float x) {
  float x3 = x*x*x;
  return 0.5f*x*(1.0f + tanhf(0.7978845608028654f*(x + 0.044715f*x3)));
}

__device__ __forceinline__ unsigned short f2b(float f) {
  unsigned u = __builtin_bit_cast(unsigned, f);
  u += 0x7fffu + ((u >> 16) & 1u);
  return (unsigned short)(u >> 16);
}

__device__ __forceinline__ float b2f(unsigned short u) {
  return __builtin_bit_cast(float, ((unsigned)u) << 16);
}

__device__ __forceinline__ unsigned cvtpk(float a, float b) {
  unsigned r;
  asm("v_cvt_pk_bf16_f32 %0, %1, %2" : "=v"(r) : "v"(a), "v"(b));
  return r;
}

typedef __attribute__((address_space(1))) const void gvoid_t;
typedef __attribute__((address_space(3))) void lvoid_t;
__device__ __forceinline__ void gl16(const void* g, void* l) {
  __builtin_amdgcn_global_load_lds((gvoid_t*)g, (lvoid_t*)l, 16, 0, 0);
}

__device__ __forceinline__ unsigned long long shfl_xor_u64(unsigned long long v, int m) {
  unsigned lo = (unsigned)v, hi = (unsigned)(v >> 32);
  lo = (unsigned)__shfl_xor((int)lo, m);
  hi = (unsigned)__shfl_xor((int)hi, m);
  return ((unsigned long long)hi << 32) | lo;
}

// ---------- split (B,387,N) -> coords xyzw (B,N,4), feats (B,N,384) ----------
__global__ __launch_bounds__(256) void split_k(const float* __restrict__ pts,
                                               float* __restrict__ coords,
                                               float* __restrict__ feats) {
  __shared__ float t[32][33];
  int b = blockIdx.z;
  int c0 = blockIdx.x*32, n0 = blockIdx.y*32;
  int tx = threadIdx.x, ty = threadIdx.y;
#pragma unroll
  for (int i = 0; i < 4; ++i) {
    int c = c0 + ty + i*8;
    if (c < 387) t[ty+i*8][tx] = pts[((size_t)b*387 + c)*NN + n0 + tx];
  }
  __syncthreads();
#pragma unroll
  for (int i = 0; i < 4; ++i) {
    int n = n0 + ty + i*8;
    int c = c0 + tx;
    if (c < 387) {
      float v = t[tx][ty+i*8];
      if (c < 3) coords[((size_t)b*NN + n)*4 + c] = v;
      else       feats[((size_t)b*NN + n)*DD + (c-3)] = v;
    }
  }
}

// ---------- fill w = x^2+y^2+z^2 for all 16384 points ----------
__global__ __launch_bounds__(256) void kprep_k(float* __restrict__ c4) {
  int i = blockIdx.x*256 + threadIdx.x;
  f4 v = *(f4*)(c4 + (size_t)i*4);
  v[3] = v[0]*v[0] + v[1]*v[1] + v[2]*v[2];
  *(f4*)(c4 + (size_t)i*4) = v;
}

// ---------- pack coords+feats -> (B,387,N) ----------
__global__ __launch_bounds__(256) void pack_k(const float* __restrict__ coords,
                                              const float* __restrict__ feats,
                                              float* __restrict__ out) {
  __shared__ float t[32][33];
  int b = blockIdx.z;
  int c0 = blockIdx.x*32, n0 = blockIdx.y*32;
  int tx = threadIdx.x, ty = threadIdx.y;
#pragma unroll
  for (int i = 0; i < 4; ++i) {
    int n = n0 + ty + i*8;
    int c = c0 + tx;
    if (c < 387) {
      float v = (c < 3) ? coords[((size_t)b*NN + n)*4 + c]
                        : feats[((size_t)b*NN + n)*DD + (c-3)];
      t[tx][ty+i*8] = v;
    }
  }
  __syncthreads();
#pragma unroll
  for (int i = 0; i < 4; ++i) {
    int c = c0 + ty + i*8;
    if (c < 387) out[((size_t)b*387 + c)*NN + n0 + tx] = t[ty+i*8][tx];
  }
}

// ---------- LayerNorm body ----------
__device__ __forceinline__ void ln_body(const float* __restrict__ x,
                                        const float* __restrict__ g,
                                        const float* __restrict__ bb,
                                        unsigned short* __restrict__ o,
                                        int row) {
  int lane = threadIdx.x & 63;
  const float* xr = x + (size_t)row*DD;
  float v[6]; float s = 0.f;
#pragma unroll
  for (int i = 0; i < 6; ++i) { v[i] = xr[lane + i*64]; s += v[i]; }
#pragma unroll
  for (int off = 1; off < 64; off <<= 1) s += __shfl_xor(s, off);
  float mean = s * (1.f/384.f);
  float s2 = 0.f;
#pragma unroll
  for (int i = 0; i < 6; ++i) { float d = v[i] - mean; s2 += d*d; }
#pragma unroll
  for (int off = 1; off < 64; off <<= 1) s2 += __shfl_xor(s2, off);
  float rs = rsqrtf(s2*(1.f/384.f) + 1e-5f);
  unsigned short* orow = o + (size_t)row*DD;
#pragma unroll
  for (int i = 0; i < 6; ++i) {
    int c = lane + i*64;
    orow[c] = f2b((v[i]-mean)*rs*g[c] + bb[c]);
  }
}

__global__ __launch_bounds__(256) void ln_k(const float* __restrict__ x,
                                            const float* __restrict__ g,
                                            const float* __restrict__ bb,
                                            unsigned short* __restrict__ o) {
  ln_body(x, g, bb, o, blockIdx.x*4 + (threadIdx.x >> 6));
}

__global__ __launch_bounds__(256) void ln2_k(const float* __restrict__ x1,
                                             const float* __restrict__ g1,
                                             const float* __restrict__ b1,
                                             unsigned short* __restrict__ o1,
                                             const float* __restrict__ x2,
                                             const float* __restrict__ g2,
                                             const float* __restrict__ b2,
                                             unsigned short* __restrict__ o2) {
  int row = blockIdx.x*4 + (threadIdx.x >> 6);
  if (blockIdx.y == 0) ln_body(x1, g1, b1, o1, row);
  else                 ln_body(x2, g2, b2, o2, row);
}

// ---------- one-shot weight transpose+convert ----------
struct WSrcs { const float* p[13]; };

__global__ __launch_bounds__(256) void wtrans_k(WSrcs srcs, unsigned short* __restrict__ dst) {
  constexpr int KK[13]  = {384,384,384,384,768,384,384,384,384,384,768,384,768};
  constexpr int NW[13]  = {1152,384,384,384,384,384,384,384,384,384,384,768,384};
  constexpr int MD[13]  = {0,0,2,0,0,0,0,0,0,2,0,0,0};
  constexpr int OFF[13] = {0,442368,589824,737280,884736,1179648,1327104,1474560,
                           1622016,1769472,1916928,2211840,2506752};
  constexpr int PFX[14] = {0,432,576,720,864,1152,1296,1440,1584,1728,1872,2160,2448,2736};
  int bid = blockIdx.x;
  int e = 0;
  while (bid >= PFX[e+1]) ++e;
  int t = bid - PFX[e];
  int K = KK[e], N = NW[e];
  int ntiles = N >> 5;
  int kt = t / ntiles, nt = t - kt*ntiles;
  const float* src = srcs.p[e];
  __shared__ float T[32][33];
  int tx = threadIdx.x & 31, ty = threadIdx.x >> 5;
  int n = nt*32 + tx;
#pragma unroll
  for (int i = 0; i < 4; ++i) {
    int k = kt*32 + ty + i*8;
    float v = src[(size_t)k*N + n];
    if (MD[e] == 2) v = src[(size_t)(k+384)*N + n] - v;
    T[ty+i*8][tx] = v;
  }
  __syncthreads();
#pragma unroll
  for (int i = 0; i < 4; ++i) {
    int nn = nt*32 + ty + i*8;
    int kk = kt*32 + tx;
    dst[(size_t)OFF[e] + (size_t)nn*K + kk] = f2b(T[tx][ty+i*8]);
  }
}

// ---------- MFMA bf16 GEMM, double-buffered gl16 staging ----------
template<int ACT, int ACC, int OB>
__global__ __launch_bounds__(256) void mgemm_k(const unsigned short* __restrict__ A, int lda,
                                               const unsigned short* __restrict__ Wt,
                                               const float* __restrict__ bias,
                                               void* __restrict__ Cv, int ldc, int cofs,
                                               int Kd) {
  __shared__ char lds[49152];
  int tid = threadIdx.x;
  int lane = tid & 63, w = tid >> 6, g = lane >> 4, c = lane & 15;
  int wr = w >> 1, wc = w & 1;
  int m0 = blockIdx.y*128, n0 = blockIdx.x*64;
  int lrow = lane >> 3;
  int cswz = ((lane & 7) ^ lrow)*8;

  f32x4 acc[4][2];
#pragma unroll
  for (int mt = 0; mt < 4; ++mt)
#pragma unroll
    for (int nt = 0; nt < 2; ++nt) acc[mt][nt] = 0.f;

  int KT = Kd >> 6;
  {
    char* As = lds; char* Bs = lds + 16384;
#pragma unroll
    for (int i = 0; i < 4; ++i) {
      int rb = i*32 + w*8;
      gl16(A + (size_t)(m0 + rb + lrow)*lda + cswz, As + rb*128);
    }
#pragma unroll
    for (int i = 0; i < 2; ++i) {
      int rb = i*32 + w*8;
      gl16(Wt + (size_t)(n0 + rb + lrow)*Kd + cswz, Bs + rb*128);
    }
  }
  __syncthreads();

  for (int kt = 0; kt < KT; ++kt) {
    char* Asc = lds + (kt & 1)*24576;
    char* Bsc = Asc + 16384;
    if (kt + 1 < KT) {
      char* Asn = lds + ((kt + 1) & 1)*24576;
      char* Bsn = Asn + 16384;
      int k0 = (kt + 1)*64;
#pragma unroll
      for (int i = 0; i < 4; ++i) {
        int rb = i*32 + w*8;
        gl16(A + (size_t)(m0 + rb + lrow)*lda + k0 + cswz, Asn + rb*128);
      }
#pragma unroll
      for (int i = 0; i < 2; ++i) {
        int rb = i*32 + w*8;
        gl16(Wt + (size_t)(n0 + rb + lrow)*Kd + k0 + cswz, Bsn + rb*128);
      }
    }
#pragma unroll
    for (int kb = 0; kb < 2; ++kb) {
      bf16x8 af[4], bfr[2];
#pragma unroll
      for (int mt = 0; mt < 4; ++mt) {
        int row = wr*64 + mt*16 + c;
        int ch = (kb*4 + g) ^ (row & 7);
        af[mt] = *(const bf16x8*)(Asc + row*128 + ch*16);
      }
#pragma unroll
      for (int nt = 0; nt < 2; ++nt) {
        int row = wc*32 + nt*16 + c;
        int ch = (kb*4 + g) ^ (row & 7);
        bfr[nt] = *(const bf16x8*)(Bsc + row*128 + ch*16);
      }
#pragma unroll
      for (int mt = 0; mt < 4; ++mt)
#pragma unroll
        for (int nt = 0; nt < 2; ++nt)
          acc[mt][nt] = __builtin_amdgcn_mfma_f32_16x16x32_bf16(af[mt], bfr[nt], acc[mt][nt], 0, 0, 0);
    }
    __syncthreads();
  }

#pragma unroll
  for (int mt = 0; mt < 4; ++mt) {
#pragma unroll
    for (int nt = 0; nt < 2; ++nt) {
      int coln = n0 + wc*32 + nt*16 + c;
      float bval = bias ? bias[coln] : 0.f;
#pragma unroll
      for (int r = 0; r < 4; ++r) {
        int m = m0 + wr*64 + mt*16 + 4*g + r;
        float t = acc[mt][nt][r] + bval;
        if (ACT == 1) t = gelu_t(t);
        if (OB) {
          ((unsigned short*)Cv)[(size_t)m*ldc + cofs + coln] = f2b(t);
        } else {
          float* cp = (float*)Cv + (size_t)m*ldc + cofs + coln;
          if (ACC) t += *cp;
          *cp = t;
        }
      }
    }
  }
}

// ---------- fused 5-segment GEMM (K=384, N=1920); seg 2 writes V^T ----------
struct FSegs {
  const unsigned short* A[5];
  unsigned short* out[5];     // out[2] = vt base
  int ldc[5];
  int cofs[5];
};

__global__ __launch_bounds__(256) void fgemm_k(FSegs fs, const unsigned short* __restrict__ Wt) {
  __shared__ char lds[49152];
  int tid = threadIdx.x;
  int lane = tid & 63, w = tid >> 6, g = lane >> 4, c = lane & 15;
  int wr = w >> 1, wc = w & 1;
  int m0 = blockIdx.y*128, n0 = blockIdx.x*64;
  int seg = n0 / 384;
  const unsigned short* A = fs.A[seg];
  int lrow = lane >> 3;
  int cswz = ((lane & 7) ^ lrow)*8;

  f32x4 acc[4][2];
#pragma unroll
  for (int mt = 0; mt < 4; ++mt)
#pragma unroll
    for (int nt = 0; nt < 2; ++nt) acc[mt][nt] = 0.f;

  {
    char* As = lds; char* Bs = lds + 16384;
#pragma unroll
    for (int i = 0; i < 4; ++i) {
      int rb = i*32 + w*8;
      gl16(A + (size_t)(m0 + rb + lrow)*384 + cswz, As + rb*128);
    }
#pragma unroll
    for (int i = 0; i < 2; ++i) {
      int rb = i*32 + w*8;
      gl16(Wt + (size_t)(n0 + rb + lrow)*384 + cswz, Bs + rb*128);
    }
  }
  __syncthreads();

  for (int kt = 0; kt < 6; ++kt) {
    char* Asc = lds + (kt & 1)*24576;
    char* Bsc = Asc + 16384;
    if (kt + 1 < 6) {
      char* Asn = lds + ((kt + 1) & 1)*24576;
      char* Bsn = Asn + 16384;
      int k0 = (kt + 1)*64;
#pragma unroll
      for (int i = 0; i < 4; ++i) {
        int rb = i*32 + w*8;
        gl16(A + (size_t)(m0 + rb + lrow)*384 + k0 + cswz, Asn + rb*128);
      }
#pragma unroll
      for (int i = 0; i < 2; ++i) {
        int rb = i*32 + w*8;
        gl16(Wt + (size_t)(n0 + rb + lrow)*384 + k0 + cswz, Bsn + rb*128);
      }
    }
#pragma unroll
    for (int kb = 0; kb < 2; ++kb) {
      bf16x8 af[4], bfr[2];
#pragma unroll
      for (int mt = 0; mt < 4; ++mt) {
        int row = wr*64 + mt*16 + c;
        int ch = (kb*4 + g) ^ (row & 7);
        af[mt] = *(const bf16x8*)(Asc + row*128 + ch*16);
      }
#pragma unroll
      for (int nt = 0; nt < 2; ++nt) {
        int row = wc*32 + nt*16 + c;
        int ch = (kb*4 + g) ^ (row & 7);
        bfr[nt] = *(const bf16x8*)(Bsc + row*128 + ch*16);
      }
#pragma unroll
      for (int mt = 0; mt < 4; ++mt)
#pragma unroll
        for (int nt = 0; nt < 2; ++nt)
          acc[mt][nt] = __builtin_amdgcn_mfma_f32_16x16x32_bf16(af[mt], bfr[nt], acc[mt][nt], 0, 0, 0);
    }
    __syncthreads();
  }

  if (seg == 2) {
    unsigned short* vtp = fs.out[2];
    int bb = m0 >> 11;
    int tokb = (m0 & 2047) + wr*64 + 4*g;
#pragma unroll
    for (int mt = 0; mt < 4; ++mt) {
#pragma unroll
      for (int nt = 0; nt < 2; ++nt) {
        int cseg = (n0 - 768) + wc*32 + nt*16 + c;
        int h = cseg >> 6, d = cseg & 63;
        u32x2 pv;
        pv[0] = cvtpk(acc[mt][nt][0], acc[mt][nt][1]);
        pv[1] = cvtpk(acc[mt][nt][2], acc[mt][nt][3]);
        *(u32x2*)(vtp + ((size_t)((bb*NH + h)*64 + d))*NN + tokb + mt*16) = pv;
      }
    }
    return;
  }

  unsigned short* outp = fs.out[seg];
  int ldcs = fs.ldc[seg];
  int cbase = fs.cofs[seg] + (n0 - seg*384);
#pragma unroll
  for (int mt = 0; mt < 4; ++mt) {
#pragma unroll
    for (int nt = 0; nt < 2; ++nt) {
      int coln = cbase + wc*32 + nt*16 + c;
#pragma unroll
      for (int r = 0; r < 4; ++r) {
        int m = m0 + wr*64 + mt*16 + 4*g + r;
        outp[(size_t)m*ldcs + coln] = f2b(acc[mt][nt][r]);
      }
    }
  }
}

// ---------- MFMA flash attention: gl16-staged dbuf K/V, XCD-swizzled grid ----------
__global__ __launch_bounds__(256) void flashm_k(const unsigned short* __restrict__ qkvb,
                                                const unsigned short* __restrict__ vt,
                                                unsigned short* __restrict__ o) {
  __shared__ char smem[40960];   // buf0 {KT|VT} 16KB | buf1 16KB | PT 8KB
  char* PT = smem + 32768;
  int bid = blockIdx.x;
  int s = (bid & 7)*96 + (bid >> 3);      // bijective XCD swizzle (768 = 8*96)
  int qt = s & 31; int hb = s >> 5;
  int h = hb % NH, b = hb / NH;
  int q0 = qt*64;
  int tid = threadIdx.x;
  int w = tid >> 6, lane = tid & 63, g = lane >> 4, c = lane & 15;
  int lrow = lane >> 3;
  int gsw = ((lane & 7) ^ lrow)*8;        // pre-swizzled source chunk (ushort elems)

  const unsigned short* kbase = qkvb + (size_t)b*NN*1152 + 384 + h*64;
  const unsigned short* vbase = vt + ((size_t)(b*NH + h))*64*NN;

  bf16x8 qf[2];
  {
    const unsigned short* qrow = qkvb + ((size_t)(b*NN + q0 + w*16 + c))*1152 + h*64;
    qf[0] = *(const bf16x8*)(qrow + 8*g);
    qf[1] = *(const bf16x8*)(qrow + 32 + 8*g);
  }
  f32x4 oacc[4];
#pragma unroll
  for (int i = 0; i < 4; ++i) oacc[i] = 0.f;
  float lsum = 0.f;

#define FSTAGE(bf, ktb) { \
    char* KB = smem + (bf)*16384; char* VB = KB + 8192; \
    gl16(kbase + (size_t)((ktb) + w*16 + lrow)*1152 + gsw,     KB + (w*16)*128); \
    gl16(kbase + (size_t)((ktb) + w*16 + 8 + lrow)*1152 + gsw, KB + (w*16+8)*128); \
    gl16(vbase + (size_t)(w*16 + lrow)*NN + (ktb) + gsw,       VB + (w*16)*128); \
    gl16(vbase + (size_t)(w*16 + 8 + lrow)*NN + (ktb) + gsw,   VB + (w*16+8)*128); }

  FSTAGE(0, 0);
  __syncthreads();

  for (int kt = 0; kt < 32; ++kt) {
    if (kt + 1 < 32) FSTAGE((kt + 1) & 1, (kt + 1)*64);
    char* KTc = smem + (kt & 1)*16384;
    char* VTc = KTc + 8192;

    f32x4 sT[4];
#pragma unroll
    for (int nt = 0; nt < 4; ++nt) sT[nt] = 0.f;
#pragma unroll
    for (int nt = 0; nt < 4; ++nt) {
      int krow = nt*16 + c;
#pragma unroll
      for (int kb = 0; kb < 2; ++kb) {
        int ch = ((kb*4 + g) ^ (krow & 7))*16;
        bf16x8 kf_ = *(const bf16x8*)(KTc + krow*128 + ch);
        sT[nt] = __builtin_amdgcn_mfma_f32_16x16x32_bf16(kf_, qf[kb], sT[nt], 0, 0, 0);
      }
    }

    int prow = w*16 + c;
    int pswz = (c & 7) << 4;
#pragma unroll
    for (int nt = 0; nt < 4; ++nt) {
      float p0 = __builtin_amdgcn_exp2f(sT[nt][0] * 0.18033688011112042f);
      float p1 = __builtin_amdgcn_exp2f(sT[nt][1] * 0.18033688011112042f);
      float p2 = __builtin_amdgcn_exp2f(sT[nt][2] * 0.18033688011112042f);
      float p3 = __builtin_amdgcn_exp2f(sT[nt][3] * 0.18033688011112042f);
      lsum += (p0 + p1) + (p2 + p3);
      u32x2 pk;
      pk[0] = cvtpk(p0, p1);
      pk[1] = cvtpk(p2, p3);
      *(u32x2*)(PT + prow*128 + ((nt*32 + 8*g) ^ pswz)) = pk;
    }

    bf16x8 pb[2];
#pragma unroll
    for (int kb = 0; kb < 2; ++kb)
      pb[kb] = *(const bf16x8*)(PT + prow*128 + (((kb*4 + g) ^ (c & 7))*16));

#pragma unroll
    for (int dt = 0; dt < 4; ++dt) {
      int vrow = dt*16 + c;
#pragma unroll
      for (int kb = 0; kb < 2; ++kb) {
        int ch = ((kb*4 + g) ^ (vrow & 7))*16;
        bf16x8 vf = *(const bf16x8*)(VTc + vrow*128 + ch);
        oacc[dt] = __builtin_amdgcn_mfma_f32_16x16x32_bf16(vf, pb[kb], oacc[dt], 0, 0, 0);
      }
    }
    __syncthreads();
  }
#undef FSTAGE

  lsum += __shfl_xor(lsum, 16);
  lsum += __shfl_xor(lsum, 32);
  float inv = 1.f / lsum;
  size_t orow = ((size_t)b*NN + q0 + w*16 + c)*DD + h*64;
#pragma unroll
  for (int dt = 0; dt < 4; ++dt) {
    u32x2 ov;
    ov[0] = cvtpk(oacc[dt][0]*inv, oacc[dt][1]*inv);
    ov[1] = cvtpk(oacc[dt][2]*inv, oacc[dt][3]*inv);
    *(u32x2*)(o + orow + dt*16 + 4*g) = ov;
  }
}

// ---------- merged KNN top-8: xyzw coords, key = kk - 2*q.k ----------
#define CEX(a, b) { \
  unsigned long long lo_ = bd[a] < bd[b] ? bd[a] : bd[b]; \
  unsigned long long hi_ = bd[a] < bd[b] ? bd[b] : bd[a]; \
  bd[a] = lo_; bd[b] = hi_; }

__global__ __launch_bounds__(256) void knn2_k(const float* __restrict__ qc4,
                                              const float* __restrict__ kc4,
                                              int* __restrict__ idx1,
                                              int* __restrict__ idx2) {
  const float* kcs = blockIdx.y ? kc4 : qc4;
  int* idxo = blockIdx.y ? idx2 : idx1;
  int lane = threadIdx.x & 63;
  int q = blockIdx.x*4 + (threadIdx.x >> 6);
  int b = q >> 11;
  f4 qv = *(const f4*)(qc4 + (size_t)q*4);
  unsigned long long bd[8];
#pragma unroll
  for (int i = 0; i < 8; ++i) bd[i] = ~0ull;
  const float* kb = kcs + (size_t)b*NN*4;
#pragma unroll 4
  for (int j = lane; j < NN; j += 64) {
    f4 kv = *(const f4*)(kb + (size_t)j*4);
    float f = kv[3] - 2.f*(qv[0]*kv[0] + qv[1]*kv[1] + qv[2]*kv[2]);
    unsigned u = __builtin_bit_cast(unsigned, f);
    u ^= 0x80000000u | (unsigned)((int)u >> 31);     // monotone flip (handles negatives)
    unsigned long long key = ((unsigned long long)u << 32) | (unsigned)j;
#pragma unroll
    for (int k = 0; k < 8; ++k) {
      unsigned long long lo = key < bd[k] ? key : bd[k];
      unsigned long long hi = key < bd[k] ? bd[k] : key;
      bd[k] = lo; key = hi;
    }
  }
#pragma unroll
  for (int m = 1; m <= 32; m <<= 1) {
    unsigned long long pr[8];
#pragma unroll
    for (int i = 0; i < 8; ++i) pr[i] = shfl_xor_u64(bd[7-i], m);
#pragma unroll
    for (int i = 0; i < 8; ++i) bd[i] = bd[i] < pr[i] ? bd[i] : pr[i];
    CEX(0,4) CEX(1,5) CEX(2,6) CEX(3,7)
    CEX(0,2) CEX(1,3) CEX(4,6) CEX(5,7)
    CEX(0,1) CEX(2,3) CEX(4,5) CEX(6,7)
  }
  if (lane == 0) {
#pragma unroll
    for (int r = 0; r < 8; ++r) idxo[(size_t)q*8 + r] = (int)(unsigned)bd[r];
  }
}

// ---------- geom = max_k lrelu(G[idx_k] + Cb + bias) ----------
__global__ __launch_bounds__(384) void geom_k(const unsigned short* __restrict__ GCb,
                                              const float* __restrict__ bias,
                                              const int* __restrict__ idx,
                                              unsigned short* __restrict__ out) {
  int q = blockIdx.x;
  int b = q >> 11;
  int d = threadIdx.x;
  float c = b2f(GCb[(size_t)q*768 + 384 + d]) + bias[d];
  float mx = -INFINITY;
#pragma unroll
  for (int kn = 0; kn < 8; ++kn) {
    int j = idx[(size_t)q*8 + kn];
    float gg = b2f(GCb[((size_t)(b << 11) + j)*768 + d]);
    float y = gg + c;
    y = (y > 0.f) ? y : 0.2f*y;
    mx = fmaxf(mx, y);
  }
  out[(size_t)q*768 + 384 + d] = f2b(mx);
}

extern "C" void kernel_launch(void* const* d_in, const int* in_sizes, int n_in,
                              void* d_out, int out_size, void* d_ws, size_t ws_size,
                              hipStream_t stream) {
  (void)in_sizes; (void)n_in; (void)out_size; (void)ws_size;
  const float* qpts  = (const float*)d_in[0];
  const float* kpts  = (const float*)d_in[1];
  const float* ln_s  = (const float*)d_in[2];
  const float* ln_b  = (const float*)d_in[3];
  const float* qkvW  = (const float*)d_in[4];
  const float* Wo    = (const float*)d_in[5];
  const float* bo    = (const float*)d_in[6];
  const float* ffW1  = (const float*)d_in[7];
  const float* ffb1  = (const float*)d_in[8];
  const float* ffW2  = (const float*)d_in[9];
  const float* ffb2  = (const float*)d_in[10];
  const float* ffns  = (const float*)d_in[11];
  const float* ffnb  = (const float*)d_in[12];
  const float* knn1W = (const float*)d_in[13];
  const float* knn1b = (const float*)d_in[14];
  const float* knn2W = (const float*)d_in[15];
  const float* knn2b = (const float*)d_in[16];
  const float* smW   = (const float*)d_in[17];
  const float* smb   = (const float*)d_in[18];
  const float* cmW   = (const float*)d_in[19];
  const float* cmb   = (const float*)d_in[20];
  const float* cnqs  = (const float*)d_in[21];
  const float* cnqb  = (const float*)d_in[22];
  const float* cnks  = (const float*)d_in[23];
  const float* cnkb  = (const float*)d_in[24];
  const float* cqW   = (const float*)d_in[25];
  const float* ckW   = (const float*)d_in[26];
  const float* cvW   = (const float*)d_in[27];

  float* ws = (float*)d_ws;
  float* qc4  = ws;                        // 8192*4
  float* kc4  = qc4 + 32768;               // 8192*4
  float* qf   = kc4 + 32768;
  float* kf   = qf + 3145728;
  unsigned short* nrmb = (unsigned short*)(kf + 3145728);
  unsigned short* nkb  = (unsigned short*)(kf + 3145728 + 1572864);
  float* qkv = kf + 3145728 + 1572864 + 1572864;
  unsigned short* qkvb   = (unsigned short*)qkv;
  unsigned short* attnGb = (unsigned short*)qkv;
  unsigned short* vtb    = (unsigned short*)(qkv + 4718592);
  unsigned short* wtb    = (unsigned short*)(qkv + 4718592 + 1572864);
  unsigned short* attnOb = (unsigned short*)(qkv + 4718592 + 1572864 + 1400832);
  unsigned short* GCbb   = (unsigned short*)((float*)attnOb + 1572864);
  int* idx1 = (int*)((float*)GCbb + 3145728);
  int* idx2 = idx1 + 65536;

  const int W_FA=0, W_WO=737280, W_SM=884736, W_FB=1179648,
            W_CM=1916928, W_FF1=2211840, W_FF2=2506752;

  WSrcs srcs;
  srcs.p[0]=qkvW; srcs.p[1]=knn1W; srcs.p[2]=knn1W; srcs.p[3]=Wo; srcs.p[4]=smW;
  srcs.p[5]=cqW; srcs.p[6]=ckW; srcs.p[7]=cvW; srcs.p[8]=knn2W; srcs.p[9]=knn2W;
  srcs.p[10]=cmW; srcs.p[11]=ffW1; srcs.p[12]=ffW2;
  wtrans_k<<<2736, 256, 0, stream>>>(srcs, wtb);

  dim3 tgrid(13, 64, NB), tblk(32, 8);
  split_k<<<tgrid, tblk, 0, stream>>>(qpts, qc4, qf);
  split_k<<<tgrid, tblk, 0, stream>>>(kpts, kc4, kf);
  kprep_k<<<64, 256, 0, stream>>>(qc4);   // fills w for qc4 AND kc4 (contiguous 16384 pts)

  knn2_k<<<dim3(2048, 2), 256, 0, stream>>>(qc4, kc4, idx1, idx2);

  dim3 mg384(6, 64), mg768(12, 64), fg(30, 64);

  // ---- self attention branch ----
  ln_k<<<2048, 256, 0, stream>>>(qf, ln_s, ln_b, nrmb);
  {
    FSegs fa;
    for (int s = 0; s < 5; ++s) fa.A[s] = nrmb;
    fa.out[0] = qkvb; fa.ldc[0] = 1152; fa.cofs[0] = 0;
    fa.out[1] = qkvb; fa.ldc[1] = 1152; fa.cofs[1] = 384;
    fa.out[2] = vtb;  fa.ldc[2] = 0;    fa.cofs[2] = 0;
    fa.out[3] = GCbb; fa.ldc[3] = 768;  fa.cofs[3] = 0;
    fa.out[4] = GCbb; fa.ldc[4] = 768;  fa.cofs[4] = 384;
    fgemm_k<<<fg, 256, 0, stream>>>(fa, wtb + W_FA);
  }
  flashm_k<<<768, 256, 0, stream>>>(qkvb, vtb, attnOb);
  mgemm_k<0,0,1><<<mg384, 256, 0, stream>>>(attnOb, DD, wtb+W_WO, bo, attnGb, 768, 0, DD);
  geom_k<<<8192, 384, 0, stream>>>(GCbb, knn1b, idx1, attnGb);
  mgemm_k<0,1,0><<<mg384, 256, 0, stream>>>(attnGb, 768, wtb+W_SM, smb, qf, DD, 0, 768);

  // ---- cross attention branch ----
  ln2_k<<<dim3(2048, 2), 256, 0, stream>>>(qf, cnqs, cnqb, nrmb, kf, cnks, cnkb, nkb);
  {
    FSegs fb;
    fb.A[0] = nrmb; fb.A[1] = nkb; fb.A[2] = nkb; fb.A[3] = nkb; fb.A[4] = nrmb;
    fb.out[0] = qkvb; fb.ldc[0] = 1152; fb.cofs[0] = 0;
    fb.out[1] = qkvb; fb.ldc[1] = 1152; fb.cofs[1] = 384;
    fb.out[2] = vtb;  fb.ldc[2] = 0;    fb.cofs[2] = 0;
    fb.out[3] = GCbb; fb.ldc[3] = 768;  fb.cofs[3] = 0;
    fb.out[4] = GCbb; fb.ldc[4] = 768;  fb.cofs[4] = 384;
    fgemm_k<<<fg, 256, 0, stream>>>(fb, wtb + W_FB);
  }
  flashm_k<<<768, 256, 0, stream>>>(qkvb, vtb, attnOb);
  mgemm_k<0,0,1><<<mg384, 256, 0, stream>>>(attnOb, DD, wtb+W_WO, bo, attnGb, 768, 0, DD);
  geom_k<<<8192, 384, 0, stream>>>(GCbb, knn2b, idx2, attnGb);
  mgemm_k<0,1,0><<<mg384, 256, 0, stream>>>(attnGb, 768, wtb+W_CM, cmb, qf, DD, 0, 768);

  // ---- FFN ----
  ln_k<<<2048, 256, 0, stream>>>(qf, ffns, ffnb, nrmb);
  mgemm_k<1,0,1><<<mg768, 256, 0, stream>>>(nrmb, DD, wtb+W_FF1, ffb1, attnGb, 768, 0, DD);
  mgemm_k<0,1,0><<<mg384, 256, 0, stream>>>(attnGb, 768, wtb+W_FF2, ffb2, qf, DD, 0, 768);

  pack_k<<<tgrid, tblk, 0, stream>>>(qc4, qf, (float*)d_out);
}

// Round 9
// 352.056 us; speedup vs baseline: 6.9856x; 1.0782x over previous
//
#include <hip/hip_runtime.h>
#include <cstdint>
#include <cstddef>

#define NB 4
#define NN 2048
#define DD 384
#define NH 6

typedef float f4 __attribute__((ext_vector_type(4)));
typedef float f32x4 __attribute__((ext_vector_type(4)));
typedef short bf16x8 __attribute__((ext_vector_type(8)));
typedef unsigned u32x2 __attribute__((ext_vector_type(2)));

__device__ __forceinline__ float gelu_t(float x) {
  float x3 = x*x*x;
  return 0.5f*x*(1.0f + tanhf(0.7978845608028654f*(x + 0.044715f*x3)));
}

__device__ __forceinline__ unsigned short f2b(float f) {
  unsigned u = __builtin_bit_cast(unsigned, f);
  u += 0x7fffu + ((u >> 16) & 1u);
  return (unsigned short)(u >> 16);
}

__device__ __forceinline__ float b2f(unsigned short u) {
  return __builtin_bit_cast(float, ((unsigned)u) << 16);
}

__device__ __forceinline__ unsigned cvtpk(float a, float b) {
  unsigned r;
  asm("v_cvt_pk_bf16_f32 %0, %1, %2" : "=v"(r) : "v"(a), "v"(b));
  return r;
}

typedef __attribute__((address_space(1))) const void gvoid_t;
typedef __attribute__((address_space(3))) void lvoid_t;
__device__ __forceinline__ void gl16(const void* g, void* l) {
  __builtin_amdgcn_global_load_lds((gvoid_t*)g, (lvoid_t*)l, 16, 0, 0);
}

__device__ __forceinline__ unsigned long long shfl_xor_u64(unsigned long long v, int m) {
  unsigned lo = (unsigned)v, hi = (unsigned)(v >> 32);
  lo = (unsigned)__shfl_xor((int)lo, m);
  hi = (unsigned)__shfl_xor((int)hi, m);
  return ((unsigned long long)hi << 32) | lo;
}

// ---------- split (B,387,N) -> coords xyzw (B,N,4), feats (B,N,384) ----------
__global__ __launch_bounds__(256) void split_k(const float* __restrict__ pts,
                                               float* __restrict__ coords,
                                               float* __restrict__ feats) {
  __shared__ float t[32][33];
  int b = blockIdx.z;
  int c0 = blockIdx.x*32, n0 = blockIdx.y*32;
  int tx = threadIdx.x, ty = threadIdx.y;
#pragma unroll
  for (int i = 0; i < 4; ++i) {
    int c = c0 + ty + i*8;
    if (c < 387) t[ty+i*8][tx] = pts[((size_t)b*387 + c)*NN + n0 + tx];
  }
  __syncthreads();
#pragma unroll
  for (int i = 0; i < 4; ++i) {
    int n = n0 + ty + i*8;
    int c = c0 + tx;
    if (c < 387) {
      float v = t[tx][ty+i*8];
      if (c < 3) coords[((size_t)b*NN + n)*4 + c] = v;
      else       feats[((size_t)b*NN + n)*DD + (c-3)] = v;
    }
  }
}

// ---------- fill w = x^2+y^2+z^2 for all 16384 points ----------
__global__ __launch_bounds__(256) void kprep_k(float* __restrict__ c4) {
  int i = blockIdx.x*256 + threadIdx.x;
  f4 v = *(f4*)(c4 + (size_t)i*4);
  v[3] = v[0]*v[0] + v[1]*v[1] + v[2]*v[2];
  *(f4*)(c4 + (size_t)i*4) = v;
}

// ---------- pack coords+feats -> (B,387,N) ----------
__global__ __launch_bounds__(256) void pack_k(const float* __restrict__ coords,
                                              const float* __restrict__ feats,
                                              float* __restrict__ out) {
  __shared__ float t[32][33];
  int b = blockIdx.z;
  int c0 = blockIdx.x*32, n0 = blockIdx.y*32;
  int tx = threadIdx.x, ty = threadIdx.y;
#pragma unroll
  for (int i = 0; i < 4; ++i) {
    int n = n0 + ty + i*8;
    int c = c0 + tx;
    if (c < 387) {
      float v = (c < 3) ? coords[((size_t)b*NN + n)*4 + c]
                        : feats[((size_t)b*NN + n)*DD + (c-3)];
      t[tx][ty+i*8] = v;
    }
  }
  __syncthreads();
#pragma unroll
  for (int i = 0; i < 4; ++i) {
    int c = c0 + ty + i*8;
    if (c < 387) out[((size_t)b*387 + c)*NN + n0 + tx] = t[ty+i*8][tx];
  }
}

// ---------- LayerNorm body ----------
__device__ __forceinline__ void ln_body(const float* __restrict__ x,
                                        const float* __restrict__ g,
                                        const float* __restrict__ bb,
                                        unsigned short* __restrict__ o,
                                        int row) {
  int lane = threadIdx.x & 63;
  const float* xr = x + (size_t)row*DD;
  float v[6]; float s = 0.f;
#pragma unroll
  for (int i = 0; i < 6; ++i) { v[i] = xr[lane + i*64]; s += v[i]; }
#pragma unroll
  for (int off = 1; off < 64; off <<= 1) s += __shfl_xor(s, off);
  float mean = s * (1.f/384.f);
  float s2 = 0.f;
#pragma unroll
  for (int i = 0; i < 6; ++i) { float d = v[i] - mean; s2 += d*d; }
#pragma unroll
  for (int off = 1; off < 64; off <<= 1) s2 += __shfl_xor(s2, off);
  float rs = rsqrtf(s2*(1.f/384.f) + 1e-5f);
  unsigned short* orow = o + (size_t)row*DD;
#pragma unroll
  for (int i = 0; i < 6; ++i) {
    int c = lane + i*64;
    orow[c] = f2b((v[i]-mean)*rs*g[c] + bb[c]);
  }
}

__global__ __launch_bounds__(256) void ln_k(const float* __restrict__ x,
                                            const float* __restrict__ g,
                                            const float* __restrict__ bb,
                                            unsigned short* __restrict__ o) {
  ln_body(x, g, bb, o, blockIdx.x*4 + (threadIdx.x >> 6));
}

__global__ __launch_bounds__(256) void ln2_k(const float* __restrict__ x1,
                                             const float* __restrict__ g1,
                                             const float* __restrict__ b1,
                                             unsigned short* __restrict__ o1,
                                             const float* __restrict__ x2,
                                             const float* __restrict__ g2,
                                             const float* __restrict__ b2,
                                             unsigned short* __restrict__ o2) {
  int row = blockIdx.x*4 + (threadIdx.x >> 6);
  if (blockIdx.y == 0) ln_body(x1, g1, b1, o1, row);
  else                 ln_body(x2, g2, b2, o2, row);
}

// ---------- one-shot weight transpose+convert ----------
struct WSrcs { const float* p[13]; };

__global__ __launch_bounds__(256) void wtrans_k(WSrcs srcs, unsigned short* __restrict__ dst) {
  constexpr int KK[13]  = {384,384,384,384,768,384,384,384,384,384,768,384,768};
  constexpr int NW[13]  = {1152,384,384,384,384,384,384,384,384,384,384,768,384};
  constexpr int MD[13]  = {0,0,2,0,0,0,0,0,0,2,0,0,0};
  constexpr int OFF[13] = {0,442368,589824,737280,884736,1179648,1327104,1474560,
                           1622016,1769472,1916928,2211840,2506752};
  constexpr int PFX[14] = {0,432,576,720,864,1152,1296,1440,1584,1728,1872,2160,2448,2736};
  int bid = blockIdx.x;
  int e = 0;
  while (bid >= PFX[e+1]) ++e;
  int t = bid - PFX[e];
  int K = KK[e], N = NW[e];
  int ntiles = N >> 5;
  int kt = t / ntiles, nt = t - kt*ntiles;
  const float* src = srcs.p[e];
  __shared__ float T[32][33];
  int tx = threadIdx.x & 31, ty = threadIdx.x >> 5;
  int n = nt*32 + tx;
#pragma unroll
  for (int i = 0; i < 4; ++i) {
    int k = kt*32 + ty + i*8;
    float v = src[(size_t)k*N + n];
    if (MD[e] == 2) v = src[(size_t)(k+384)*N + n] - v;
    T[ty+i*8][tx] = v;
  }
  __syncthreads();
#pragma unroll
  for (int i = 0; i < 4; ++i) {
    int nn = nt*32 + ty + i*8;
    int kk = kt*32 + tx;
    dst[(size_t)OFF[e] + (size_t)nn*K + kk] = f2b(T[tx][ty+i*8]);
  }
}

// ---------- MFMA bf16 GEMM, double-buffered gl16 staging ----------
// HALFM=0: 128x64 block (4 waves 2x2, wave 64x32). HALFM=1: 64x64 block (wave 32x32).
template<int ACT, int ACC, int OB, int HALFM>
__global__ __launch_bounds__(256) void mgemm_k(const unsigned short* __restrict__ A, int lda,
                                               const unsigned short* __restrict__ Wt,
                                               const float* __restrict__ bias,
                                               void* __restrict__ Cv, int ldc, int cofs,
                                               int Kd) {
  constexpr int BM   = HALFM ? 64 : 128;
  constexpr int MT   = HALFM ? 2 : 4;
  constexpr int AG   = HALFM ? 2 : 4;
  constexpr int ABUF = BM*128;
  constexpr int BUFSZ = ABUF + 8192;
  __shared__ char lds[2*BUFSZ];
  int tid = threadIdx.x;
  int lane = tid & 63, w = tid >> 6, g = lane >> 4, c = lane & 15;
  int wr = w >> 1, wc = w & 1;
  int m0 = blockIdx.y*BM, n0 = blockIdx.x*64;
  int lrow = lane >> 3;
  int cswz = ((lane & 7) ^ lrow)*8;

  f32x4 acc[MT][2];
#pragma unroll
  for (int mt = 0; mt < MT; ++mt)
#pragma unroll
    for (int nt = 0; nt < 2; ++nt) acc[mt][nt] = 0.f;

  int KT = Kd >> 6;
  {
    char* As = lds; char* Bs = lds + ABUF;
#pragma unroll
    for (int i = 0; i < AG; ++i) {
      int rb = i*32 + w*8;
      gl16(A + (size_t)(m0 + rb + lrow)*lda + cswz, As + rb*128);
    }
#pragma unroll
    for (int i = 0; i < 2; ++i) {
      int rb = i*32 + w*8;
      gl16(Wt + (size_t)(n0 + rb + lrow)*Kd + cswz, Bs + rb*128);
    }
  }
  __syncthreads();

  for (int kt = 0; kt < KT; ++kt) {
    char* Asc = lds + (kt & 1)*BUFSZ;
    char* Bsc = Asc + ABUF;
    if (kt + 1 < KT) {
      char* Asn = lds + ((kt + 1) & 1)*BUFSZ;
      char* Bsn = Asn + ABUF;
      int k0 = (kt + 1)*64;
#pragma unroll
      for (int i = 0; i < AG; ++i) {
        int rb = i*32 + w*8;
        gl16(A + (size_t)(m0 + rb + lrow)*lda + k0 + cswz, Asn + rb*128);
      }
#pragma unroll
      for (int i = 0; i < 2; ++i) {
        int rb = i*32 + w*8;
        gl16(Wt + (size_t)(n0 + rb + lrow)*Kd + k0 + cswz, Bsn + rb*128);
      }
    }
#pragma unroll
    for (int kb = 0; kb < 2; ++kb) {
      bf16x8 af[MT], bfr[2];
#pragma unroll
      for (int mt = 0; mt < MT; ++mt) {
        int row = wr*(BM/2) + mt*16 + c;
        int ch = (kb*4 + g) ^ (row & 7);
        af[mt] = *(const bf16x8*)(Asc + row*128 + ch*16);
      }
#pragma unroll
      for (int nt = 0; nt < 2; ++nt) {
        int row = wc*32 + nt*16 + c;
        int ch = (kb*4 + g) ^ (row & 7);
        bfr[nt] = *(const bf16x8*)(Bsc + row*128 + ch*16);
      }
#pragma unroll
      for (int mt = 0; mt < MT; ++mt)
#pragma unroll
        for (int nt = 0; nt < 2; ++nt)
          acc[mt][nt] = __builtin_amdgcn_mfma_f32_16x16x32_bf16(af[mt], bfr[nt], acc[mt][nt], 0, 0, 0);
    }
    __syncthreads();
  }

#pragma unroll
  for (int mt = 0; mt < MT; ++mt) {
#pragma unroll
    for (int nt = 0; nt < 2; ++nt) {
      int coln = n0 + wc*32 + nt*16 + c;
      float bval = bias ? bias[coln] : 0.f;
#pragma unroll
      for (int r = 0; r < 4; ++r) {
        int m = m0 + wr*(BM/2) + mt*16 + 4*g + r;
        float t = acc[mt][nt][r] + bval;
        if (ACT == 1) t = gelu_t(t);
        if (OB) {
          ((unsigned short*)Cv)[(size_t)m*ldc + cofs + coln] = f2b(t);
        } else {
          float* cp = (float*)Cv + (size_t)m*ldc + cofs + coln;
          if (ACC) t += *cp;
          *cp = t;
        }
      }
    }
  }
}

// ---------- fused 5-segment GEMM (K=384, N=1920); seg 2 writes V^T ----------
struct FSegs {
  const unsigned short* A[5];
  unsigned short* out[5];     // out[2] = vt base
  int ldc[5];
  int cofs[5];
};

__global__ __launch_bounds__(256) void fgemm_k(FSegs fs, const unsigned short* __restrict__ Wt) {
  __shared__ char lds[49152];
  int tid = threadIdx.x;
  int lane = tid & 63, w = tid >> 6, g = lane >> 4, c = lane & 15;
  int wr = w >> 1, wc = w & 1;
  int m0 = blockIdx.y*128, n0 = blockIdx.x*64;
  int seg = n0 / 384;
  const unsigned short* A = fs.A[seg];
  int lrow = lane >> 3;
  int cswz = ((lane & 7) ^ lrow)*8;

  f32x4 acc[4][2];
#pragma unroll
  for (int mt = 0; mt < 4; ++mt)
#pragma unroll
    for (int nt = 0; nt < 2; ++nt) acc[mt][nt] = 0.f;

  {
    char* As = lds; char* Bs = lds + 16384;
#pragma unroll
    for (int i = 0; i < 4; ++i) {
      int rb = i*32 + w*8;
      gl16(A + (size_t)(m0 + rb + lrow)*384 + cswz, As + rb*128);
    }
#pragma unroll
    for (int i = 0; i < 2; ++i) {
      int rb = i*32 + w*8;
      gl16(Wt + (size_t)(n0 + rb + lrow)*384 + cswz, Bs + rb*128);
    }
  }
  __syncthreads();

  for (int kt = 0; kt < 6; ++kt) {
    char* Asc = lds + (kt & 1)*24576;
    char* Bsc = Asc + 16384;
    if (kt + 1 < 6) {
      char* Asn = lds + ((kt + 1) & 1)*24576;
      char* Bsn = Asn + 16384;
      int k0 = (kt + 1)*64;
#pragma unroll
      for (int i = 0; i < 4; ++i) {
        int rb = i*32 + w*8;
        gl16(A + (size_t)(m0 + rb + lrow)*384 + k0 + cswz, Asn + rb*128);
      }
#pragma unroll
      for (int i = 0; i < 2; ++i) {
        int rb = i*32 + w*8;
        gl16(Wt + (size_t)(n0 + rb + lrow)*384 + k0 + cswz, Bsn + rb*128);
      }
    }
#pragma unroll
    for (int kb = 0; kb < 2; ++kb) {
      bf16x8 af[4], bfr[2];
#pragma unroll
      for (int mt = 0; mt < 4; ++mt) {
        int row = wr*64 + mt*16 + c;
        int ch = (kb*4 + g) ^ (row & 7);
        af[mt] = *(const bf16x8*)(Asc + row*128 + ch*16);
      }
#pragma unroll
      for (int nt = 0; nt < 2; ++nt) {
        int row = wc*32 + nt*16 + c;
        int ch = (kb*4 + g) ^ (row & 7);
        bfr[nt] = *(const bf16x8*)(Bsc + row*128 + ch*16);
      }
#pragma unroll
      for (int mt = 0; mt < 4; ++mt)
#pragma unroll
        for (int nt = 0; nt < 2; ++nt)
          acc[mt][nt] = __builtin_amdgcn_mfma_f32_16x16x32_bf16(af[mt], bfr[nt], acc[mt][nt], 0, 0, 0);
    }
    __syncthreads();
  }

  if (seg == 2) {
    unsigned short* vtp = fs.out[2];
    int bb = m0 >> 11;
    int tokb = (m0 & 2047) + wr*64 + 4*g;
#pragma unroll
    for (int mt = 0; mt < 4; ++mt) {
#pragma unroll
      for (int nt = 0; nt < 2; ++nt) {
        int cseg = (n0 - 768) + wc*32 + nt*16 + c;
        int h = cseg >> 6, d = cseg & 63;
        u32x2 pv;
        pv[0] = cvtpk(acc[mt][nt][0], acc[mt][nt][1]);
        pv[1] = cvtpk(acc[mt][nt][2], acc[mt][nt][3]);
        *(u32x2*)(vtp + ((size_t)((bb*NH + h)*64 + d))*NN + tokb + mt*16) = pv;
      }
    }
    return;
  }

  unsigned short* outp = fs.out[seg];
  int ldcs = fs.ldc[seg];
  int cbase = fs.cofs[seg] + (n0 - seg*384);
#pragma unroll
  for (int mt = 0; mt < 4; ++mt) {
#pragma unroll
    for (int nt = 0; nt < 2; ++nt) {
      int coln = cbase + wc*32 + nt*16 + c;
#pragma unroll
      for (int r = 0; r < 4; ++r) {
        int m = m0 + wr*64 + mt*16 + 4*g + r;
        outp[(size_t)m*ldcs + coln] = f2b(acc[mt][nt][r]);
      }
    }
  }
}

// ---------- MFMA flash attention: gl16-staged dbuf K/V, XCD-swizzled grid ----------
__global__ __launch_bounds__(256) void flashm_k(const unsigned short* __restrict__ qkvb,
                                                const unsigned short* __restrict__ vt,
                                                unsigned short* __restrict__ o) {
  __shared__ char smem[40960];
  char* PT = smem + 32768;
  int bid = blockIdx.x;
  int s = (bid & 7)*96 + (bid >> 3);
  int qt = s & 31; int hb = s >> 5;
  int h = hb % NH, b = hb / NH;
  int q0 = qt*64;
  int tid = threadIdx.x;
  int w = tid >> 6, lane = tid & 63, g = lane >> 4, c = lane & 15;
  int lrow = lane >> 3;
  int gsw = ((lane & 7) ^ lrow)*8;

  const unsigned short* kbase = qkvb + (size_t)b*NN*1152 + 384 + h*64;
  const unsigned short* vbase = vt + ((size_t)(b*NH + h))*64*NN;

  bf16x8 qf[2];
  {
    const unsigned short* qrow = qkvb + ((size_t)(b*NN + q0 + w*16 + c))*1152 + h*64;
    qf[0] = *(const bf16x8*)(qrow + 8*g);
    qf[1] = *(const bf16x8*)(qrow + 32 + 8*g);
  }
  f32x4 oacc[4];
#pragma unroll
  for (int i = 0; i < 4; ++i) oacc[i] = 0.f;
  float lsum = 0.f;

#define FSTAGE(bf, ktb) { \
    char* KB = smem + (bf)*16384; char* VB = KB + 8192; \
    gl16(kbase + (size_t)((ktb) + w*16 + lrow)*1152 + gsw,     KB + (w*16)*128); \
    gl16(kbase + (size_t)((ktb) + w*16 + 8 + lrow)*1152 + gsw, KB + (w*16+8)*128); \
    gl16(vbase + (size_t)(w*16 + lrow)*NN + (ktb) + gsw,       VB + (w*16)*128); \
    gl16(vbase + (size_t)(w*16 + 8 + lrow)*NN + (ktb) + gsw,   VB + (w*16+8)*128); }

  FSTAGE(0, 0);
  __syncthreads();

  for (int kt = 0; kt < 32; ++kt) {
    if (kt + 1 < 32) FSTAGE((kt + 1) & 1, (kt + 1)*64);
    char* KTc = smem + (kt & 1)*16384;
    char* VTc = KTc + 8192;

    f32x4 sT[4];
#pragma unroll
    for (int nt = 0; nt < 4; ++nt) sT[nt] = 0.f;
#pragma unroll
    for (int nt = 0; nt < 4; ++nt) {
      int krow = nt*16 + c;
#pragma unroll
      for (int kb = 0; kb < 2; ++kb) {
        int ch = ((kb*4 + g) ^ (krow & 7))*16;
        bf16x8 kf_ = *(const bf16x8*)(KTc + krow*128 + ch);
        sT[nt] = __builtin_amdgcn_mfma_f32_16x16x32_bf16(kf_, qf[kb], sT[nt], 0, 0, 0);
      }
    }

    int prow = w*16 + c;
    int pswz = (c & 7) << 4;
#pragma unroll
    for (int nt = 0; nt < 4; ++nt) {
      float p0 = __builtin_amdgcn_exp2f(sT[nt][0] * 0.18033688011112042f);
      float p1 = __builtin_amdgcn_exp2f(sT[nt][1] * 0.18033688011112042f);
      float p2 = __builtin_amdgcn_exp2f(sT[nt][2] * 0.18033688011112042f);
      float p3 = __builtin_amdgcn_exp2f(sT[nt][3] * 0.18033688011112042f);
      lsum += (p0 + p1) + (p2 + p3);
      u32x2 pk;
      pk[0] = cvtpk(p0, p1);
      pk[1] = cvtpk(p2, p3);
      *(u32x2*)(PT + prow*128 + ((nt*32 + 8*g) ^ pswz)) = pk;
    }

    bf16x8 pb[2];
#pragma unroll
    for (int kb = 0; kb < 2; ++kb)
      pb[kb] = *(const bf16x8*)(PT + prow*128 + (((kb*4 + g) ^ (c & 7))*16));

#pragma unroll
    for (int dt = 0; dt < 4; ++dt) {
      int vrow = dt*16 + c;
#pragma unroll
      for (int kb = 0; kb < 2; ++kb) {
        int ch = ((kb*4 + g) ^ (vrow & 7))*16;
        bf16x8 vf = *(const bf16x8*)(VTc + vrow*128 + ch);
        oacc[dt] = __builtin_amdgcn_mfma_f32_16x16x32_bf16(vf, pb[kb], oacc[dt], 0, 0, 0);
      }
    }
    __syncthreads();
  }
#undef FSTAGE

  lsum += __shfl_xor(lsum, 16);
  lsum += __shfl_xor(lsum, 32);
  float inv = 1.f / lsum;
  size_t orow = ((size_t)b*NN + q0 + w*16 + c)*DD + h*64;
#pragma unroll
  for (int dt = 0; dt < 4; ++dt) {
    u32x2 ov;
    ov[0] = cvtpk(oacc[dt][0]*inv, oacc[dt][1]*inv);
    ov[1] = cvtpk(oacc[dt][2]*inv, oacc[dt][3]*inv);
    *(u32x2*)(o + orow + dt*16 + 4*g) = ov;
  }
}

// ---------- merged KNN top-8: float-value filter + exact u64 pass ----------
#define CEXF(a, b) { \
  float lo_ = fminf(bf[a], bf[b]); \
  float hi_ = fmaxf(bf[a], bf[b]); \
  bf[a] = lo_; bf[b] = hi_; }

#define CEX(a, b) { \
  unsigned long long lo_ = bd[a] < bd[b] ? bd[a] : bd[b]; \
  unsigned long long hi_ = bd[a] < bd[b] ? bd[b] : bd[a]; \
  bd[a] = lo_; bd[b] = hi_; }

__global__ __launch_bounds__(256) void knn2_k(const float* __restrict__ qc4,
                                              const float* __restrict__ kc4,
                                              int* __restrict__ idx1,
                                              int* __restrict__ idx2) {
  const float* kcs = blockIdx.y ? kc4 : qc4;
  int* idxo = blockIdx.y ? idx2 : idx1;
  int lane = threadIdx.x & 63;
  int q = blockIdx.x*4 + (threadIdx.x >> 6);
  int b = q >> 11;
  f4 qv = *(const f4*)(qc4 + (size_t)q*4);
  float mx_ = -2.f*qv[0], my_ = -2.f*qv[1], mz_ = -2.f*qv[2];
  const float* kb = kcs + (size_t)b*NN*4;

  // phase 1: per-lane top-8 VALUES (f32 min/max network), then wave merge
  float fv[32];
  float bf[8];
#pragma unroll
  for (int i = 0; i < 8; ++i) bf[i] = INFINITY;
#pragma unroll
  for (int i = 0; i < 32; ++i) {
    f4 kv = *(const f4*)(kb + (size_t)(lane + i*64)*4);
    float f = fmaf(mx_, kv[0], fmaf(my_, kv[1], fmaf(mz_, kv[2], kv[3])));
    fv[i] = f;
#pragma unroll
    for (int k = 0; k < 8; ++k) {
      float lo = fminf(f, bf[k]);
      float hi = fmaxf(f, bf[k]);
      bf[k] = lo; f = hi;
    }
  }
#pragma unroll
  for (int m = 1; m <= 32; m <<= 1) {
    float pr[8];
#pragma unroll
    for (int i = 0; i < 8; ++i) pr[i] = __shfl_xor(bf[7-i], m);
#pragma unroll
    for (int i = 0; i < 8; ++i) bf[i] = fminf(bf[i], pr[i]);
    CEXF(0,4) CEXF(1,5) CEXF(2,6) CEXF(3,7)
    CEXF(0,2) CEXF(1,3) CEXF(4,6) CEXF(5,7)
    CEXF(0,1) CEXF(2,3) CEXF(4,5) CEXF(6,7)
  }
  float T = bf[7];   // 8th-smallest value, uniform across lanes

  // phase 2: exact (value, idx) top-8 over survivors only
  unsigned long long bd[8];
#pragma unroll
  for (int i = 0; i < 8; ++i) bd[i] = ~0ull;
#pragma unroll
  for (int i = 0; i < 32; ++i) {
    if (__any(fv[i] <= T)) {
      unsigned u = __builtin_bit_cast(unsigned, fv[i]);
      u ^= 0x80000000u | (unsigned)((int)u >> 31);
      unsigned long long key = ((unsigned long long)u << 32) | (unsigned)(lane + i*64);
#pragma unroll
      for (int k = 0; k < 8; ++k) {
        unsigned long long lo = key < bd[k] ? key : bd[k];
        unsigned long long hi = key < bd[k] ? bd[k] : key;
        bd[k] = lo; key = hi;
      }
    }
  }
#pragma unroll
  for (int m = 1; m <= 32; m <<= 1) {
    unsigned long long pr[8];
#pragma unroll
    for (int i = 0; i < 8; ++i) pr[i] = shfl_xor_u64(bd[7-i], m);
#pragma unroll
    for (int i = 0; i < 8; ++i) bd[i] = bd[i] < pr[i] ? bd[i] : pr[i];
    CEX(0,4) CEX(1,5) CEX(2,6) CEX(3,7)
    CEX(0,2) CEX(1,3) CEX(4,6) CEX(5,7)
    CEX(0,1) CEX(2,3) CEX(4,5) CEX(6,7)
  }
  if (lane == 0) {
#pragma unroll
    for (int r = 0; r < 8; ++r) idxo[(size_t)q*8 + r] = (int)(unsigned)bd[r];
  }
}

// ---------- geom = max_k lrelu(G[idx_k] + Cb + bias) ----------
__global__ __launch_bounds__(384) void geom_k(const unsigned short* __restrict__ GCb,
                                              const float* __restrict__ bias,
                                              const int* __restrict__ idx,
                                              unsigned short* __restrict__ out) {
  int q = blockIdx.x;
  int b = q >> 11;
  int d = threadIdx.x;
  float c = b2f(GCb[(size_t)q*768 + 384 + d]) + bias[d];
  float mx = -INFINITY;
#pragma unroll
  for (int kn = 0; kn < 8; ++kn) {
    int j = idx[(size_t)q*8 + kn];
    float gg = b2f(GCb[((size_t)(b << 11) + j)*768 + d]);
    float y = gg + c;
    y = (y > 0.f) ? y : 0.2f*y;
    mx = fmaxf(mx, y);
  }
  out[(size_t)q*768 + 384 + d] = f2b(mx);
}

extern "C" void kernel_launch(void* const* d_in, const int* in_sizes, int n_in,
                              void* d_out, int out_size, void* d_ws, size_t ws_size,
                              hipStream_t stream) {
  (void)in_sizes; (void)n_in; (void)out_size; (void)ws_size;
  const float* qpts  = (const float*)d_in[0];
  const float* kpts  = (const float*)d_in[1];
  const float* ln_s  = (const float*)d_in[2];
  const float* ln_b  = (const float*)d_in[3];
  const float* qkvW  = (const float*)d_in[4];
  const float* Wo    = (const float*)d_in[5];
  const float* bo    = (const float*)d_in[6];
  const float* ffW1  = (const float*)d_in[7];
  const float* ffb1  = (const float*)d_in[8];
  const float* ffW2  = (const float*)d_in[9];
  const float* ffb2  = (const float*)d_in[10];
  const float* ffns  = (const float*)d_in[11];
  const float* ffnb  = (const float*)d_in[12];
  const float* knn1W = (const float*)d_in[13];
  const float* knn1b = (const float*)d_in[14];
  const float* knn2W = (const float*)d_in[15];
  const float* knn2b = (const float*)d_in[16];
  const float* smW   = (const float*)d_in[17];
  const float* smb   = (const float*)d_in[18];
  const float* cmW   = (const float*)d_in[19];
  const float* cmb   = (const float*)d_in[20];
  const float* cnqs  = (const float*)d_in[21];
  const float* cnqb  = (const float*)d_in[22];
  const float* cnks  = (const float*)d_in[23];
  const float* cnkb  = (const float*)d_in[24];
  const float* cqW   = (const float*)d_in[25];
  const float* ckW   = (const float*)d_in[26];
  const float* cvW   = (const float*)d_in[27];

  float* ws = (float*)d_ws;
  float* qc4  = ws;
  float* kc4  = qc4 + 32768;
  float* qf   = kc4 + 32768;
  float* kf   = qf + 3145728;
  unsigned short* nrmb = (unsigned short*)(kf + 3145728);
  unsigned short* nkb  = (unsigned short*)(kf + 3145728 + 1572864);
  float* qkv = kf + 3145728 + 1572864 + 1572864;
  unsigned short* qkvb   = (unsigned short*)qkv;
  unsigned short* attnGb = (unsigned short*)qkv;
  unsigned short* vtb    = (unsigned short*)(qkv + 4718592);
  unsigned short* wtb    = (unsigned short*)(qkv + 4718592 + 1572864);
  unsigned short* attnOb = (unsigned short*)(qkv + 4718592 + 1572864 + 1400832);
  unsigned short* GCbb   = (unsigned short*)((float*)attnOb + 1572864);
  int* idx1 = (int*)((float*)GCbb + 3145728);
  int* idx2 = idx1 + 65536;

  const int W_FA=0, W_WO=737280, W_SM=884736, W_FB=1179648,
            W_CM=1916928, W_FF1=2211840, W_FF2=2506752;

  WSrcs srcs;
  srcs.p[0]=qkvW; srcs.p[1]=knn1W; srcs.p[2]=knn1W; srcs.p[3]=Wo; srcs.p[4]=smW;
  srcs.p[5]=cqW; srcs.p[6]=ckW; srcs.p[7]=cvW; srcs.p[8]=knn2W; srcs.p[9]=knn2W;
  srcs.p[10]=cmW; srcs.p[11]=ffW1; srcs.p[12]=ffW2;
  wtrans_k<<<2736, 256, 0, stream>>>(srcs, wtb);

  dim3 tgrid(13, 64, NB), tblk(32, 8);
  split_k<<<tgrid, tblk, 0, stream>>>(qpts, qc4, qf);
  split_k<<<tgrid, tblk, 0, stream>>>(kpts, kc4, kf);
  kprep_k<<<64, 256, 0, stream>>>(qc4);

  knn2_k<<<dim3(2048, 2), 256, 0, stream>>>(qc4, kc4, idx1, idx2);

  dim3 mg384h(6, 128), mg768(12, 64), fg(30, 64);

  // ---- self attention branch ----
  ln_k<<<2048, 256, 0, stream>>>(qf, ln_s, ln_b, nrmb);
  {
    FSegs fa;
    for (int s = 0; s < 5; ++s) fa.A[s] = nrmb;
    fa.out[0] = qkvb; fa.ldc[0] = 1152; fa.cofs[0] = 0;
    fa.out[1] = qkvb; fa.ldc[1] = 1152; fa.cofs[1] = 384;
    fa.out[2] = vtb;  fa.ldc[2] = 0;    fa.cofs[2] = 0;
    fa.out[3] = GCbb; fa.ldc[3] = 768;  fa.cofs[3] = 0;
    fa.out[4] = GCbb; fa.ldc[4] = 768;  fa.cofs[4] = 384;
    fgemm_k<<<fg, 256, 0, stream>>>(fa, wtb + W_FA);
  }
  flashm_k<<<768, 256, 0, stream>>>(qkvb, vtb, attnOb);
  mgemm_k<0,0,1,1><<<mg384h, 256, 0, stream>>>(attnOb, DD, wtb+W_WO, bo, attnGb, 768, 0, DD);
  geom_k<<<8192, 384, 0, stream>>>(GCbb, knn1b, idx1, attnGb);
  mgemm_k<0,1,0,1><<<mg384h, 256, 0, stream>>>(attnGb, 768, wtb+W_SM, smb, qf, DD, 0, 768);

  // ---- cross attention branch ----
  ln2_k<<<dim3(2048, 2), 256, 0, stream>>>(qf, cnqs, cnqb, nrmb, kf, cnks, cnkb, nkb);
  {
    FSegs fb;
    fb.A[0] = nrmb; fb.A[1] = nkb; fb.A[2] = nkb; fb.A[3] = nkb; fb.A[4] = nrmb;
    fb.out[0] = qkvb; fb.ldc[0] = 1152; fb.cofs[0] = 0;
    fb.out[1] = qkvb; fb.ldc[1] = 1152; fb.cofs[1] = 384;
    fb.out[2] = vtb;  fb.ldc[2] = 0;    fb.cofs[2] = 0;
    fb.out[3] = GCbb; fb.ldc[3] = 768;  fb.cofs[3] = 0;
    fb.out[4] = GCbb; fb.ldc[4] = 768;  fb.cofs[4] = 384;
    fgemm_k<<<fg, 256, 0, stream>>>(fb, wtb + W_FB);
  }
  flashm_k<<<768, 256, 0, stream>>>(qkvb, vtb, attnOb);
  mgemm_k<0,0,1,1><<<mg384h, 256, 0, stream>>>(attnOb, DD, wtb+W_WO, bo, attnGb, 768, 0, DD);
  geom_k<<<8192, 384, 0, stream>>>(GCbb, knn2b, idx2, attnGb);
  mgemm_k<0,1,0,1><<<mg384h, 256, 0, stream>>>(attnGb, 768, wtb+W_CM, cmb, qf, DD, 0, 768);

  // ---- FFN ----
  ln_k<<<2048, 256, 0, stream>>>(qf, ffns, ffnb, nrmb);
  mgemm_k<1,0,1,0><<<mg768, 256, 0, stream>>>(nrmb, DD, wtb+W_FF1, ffb1, attnGb, 768, 0, DD);
  mgemm_k<0,1,0,1><<<mg384h, 256, 0, stream>>>(attnGb, 768, wtb+W_FF2, ffb2, qf, DD, 0, 768);

  pack_k<<<tgrid, tblk, 0, stream>>>(qc4, qf, (float*)d_out);
}